// Round 1
// baseline (1231.226 us; speedup 1.0000x reference)
//
#include <hip/hip_runtime.h>
#include <math.h>

#define NCELL 100000
#define NNET  100000
#define NPIN  500000
#define NNN   200000
#define NPAIR 500000

__device__ __forceinline__ float softplusf(float x) {
    return fmaxf(x, 0.f) + log1pf(expf(-fabsf(x)));
}
__device__ __forceinline__ float sspf(float x) {
    return softplusf(x) - 0.69314718055994530942f;
}

// ---------------- degree computation ----------------
__global__ void k_degrees(const int* __restrict__ pin_cell, const int* __restrict__ pin_net,
                          const int* __restrict__ nn_src, const int* __restrict__ nn_dst,
                          float* degC, float* degNp, float* degS, float* degD) {
    int i = blockIdx.x * blockDim.x + threadIdx.x;
    if (i < NPIN) {
        atomicAdd(&degC[pin_cell[i]], 1.f);
        atomicAdd(&degNp[pin_net[i]], 1.f);
    }
    if (i < NNN) {
        atomicAdd(&degS[nn_src[i]], 1.f);
        atomicAdd(&degD[nn_dst[i]], 1.f);
    }
}

__global__ void k_deg_fin(float* deg) {
    int i = blockIdx.x * blockDim.x + threadIdx.x;
    if (i < 4 * NNET) deg[i] = rsqrtf(fmaxf(deg[i], 1.f));
}

// ---------------- [n,16] @ [16,64] + b, tanh ----------------
__global__ __launch_bounds__(256) void k_lin16_tanh(
    const float* __restrict__ in, const float* __restrict__ W,
    const float* __restrict__ b, float* __restrict__ out, int n) {
    __shared__ float Ws[16 * 64];
    __shared__ float bs[64];
    int tid = threadIdx.x;
    for (int i = tid; i < 16 * 64; i += 256) Ws[i] = W[i];
    if (tid < 64) bs[tid] = b[tid];
    __syncthreads();
    int row = blockIdx.x * 4 + (tid >> 6);
    int col = tid & 63;
    if (row >= n) return;
    const float* r = in + row * 16;
    float acc = bs[col];
#pragma unroll
    for (int k = 0; k < 16; k++) acc += r[k] * Ws[k * 64 + col];
    out[row * 64 + col] = tanhf(acc);
}

// ---------------- edge scatter: acc[dst] += h[src]*rs[src] ----------------
__global__ __launch_bounds__(256) void k_scatter_edge(
    const int* __restrict__ src, const int* __restrict__ dst,
    const float* __restrict__ h, const float* __restrict__ rs,
    float* __restrict__ acc, int nedge) {
    int e = blockIdx.x * 4 + (threadIdx.x >> 6);
    if (e >= nedge) return;
    int lane = threadIdx.x & 63;
    int s = src[e], d = dst[e];
    float v = h[s * 64 + lane] * rs[s];
    atomicAdd(&acc[d * 64 + lane], v);
}

// ---------------- h_net2 = max over 3 of (msg*cd) @ W + b ----------------
__global__ __launch_bounds__(256) void k_combine_net(
    const float* __restrict__ accP, const float* __restrict__ accF, const float* __restrict__ accS,
    const float* __restrict__ rNp, const float* __restrict__ rD, const float* __restrict__ rS,
    const float* __restrict__ Wp, const float* __restrict__ bp,
    const float* __restrict__ Wf, const float* __restrict__ bf,
    const float* __restrict__ Wso, const float* __restrict__ bso,
    float* __restrict__ out) {
    __shared__ float sWp[4096], sWf[4096], sWs[4096];
    __shared__ float sb[3 * 64];
    __shared__ float mp[256], mf[256], ms[256];
    int tid = threadIdx.x;
    for (int i = tid; i < 4096; i += 256) { sWp[i] = Wp[i]; sWf[i] = Wf[i]; sWs[i] = Wso[i]; }
    if (tid < 64) { sb[tid] = bp[tid]; sb[64 + tid] = bf[tid]; sb[128 + tid] = bso[tid]; }
    int row = blockIdx.x * 4 + (tid >> 6);
    int lane = tid & 63;
    mp[tid] = accP[row * 64 + lane] * rNp[row];
    mf[tid] = accF[row * 64 + lane] * rD[row];
    ms[tid] = accS[row * 64 + lane] * rS[row];
    __syncthreads();
    int g = (tid >> 6) * 64;
    float ap = sb[lane], af = sb[64 + lane], as = sb[128 + lane];
#pragma unroll
    for (int k = 0; k < 64; k++) {
        ap += mp[g + k] * sWp[k * 64 + lane];
        af += mf[g + k] * sWf[k * 64 + lane];
        as += ms[g + k] * sWs[k * 64 + lane];
    }
    out[row * 64 + lane] = fmaxf(fmaxf(ap, af), as);
}

// ---------------- [n,64] @ [64,64] + b, optional ssp ----------------
template <int ACT>  // 0 = none, 1 = ssp
__global__ __launch_bounds__(256) void k_lin64(
    const float* __restrict__ in, const float* __restrict__ W,
    const float* __restrict__ b, float* __restrict__ out, int n) {
    __shared__ float sW[4096];
    __shared__ float sb[64];
    __shared__ float sin_[256];
    int tid = threadIdx.x;
    for (int i = tid; i < 4096; i += 256) sW[i] = W[i];
    if (tid < 64) sb[tid] = b[tid];
    int row = blockIdx.x * 4 + (tid >> 6);
    int lane = tid & 63;
    sin_[tid] = in[row * 64 + lane];
    __syncthreads();
    int g = (tid >> 6) * 64;
    float acc = sb[lane];
#pragma unroll
    for (int k = 0; k < 64; k++) acc += sin_[g + k] * sW[k * 64 + lane];
    if (ACT == 1) acc = sspf(acc);
    out[row * 64 + lane] = acc;
}

// ---------------- CFConv: e(pin) from raw pin_feat, scatter hv[net]*e into cell ----------------
__global__ __launch_bounds__(256) void k_cfconv(
    const float* __restrict__ pin_feat,
    const float* __restrict__ E1, const float* __restrict__ b1,
    const float* __restrict__ E2, const float* __restrict__ b2,
    const float* __restrict__ hv,
    const int* __restrict__ pin_net, const int* __restrict__ pin_cell,
    float* __restrict__ acc) {
    __shared__ float sE1[512], sE2[4096], sb1[64], sb2[64], t1s[256];
    int tid = threadIdx.x;
    for (int i = tid; i < 512; i += 256) sE1[i] = E1[i];
    for (int i = tid; i < 4096; i += 256) sE2[i] = E2[i];
    if (tid < 64) { sb1[tid] = b1[tid]; sb2[tid] = b2[tid]; }
    __syncthreads();
    int p = blockIdx.x * 4 + (tid >> 6);
    int lane = tid & 63;
    const float* pf = pin_feat + p * 8;
    float a = sb1[lane];
#pragma unroll
    for (int k = 0; k < 8; k++) a += pf[k] * sE1[k * 64 + lane];
    t1s[tid] = sspf(a);
    __syncthreads();
    int g = (tid >> 6) * 64;
    float e = sb2[lane];
#pragma unroll
    for (int k = 0; k < 64; k++) e += t1s[g + k] * sE2[k * 64 + lane];
    e = sspf(e);
    int nidx = pin_net[p], cidx = pin_cell[p];
    float v = hv[nidx * 64 + lane] * e;
    atomicAdd(&acc[cidx * 64 + lane], v);
}

// ---------------- pairwise net readout ----------------
__global__ __launch_bounds__(256) void k_net_readout(
    const float* __restrict__ hnet2, const int* __restrict__ pairs,
    const float* __restrict__ wd, const float* __restrict__ bd,
    const float* __restrict__ wa, const float* __restrict__ ba,
    float* __restrict__ out_dis, float* __restrict__ out_ang) {
    int i = blockIdx.x * 4 + (threadIdx.x >> 6);
    if (i >= NPAIR) return;
    int lane = threadIdx.x & 63;
    int p0 = pairs[2 * i], p1 = pairs[2 * i + 1];
    float a = hnet2[p0 * 64 + lane], b = hnet2[p1 * 64 + lane];
    float sd = a * wd[lane] + b * wd[64 + lane];
    float sa = a * wa[lane] + b * wa[64 + lane];
    for (int off = 32; off > 0; off >>= 1) {
        sd += __shfl_down(sd, off, 64);
        sa += __shfl_down(sa, off, 64);
    }
    if (lane == 0) {
        out_dis[i] = softplusf(sd + bd[0]);
        out_ang[i] = sa + ba[0];
    }
}

// ---------------- per-pin readout (h_pin computed on the fly) ----------------
__global__ __launch_bounds__(256) void k_pin_readout(
    const float* __restrict__ hnet2, const float* __restrict__ hcell2,
    const float* __restrict__ pin_feat,
    const float* __restrict__ plw, const float* __restrict__ plb,
    const int* __restrict__ pin_net, const int* __restrict__ pin_cell,
    const float* __restrict__ wd, const float* __restrict__ bd,
    const float* __restrict__ wa, const float* __restrict__ ba,
    float* __restrict__ out_dis, float* __restrict__ out_ang) {
    int p = blockIdx.x * 4 + (threadIdx.x >> 6);
    if (p >= NPIN) return;
    int lane = threadIdx.x & 63;
    int n = pin_net[p], c = pin_cell[p];
    float hn = hnet2[n * 64 + lane];
    float hc = hcell2[c * 64 + lane];
    float sd = hn * wd[lane] + hc * wd[72 + lane];
    float sa = hn * wa[lane] + hc * wa[72 + lane];
    if (lane < 8) {
        const float* pf = pin_feat + p * 8;
        float acc = plb[lane];
#pragma unroll
        for (int k = 0; k < 8; k++) acc += pf[k] * plw[k * 8 + lane];
        float hp = tanhf(acc);
        sd += hp * wd[64 + lane];
        sa += hp * wa[64 + lane];
    }
    for (int off = 32; off > 0; off >>= 1) {
        sd += __shfl_down(sd, off, 64);
        sa += __shfl_down(sa, off, 64);
    }
    if (lane == 0) {
        out_dis[p] = softplusf(sd + bd[0]);
        out_ang[p] = sa + ba[0];
    }
}

extern "C" void kernel_launch(void* const* d_in, const int* in_sizes, int n_in,
                              void* d_out, int out_size, void* d_ws, size_t ws_size,
                              hipStream_t stream) {
    const float* cell_feat = (const float*)d_in[0];
    const float* net_feat  = (const float*)d_in[1];
    const float* pin_feat  = (const float*)d_in[2];
    const float* cell_lin_w = (const float*)d_in[3];
    const float* cell_lin_b = (const float*)d_in[4];
    const float* net_lin_w  = (const float*)d_in[5];
    const float* net_lin_b  = (const float*)d_in[6];
    const float* pin_lin_w  = (const float*)d_in[7];
    const float* pin_lin_b  = (const float*)d_in[8];
    const float* pins_w   = (const float*)d_in[9];
    const float* pins_b   = (const float*)d_in[10];
    const float* father_w = (const float*)d_in[11];
    const float* father_b = (const float*)d_in[12];
    const float* son_w    = (const float*)d_in[13];
    const float* son_b    = (const float*)d_in[14];
    const float* cf_node_w = (const float*)d_in[15];
    const float* cf_node_b = (const float*)d_in[16];
    const float* cf_e1_w  = (const float*)d_in[17];
    const float* cf_e1_b  = (const float*)d_in[18];
    const float* cf_e2_w  = (const float*)d_in[19];
    const float* cf_e2_b  = (const float*)d_in[20];
    const float* cf_out_w = (const float*)d_in[21];
    const float* cf_out_b = (const float*)d_in[22];
    const float* net_dis_w   = (const float*)d_in[23];
    const float* net_dis_b   = (const float*)d_in[24];
    const float* net_angle_w = (const float*)d_in[25];
    const float* net_angle_b = (const float*)d_in[26];
    const float* pin_dis_w   = (const float*)d_in[27];
    const float* pin_dis_b   = (const float*)d_in[28];
    const float* pin_angle_w = (const float*)d_in[29];
    const float* pin_angle_b = (const float*)d_in[30];
    const int* pin_net = (const int*)d_in[31];
    const int* pin_cell = (const int*)d_in[32];
    const int* nn_src = (const int*)d_in[33];
    const int* nn_dst = (const int*)d_in[34];
    const int* pairs = (const int*)d_in[35];

    float* ws = (float*)d_ws;
    const size_t SZ = (size_t)NNET * 64;  // 6.4M floats
    float* h_cell = ws;                // later reused for hv
    float* h_net  = ws + SZ;
    float* bufA   = ws + 2 * SZ;       // accP, later acc_cell
    float* bufB   = ws + 3 * SZ;       // accF, later h_cell2
    float* bufC   = ws + 4 * SZ;       // accS
    float* h_net2 = ws + 5 * SZ;
    float* deg    = ws + 6 * SZ;       // 4 * NNET: rC, rNp, rS, rD
    float* rC  = deg;
    float* rNp = deg + NNET;
    float* rS  = deg + 2 * NNET;
    float* rD  = deg + 3 * NNET;

    hipMemsetAsync(bufA, 0, 3 * SZ * sizeof(float), stream);   // accP, accF, accS
    hipMemsetAsync(deg, 0, 4 * NNET * sizeof(float), stream);

    k_degrees<<<(NPIN + 255) / 256, 256, 0, stream>>>(pin_cell, pin_net, nn_src, nn_dst,
                                                      rC, rNp, rS, rD);
    k_deg_fin<<<(4 * NNET + 255) / 256, 256, 0, stream>>>(deg);

    k_lin16_tanh<<<NCELL / 4, 256, 0, stream>>>(cell_feat, cell_lin_w, cell_lin_b, h_cell, NCELL);
    k_lin16_tanh<<<NNET / 4, 256, 0, stream>>>(net_feat, net_lin_w, net_lin_b, h_net, NNET);

    // GraphConv message accumulation
    k_scatter_edge<<<NPIN / 4, 256, 0, stream>>>(pin_cell, pin_net, h_cell, rC, bufA, NPIN);
    k_scatter_edge<<<NNN / 4, 256, 0, stream>>>(nn_src, nn_dst, h_net, rS, bufB, NNN);
    k_scatter_edge<<<NNN / 4, 256, 0, stream>>>(nn_dst, nn_src, h_net, rD, bufC, NNN);

    k_combine_net<<<NNET / 4, 256, 0, stream>>>(bufA, bufB, bufC, rNp, rD, rS,
                                                pins_w, pins_b, father_w, father_b,
                                                son_w, son_b, h_net2);

    // hv = h_net @ cf_node_w + b  (into h_cell buffer, no longer needed)
    k_lin64<0><<<NNET / 4, 256, 0, stream>>>(h_net, cf_node_w, cf_node_b, h_cell, NNET);

    hipMemsetAsync(bufA, 0, SZ * sizeof(float), stream);       // acc_cell
    k_cfconv<<<NPIN / 4, 256, 0, stream>>>(pin_feat, cf_e1_w, cf_e1_b, cf_e2_w, cf_e2_b,
                                           h_cell, pin_net, pin_cell, bufA);
    k_lin64<1><<<NCELL / 4, 256, 0, stream>>>(bufA, cf_out_w, cf_out_b, bufB, NCELL);

    float* out = (float*)d_out;
    k_net_readout<<<NPAIR / 4, 256, 0, stream>>>(h_net2, pairs,
                                                 net_dis_w, net_dis_b,
                                                 net_angle_w, net_angle_b,
                                                 out, out + NPAIR);
    k_pin_readout<<<NPIN / 4, 256, 0, stream>>>(h_net2, bufB, pin_feat, pin_lin_w, pin_lin_b,
                                                pin_net, pin_cell,
                                                pin_dis_w, pin_dis_b,
                                                pin_angle_w, pin_angle_b,
                                                out + 2 * NPAIR, out + 2 * NPAIR + NPIN);
}

// Round 2
// 783.828 us; speedup vs baseline: 1.5708x; 1.5708x over previous
//
#include <hip/hip_runtime.h>
#include <math.h>

#define NCELL 100000
#define NNET  100000
#define NPIN  500000
#define NNN   200000
#define NPAIR 500000

__device__ __forceinline__ float softplusf(float x) {
    return fmaxf(x, 0.f) + log1pf(expf(-fabsf(x)));
}
__device__ __forceinline__ float sspf(float x) {
    return softplusf(x) - 0.69314718055994530942f;
}

// ---------------- degree computation ----------------
__global__ void k_degrees(const int* __restrict__ pin_cell, const int* __restrict__ pin_net,
                          const int* __restrict__ nn_src, const int* __restrict__ nn_dst,
                          float* degC, float* degNp, float* degS, float* degD) {
    int i = blockIdx.x * blockDim.x + threadIdx.x;
    if (i < NPIN) {
        atomicAdd(&degC[pin_cell[i]], 1.f);
        atomicAdd(&degNp[pin_net[i]], 1.f);
    }
    if (i < NNN) {
        atomicAdd(&degS[nn_src[i]], 1.f);
        atomicAdd(&degD[nn_dst[i]], 1.f);
    }
}

__global__ void k_deg_fin(float* deg) {
    int i = blockIdx.x * blockDim.x + threadIdx.x;
    if (i < 4 * NNET) deg[i] = rsqrtf(fmaxf(deg[i], 1.f));
}

// ---------------- [n,16] @ [16,64] + b, tanh; W column in registers ----------------
__global__ __launch_bounds__(256) void k_lin16(
    const float* __restrict__ in, const float* __restrict__ W,
    const float* __restrict__ b, float* __restrict__ out, int n) {
    int tid = threadIdx.x, lane = tid & 63, w = tid >> 6;
    float wr[16];
#pragma unroll
    for (int k = 0; k < 16; k++) wr[k] = W[k * 64 + lane];
    float bias = b[lane];
    int wave = blockIdx.x * 4 + w, nw = gridDim.x * 4;
    for (int r = wave; r < n; r += nw) {
        const float4* ip = (const float4*)(in + (size_t)r * 16);
        float4 a = ip[0], bv = ip[1], c = ip[2], d = ip[3];
        float acc = bias;
        acc = fmaf(a.x, wr[0], acc);  acc = fmaf(a.y, wr[1], acc);
        acc = fmaf(a.z, wr[2], acc);  acc = fmaf(a.w, wr[3], acc);
        acc = fmaf(bv.x, wr[4], acc); acc = fmaf(bv.y, wr[5], acc);
        acc = fmaf(bv.z, wr[6], acc); acc = fmaf(bv.w, wr[7], acc);
        acc = fmaf(c.x, wr[8], acc);  acc = fmaf(c.y, wr[9], acc);
        acc = fmaf(c.z, wr[10], acc); acc = fmaf(c.w, wr[11], acc);
        acc = fmaf(d.x, wr[12], acc); acc = fmaf(d.y, wr[13], acc);
        acc = fmaf(d.z, wr[14], acc); acc = fmaf(d.w, wr[15], acc);
        out[(size_t)r * 64 + lane] = tanhf(acc);
    }
}

// ---------------- edge scatter: acc[dst] += h[src]*rs[src] ----------------
__global__ __launch_bounds__(256) void k_scatter_edge(
    const int* __restrict__ src, const int* __restrict__ dst,
    const float* __restrict__ h, const float* __restrict__ rs,
    float* __restrict__ acc, int nedge) {
    int e = blockIdx.x * 4 + (threadIdx.x >> 6);
    if (e >= nedge) return;
    int lane = threadIdx.x & 63;
    int s = src[e], d = dst[e];
    float v = h[(size_t)s * 64 + lane] * rs[s];
    atomicAdd(&acc[(size_t)d * 64 + lane], v);
}

// ---------------- generic [n,64] @ [64,64] + b; W in registers ----------------
// MODE: 0 = store, 1 = ssp then store, 2 = max with existing out then store
template <int MODE>
__global__ __launch_bounds__(256) void k_mm64(
    const float* __restrict__ in, const float* __restrict__ scale,
    const float* __restrict__ W, const float* __restrict__ b,
    float* __restrict__ out, int n) {
    __shared__ float ts[4 * 64];
    int tid = threadIdx.x, lane = tid & 63, w = tid >> 6;
    float wr[64];
#pragma unroll
    for (int k = 0; k < 64; k++) wr[k] = W[k * 64 + lane];
    float bias = b[lane];
    float4* tp = (float4*)&ts[w * 64];
    int wave = blockIdx.x * 4 + w, nw = gridDim.x * 4;
    for (int r = wave; r < n; r += nw) {
        float v = in[(size_t)r * 64 + lane];
        if (scale) v *= scale[r];
        ts[w * 64 + lane] = v;
        float acc = bias;
#pragma unroll
        for (int k4 = 0; k4 < 16; k4++) {
            float4 t = tp[k4];
            acc = fmaf(t.x, wr[4 * k4 + 0], acc);
            acc = fmaf(t.y, wr[4 * k4 + 1], acc);
            acc = fmaf(t.z, wr[4 * k4 + 2], acc);
            acc = fmaf(t.w, wr[4 * k4 + 3], acc);
        }
        if (MODE == 1) acc = sspf(acc);
        if (MODE == 2) acc = fmaxf(acc, out[(size_t)r * 64 + lane]);
        out[(size_t)r * 64 + lane] = acc;
    }
}

// ---------------- CFConv fused: e-MLP (weights in regs) + gather/scatter ----------------
__global__ __launch_bounds__(256) void k_cfconv(
    const float* __restrict__ pin_feat,
    const float* __restrict__ E1, const float* __restrict__ b1,
    const float* __restrict__ E2, const float* __restrict__ b2,
    const float* __restrict__ hv,
    const int* __restrict__ pin_net, const int* __restrict__ pin_cell,
    float* __restrict__ acc) {
    __shared__ float ts[4 * 64];
    int tid = threadIdx.x, lane = tid & 63, w = tid >> 6;
    float e1r[8], e2r[64];
#pragma unroll
    for (int k = 0; k < 8; k++) e1r[k] = E1[k * 64 + lane];
#pragma unroll
    for (int k = 0; k < 64; k++) e2r[k] = E2[k * 64 + lane];
    float bb1 = b1[lane], bb2 = b2[lane];
    float4* tp = (float4*)&ts[w * 64];
    int wave = blockIdx.x * 4 + w, nw = gridDim.x * 4;
    for (int p = wave; p < NPIN; p += nw) {
        const float4* pf4 = (const float4*)(pin_feat + (size_t)p * 8);
        float4 pa = pf4[0], pb = pf4[1];
        float t = bb1;
        t = fmaf(pa.x, e1r[0], t); t = fmaf(pa.y, e1r[1], t);
        t = fmaf(pa.z, e1r[2], t); t = fmaf(pa.w, e1r[3], t);
        t = fmaf(pb.x, e1r[4], t); t = fmaf(pb.y, e1r[5], t);
        t = fmaf(pb.z, e1r[6], t); t = fmaf(pb.w, e1r[7], t);
        t = sspf(t);
        ts[w * 64 + lane] = t;
        float e = bb2;
#pragma unroll
        for (int k4 = 0; k4 < 16; k4++) {
            float4 q = tp[k4];
            e = fmaf(q.x, e2r[4 * k4 + 0], e);
            e = fmaf(q.y, e2r[4 * k4 + 1], e);
            e = fmaf(q.z, e2r[4 * k4 + 2], e);
            e = fmaf(q.w, e2r[4 * k4 + 3], e);
        }
        e = sspf(e);
        int ni = pin_net[p], ci = pin_cell[p];
        float v = hv[(size_t)ni * 64 + lane] * e;
        atomicAdd(&acc[(size_t)ci * 64 + lane], v);
    }
}

// ---------------- per-net scalar precompute: 6 dots per net ----------------
// tab[n*8 + {0:d0, 1:a0, 2:d1, 3:a1, 4:nd, 5:na}]
__global__ __launch_bounds__(256) void k_net_scalars(
    const float* __restrict__ hnet2,
    const float* __restrict__ ndw, const float* __restrict__ naw,   // [128]
    const float* __restrict__ pdw, const float* __restrict__ paw,   // [136]
    float* __restrict__ tab) {
    int tid = threadIdx.x, lane = tid & 63, w = tid >> 6;
    float wd0 = ndw[lane], wd1 = ndw[64 + lane];
    float wa0 = naw[lane], wa1 = naw[64 + lane];
    float wpd = pdw[lane], wpa = paw[lane];
    int wave = blockIdx.x * 4 + w, nw = gridDim.x * 4;
    for (int r = wave; r < NNET; r += nw) {
        float h = hnet2[(size_t)r * 64 + lane];
        float s0 = h * wd0, s1 = h * wd1, s2 = h * wa0, s3 = h * wa1;
        float s4 = h * wpd, s5 = h * wpa;
        for (int off = 32; off > 0; off >>= 1) {
            s0 += __shfl_down(s0, off, 64); s1 += __shfl_down(s1, off, 64);
            s2 += __shfl_down(s2, off, 64); s3 += __shfl_down(s3, off, 64);
            s4 += __shfl_down(s4, off, 64); s5 += __shfl_down(s5, off, 64);
        }
        if (lane == 0) {
            float* t = tab + (size_t)r * 8;
            t[0] = s0; t[1] = s2; t[2] = s1; t[3] = s3; t[4] = s4; t[5] = s5;
        }
    }
}

// ---------------- per-cell scalar precompute: 2 dots per cell ----------------
__global__ __launch_bounds__(256) void k_cell_scalars(
    const float* __restrict__ hcell2,
    const float* __restrict__ pdw, const float* __restrict__ paw,   // [136], use [72:136]
    float* __restrict__ tab) {   // [NCELL*2]
    int tid = threadIdx.x, lane = tid & 63, w = tid >> 6;
    float wd = pdw[72 + lane], wa = paw[72 + lane];
    int wave = blockIdx.x * 4 + w, nw = gridDim.x * 4;
    for (int r = wave; r < NCELL; r += nw) {
        float h = hcell2[(size_t)r * 64 + lane];
        float s0 = h * wd, s1 = h * wa;
        for (int off = 32; off > 0; off >>= 1) {
            s0 += __shfl_down(s0, off, 64);
            s1 += __shfl_down(s1, off, 64);
        }
        if (lane == 0) {
            tab[(size_t)r * 2] = s0;
            tab[(size_t)r * 2 + 1] = s1;
        }
    }
}

// ---------------- pair readout: one lane per pair ----------------
__global__ __launch_bounds__(256) void k_pair(
    const int* __restrict__ pairs, const float* __restrict__ tab,
    const float* __restrict__ bd, const float* __restrict__ ba,
    float* __restrict__ od, float* __restrict__ oa) {
    int i = blockIdx.x * blockDim.x + threadIdx.x;
    if (i >= NPAIR) return;
    int p0 = pairs[2 * i], p1 = pairs[2 * i + 1];
    float2 x0 = *(const float2*)(tab + (size_t)p0 * 8);       // d0, a0
    float2 x1 = *(const float2*)(tab + (size_t)p1 * 8 + 2);   // d1, a1
    od[i] = softplusf(x0.x + x1.x + bd[0]);
    oa[i] = x0.y + x1.y + ba[0];
}

// ---------------- pin readout: one lane per pin ----------------
__global__ __launch_bounds__(256) void k_pinro(
    const float* __restrict__ pin_feat,
    const int* __restrict__ pin_net, const int* __restrict__ pin_cell,
    const float* __restrict__ ntab, const float* __restrict__ ctab,
    const float* __restrict__ plw, const float* __restrict__ plb,   // [8,8],[8]
    const float* __restrict__ pdw, const float* __restrict__ paw,   // [136]
    const float* __restrict__ bd, const float* __restrict__ ba,
    float* __restrict__ od, float* __restrict__ oa) {
    int p = blockIdx.x * blockDim.x + threadIdx.x;
    if (p >= NPIN) return;
    int n = pin_net[p], c = pin_cell[p];
    float2 ns = *(const float2*)(ntab + (size_t)n * 8 + 4);   // nd, na
    float2 cs = *(const float2*)(ctab + (size_t)c * 2);       // cd, ca
    float pf[8];
    *(float4*)pf = *(const float4*)(pin_feat + (size_t)p * 8);
    *(float4*)(pf + 4) = *(const float4*)(pin_feat + (size_t)p * 8 + 4);
    float sd = ns.x + cs.x + bd[0];
    float sa = ns.y + cs.y + ba[0];
#pragma unroll
    for (int j = 0; j < 8; j++) {
        float a = plb[j];
#pragma unroll
        for (int k = 0; k < 8; k++) a = fmaf(pf[k], plw[k * 8 + j], a);
        float hp = tanhf(a);
        sd = fmaf(hp, pdw[64 + j], sd);
        sa = fmaf(hp, paw[64 + j], sa);
    }
    od[p] = softplusf(sd);
    oa[p] = sa;
}

extern "C" void kernel_launch(void* const* d_in, const int* in_sizes, int n_in,
                              void* d_out, int out_size, void* d_ws, size_t ws_size,
                              hipStream_t stream) {
    const float* cell_feat = (const float*)d_in[0];
    const float* net_feat  = (const float*)d_in[1];
    const float* pin_feat  = (const float*)d_in[2];
    const float* cell_lin_w = (const float*)d_in[3];
    const float* cell_lin_b = (const float*)d_in[4];
    const float* net_lin_w  = (const float*)d_in[5];
    const float* net_lin_b  = (const float*)d_in[6];
    const float* pin_lin_w  = (const float*)d_in[7];
    const float* pin_lin_b  = (const float*)d_in[8];
    const float* pins_w   = (const float*)d_in[9];
    const float* pins_b   = (const float*)d_in[10];
    const float* father_w = (const float*)d_in[11];
    const float* father_b = (const float*)d_in[12];
    const float* son_w    = (const float*)d_in[13];
    const float* son_b    = (const float*)d_in[14];
    const float* cf_node_w = (const float*)d_in[15];
    const float* cf_node_b = (const float*)d_in[16];
    const float* cf_e1_w  = (const float*)d_in[17];
    const float* cf_e1_b  = (const float*)d_in[18];
    const float* cf_e2_w  = (const float*)d_in[19];
    const float* cf_e2_b  = (const float*)d_in[20];
    const float* cf_out_w = (const float*)d_in[21];
    const float* cf_out_b = (const float*)d_in[22];
    const float* net_dis_w   = (const float*)d_in[23];
    const float* net_dis_b   = (const float*)d_in[24];
    const float* net_angle_w = (const float*)d_in[25];
    const float* net_angle_b = (const float*)d_in[26];
    const float* pin_dis_w   = (const float*)d_in[27];
    const float* pin_dis_b   = (const float*)d_in[28];
    const float* pin_angle_w = (const float*)d_in[29];
    const float* pin_angle_b = (const float*)d_in[30];
    const int* pin_net = (const int*)d_in[31];
    const int* pin_cell = (const int*)d_in[32];
    const int* nn_src = (const int*)d_in[33];
    const int* nn_dst = (const int*)d_in[34];
    const int* pairs = (const int*)d_in[35];

    float* ws = (float*)d_ws;
    const size_t SZ = (size_t)NNET * 64;  // 6.4M floats
    float* h_cell = ws;                // later reused for hv
    float* h_net  = ws + SZ;
    float* bufA   = ws + 2 * SZ;       // accP, later acc_cell
    float* bufB   = ws + 3 * SZ;       // accF, later h_cell2
    float* bufC   = ws + 4 * SZ;       // accS, later ntab/ctab
    float* h_net2 = ws + 5 * SZ;
    float* deg    = ws + 6 * SZ;       // 4 * NNET
    float* rC  = deg;
    float* rNp = deg + NNET;
    float* rS  = deg + 2 * NNET;
    float* rD  = deg + 3 * NNET;
    float* ntab = bufC;                       // NNET*8 floats (valid after combine)
    float* ctab = bufC + (size_t)NNET * 8;    // NCELL*2 floats

    const int GS = 2048;  // grid-stride wave kernels: 8192 waves

    hipMemsetAsync(bufA, 0, 3 * SZ * sizeof(float), stream);   // accP, accF, accS
    hipMemsetAsync(deg, 0, 4 * NNET * sizeof(float), stream);

    k_degrees<<<(NPIN + 255) / 256, 256, 0, stream>>>(pin_cell, pin_net, nn_src, nn_dst,
                                                      rC, rNp, rS, rD);
    k_deg_fin<<<(4 * NNET + 255) / 256, 256, 0, stream>>>(deg);

    k_lin16<<<GS, 256, 0, stream>>>(cell_feat, cell_lin_w, cell_lin_b, h_cell, NCELL);
    k_lin16<<<GS, 256, 0, stream>>>(net_feat, net_lin_w, net_lin_b, h_net, NNET);

    // GraphConv message accumulation
    k_scatter_edge<<<NPIN / 4, 256, 0, stream>>>(pin_cell, pin_net, h_cell, rC, bufA, NPIN);
    k_scatter_edge<<<NNN / 4, 256, 0, stream>>>(nn_src, nn_dst, h_net, rS, bufB, NNN);
    k_scatter_edge<<<NNN / 4, 256, 0, stream>>>(nn_dst, nn_src, h_net, rD, bufC, NNN);

    // h_net2 = max over 3 relations of (msg * cd) @ W + b
    k_mm64<0><<<GS, 256, 0, stream>>>(bufA, rNp, pins_w, pins_b, h_net2, NNET);
    k_mm64<2><<<GS, 256, 0, stream>>>(bufB, rD, father_w, father_b, h_net2, NNET);
    k_mm64<2><<<GS, 256, 0, stream>>>(bufC, rS, son_w, son_b, h_net2, NNET);

    // hv = h_net @ cf_node_w + b   (into h_cell buffer, no longer needed)
    k_mm64<0><<<GS, 256, 0, stream>>>(h_net, nullptr, cf_node_w, cf_node_b, h_cell, NNET);

    hipMemsetAsync(bufA, 0, SZ * sizeof(float), stream);       // acc_cell
    k_cfconv<<<GS, 256, 0, stream>>>(pin_feat, cf_e1_w, cf_e1_b, cf_e2_w, cf_e2_b,
                                     h_cell, pin_net, pin_cell, bufA);
    // h_cell2 = ssp(acc_cell @ cf_out_w + b)
    k_mm64<1><<<GS, 256, 0, stream>>>(bufA, nullptr, cf_out_w, cf_out_b, bufB, NCELL);

    // readout scalar precompute
    k_net_scalars<<<GS, 256, 0, stream>>>(h_net2, net_dis_w, net_angle_w,
                                          pin_dis_w, pin_angle_w, ntab);
    k_cell_scalars<<<GS, 256, 0, stream>>>(bufB, pin_dis_w, pin_angle_w, ctab);

    float* out = (float*)d_out;
    k_pair<<<(NPAIR + 255) / 256, 256, 0, stream>>>(pairs, ntab, net_dis_b, net_angle_b,
                                                    out, out + NPAIR);
    k_pinro<<<(NPIN + 255) / 256, 256, 0, stream>>>(pin_feat, pin_net, pin_cell,
                                                    ntab, ctab, pin_lin_w, pin_lin_b,
                                                    pin_dis_w, pin_angle_w,
                                                    pin_dis_b, pin_angle_b,
                                                    out + 2 * NPAIR, out + 2 * NPAIR + NPIN);
}

// Round 3
// 758.717 us; speedup vs baseline: 1.6228x; 1.0331x over previous
//
#include <hip/hip_runtime.h>
#include <math.h>

#define NCELL 100000
#define NNET  100000
#define NPIN  500000
#define NNN   200000
#define NPAIR 500000

__device__ __forceinline__ float softplusf(float x) {
    return fmaxf(x, 0.f) + log1pf(expf(-fabsf(x)));
}
__device__ __forceinline__ float sspf(float x) {
    return softplusf(x) - 0.69314718055994530942f;
}

// ---------------- degree computation ----------------
__global__ void k_degrees(const int* __restrict__ pin_cell, const int* __restrict__ pin_net,
                          const int* __restrict__ nn_src, const int* __restrict__ nn_dst,
                          float* degC, float* degNp, float* degS, float* degD) {
    int i = blockIdx.x * blockDim.x + threadIdx.x;
    if (i < NPIN) {
        atomicAdd(&degC[pin_cell[i]], 1.f);
        atomicAdd(&degNp[pin_net[i]], 1.f);
    }
    if (i < NNN) {
        atomicAdd(&degS[nn_src[i]], 1.f);
        atomicAdd(&degD[nn_dst[i]], 1.f);
    }
}

__global__ void k_deg_fin(float* deg) {
    int i = blockIdx.x * blockDim.x + threadIdx.x;
    if (i < 4 * NNET) deg[i] = rsqrtf(fmaxf(deg[i], 1.f));
}

// ---------------- [n,16] @ [16,64] + b, tanh; W column in registers ----------------
__global__ __launch_bounds__(256) void k_lin16(
    const float* __restrict__ in, const float* __restrict__ W,
    const float* __restrict__ b, float* __restrict__ out, int n) {
    int tid = threadIdx.x, lane = tid & 63, w = tid >> 6;
    float wr[16];
#pragma unroll
    for (int k = 0; k < 16; k++) wr[k] = W[k * 64 + lane];
    float bias = b[lane];
    int wave = blockIdx.x * 4 + w, nw = gridDim.x * 4;
    for (int r = wave; r < n; r += nw) {
        const float4* ip = (const float4*)(in + (size_t)r * 16);
        float4 a = ip[0], bv = ip[1], c = ip[2], d = ip[3];
        float acc = bias;
        acc = fmaf(a.x, wr[0], acc);  acc = fmaf(a.y, wr[1], acc);
        acc = fmaf(a.z, wr[2], acc);  acc = fmaf(a.w, wr[3], acc);
        acc = fmaf(bv.x, wr[4], acc); acc = fmaf(bv.y, wr[5], acc);
        acc = fmaf(bv.z, wr[6], acc); acc = fmaf(bv.w, wr[7], acc);
        acc = fmaf(c.x, wr[8], acc);  acc = fmaf(c.y, wr[9], acc);
        acc = fmaf(c.z, wr[10], acc); acc = fmaf(c.w, wr[11], acc);
        acc = fmaf(d.x, wr[12], acc); acc = fmaf(d.y, wr[13], acc);
        acc = fmaf(d.z, wr[14], acc); acc = fmaf(d.w, wr[15], acc);
        out[(size_t)r * 64 + lane] = tanhf(acc);
    }
}

// ---------------- edge scatter: acc[dst] += h[src]*rs[src]; 2 edges/iter ----------------
__global__ __launch_bounds__(256) void k_scatter_edge(
    const int* __restrict__ src, const int* __restrict__ dst,
    const float* __restrict__ h, const float* __restrict__ rs,
    float* __restrict__ acc, int nedge) {
    int lane = threadIdx.x & 63;
    int wave = blockIdx.x * 4 + (threadIdx.x >> 6), nw = gridDim.x * 4;
    for (int e = wave * 2; e < nedge; e += nw * 2) {
        int s0 = src[e], s1 = src[e + 1];
        int d0 = dst[e], d1 = dst[e + 1];
        float r0 = rs[s0], r1 = rs[s1];
        float h0 = h[(size_t)s0 * 64 + lane];
        float h1 = h[(size_t)s1 * 64 + lane];
        atomicAdd(&acc[(size_t)d0 * 64 + lane], h0 * r0);
        atomicAdd(&acc[(size_t)d1 * 64 + lane], h1 * r1);
    }
}

// ---------------- generic [n,64] @ [64,64] + b; W in registers; 2 rows/iter ----------------
// MODE: 0 = store, 1 = ssp then store, 2 = max with existing out then store
template <int MODE>
__global__ __launch_bounds__(256, 4) void k_mm64(
    const float* __restrict__ in, const float* __restrict__ scale,
    const float* __restrict__ W, const float* __restrict__ b,
    float* __restrict__ out, int n) {
    __shared__ float ts[4][2][64];
    int tid = threadIdx.x, lane = tid & 63, w = tid >> 6;
    float wr[64];
#pragma unroll
    for (int k = 0; k < 64; k++) wr[k] = W[k * 64 + lane];
    float bias = b[lane];
    const float4* tpa = (const float4*)ts[w][0];
    const float4* tpb = (const float4*)ts[w][1];
    int wave = blockIdx.x * 4 + w, nw = gridDim.x * 4;
    for (int r = wave * 2; r < n; r += nw * 2) {
        float v0 = in[(size_t)r * 64 + lane];
        float v1 = in[(size_t)(r + 1) * 64 + lane];
        float prev0, prev1;
        if (MODE == 2) {   // issue early so latency hides under the FMA block
            prev0 = out[(size_t)r * 64 + lane];
            prev1 = out[(size_t)(r + 1) * 64 + lane];
        }
        if (scale) { v0 *= scale[r]; v1 *= scale[r + 1]; }
        ts[w][0][lane] = v0;
        ts[w][1][lane] = v1;
        float a0 = bias, a1 = 0.f, c0 = bias, c1 = 0.f;
#pragma unroll
        for (int k4 = 0; k4 < 16; k4++) {
            float4 qa = tpa[k4], qb = tpb[k4];
            int kb = 4 * k4;
            a0 = fmaf(qa.x, wr[kb + 0], a0);
            c0 = fmaf(qb.x, wr[kb + 0], c0);
            a1 = fmaf(qa.y, wr[kb + 1], a1);
            c1 = fmaf(qb.y, wr[kb + 1], c1);
            a0 = fmaf(qa.z, wr[kb + 2], a0);
            c0 = fmaf(qb.z, wr[kb + 2], c0);
            a1 = fmaf(qa.w, wr[kb + 3], a1);
            c1 = fmaf(qb.w, wr[kb + 3], c1);
        }
        float r0 = a0 + a1, r1 = c0 + c1;
        if (MODE == 1) { r0 = sspf(r0); r1 = sspf(r1); }
        if (MODE == 2) { r0 = fmaxf(r0, prev0); r1 = fmaxf(r1, prev1); }
        out[(size_t)r * 64 + lane] = r0;
        out[(size_t)(r + 1) * 64 + lane] = r1;
    }
}

// ---------------- CFConv fused: e-MLP (weights in regs) + gather/scatter; 2 pins/iter ----------------
__global__ __launch_bounds__(256, 4) void k_cfconv(
    const float* __restrict__ pin_feat,
    const float* __restrict__ E1, const float* __restrict__ b1,
    const float* __restrict__ E2, const float* __restrict__ b2,
    const float* __restrict__ hv,
    const int* __restrict__ pin_net, const int* __restrict__ pin_cell,
    float* __restrict__ acc) {
    __shared__ float ts[4][2][64];
    int tid = threadIdx.x, lane = tid & 63, w = tid >> 6;
    float e1r[8], e2r[64];
#pragma unroll
    for (int k = 0; k < 8; k++) e1r[k] = E1[k * 64 + lane];
#pragma unroll
    for (int k = 0; k < 64; k++) e2r[k] = E2[k * 64 + lane];
    float bb1 = b1[lane], bb2 = b2[lane];
    const float4* tpa = (const float4*)ts[w][0];
    const float4* tpb = (const float4*)ts[w][1];
    int wave = blockIdx.x * 4 + w, nw = gridDim.x * 4;
    for (int p = wave * 2; p < NPIN; p += nw * 2) {
        int ni0 = pin_net[p], ni1 = pin_net[p + 1];
        int ci0 = pin_cell[p], ci1 = pin_cell[p + 1];
        // issue the random-gather rows EARLY; latency hides under e-MLP compute
        float hv0 = hv[(size_t)ni0 * 64 + lane];
        float hv1 = hv[(size_t)ni1 * 64 + lane];
        const float4* A = (const float4*)(pin_feat + (size_t)p * 8);
        float4 f0 = A[0], f1 = A[1], f2 = A[2], f3 = A[3];
        float t0 = bb1, t1 = bb1;
        t0 = fmaf(f0.x, e1r[0], t0); t1 = fmaf(f2.x, e1r[0], t1);
        t0 = fmaf(f0.y, e1r[1], t0); t1 = fmaf(f2.y, e1r[1], t1);
        t0 = fmaf(f0.z, e1r[2], t0); t1 = fmaf(f2.z, e1r[2], t1);
        t0 = fmaf(f0.w, e1r[3], t0); t1 = fmaf(f2.w, e1r[3], t1);
        t0 = fmaf(f1.x, e1r[4], t0); t1 = fmaf(f3.x, e1r[4], t1);
        t0 = fmaf(f1.y, e1r[5], t0); t1 = fmaf(f3.y, e1r[5], t1);
        t0 = fmaf(f1.z, e1r[6], t0); t1 = fmaf(f3.z, e1r[6], t1);
        t0 = fmaf(f1.w, e1r[7], t0); t1 = fmaf(f3.w, e1r[7], t1);
        t0 = sspf(t0); t1 = sspf(t1);
        ts[w][0][lane] = t0;
        ts[w][1][lane] = t1;
        float a0 = bb2, a1 = 0.f, c0 = bb2, c1 = 0.f;
#pragma unroll
        for (int k4 = 0; k4 < 16; k4++) {
            float4 qa = tpa[k4], qb = tpb[k4];
            int kb = 4 * k4;
            a0 = fmaf(qa.x, e2r[kb + 0], a0);
            c0 = fmaf(qb.x, e2r[kb + 0], c0);
            a1 = fmaf(qa.y, e2r[kb + 1], a1);
            c1 = fmaf(qb.y, e2r[kb + 1], c1);
            a0 = fmaf(qa.z, e2r[kb + 2], a0);
            c0 = fmaf(qb.z, e2r[kb + 2], c0);
            a1 = fmaf(qa.w, e2r[kb + 3], a1);
            c1 = fmaf(qb.w, e2r[kb + 3], c1);
        }
        float eA = sspf(a0 + a1), eB = sspf(c0 + c1);
        atomicAdd(&acc[(size_t)ci0 * 64 + lane], hv0 * eA);
        atomicAdd(&acc[(size_t)ci1 * 64 + lane], hv1 * eB);
    }
}

// ---------------- per-net scalar precompute: 6 dots per net ----------------
// tab[n*8 + {0:d0, 1:a0, 2:d1, 3:a1, 4:nd, 5:na}]
__global__ __launch_bounds__(256) void k_net_scalars(
    const float* __restrict__ hnet2,
    const float* __restrict__ ndw, const float* __restrict__ naw,   // [128]
    const float* __restrict__ pdw, const float* __restrict__ paw,   // [136]
    float* __restrict__ tab) {
    int tid = threadIdx.x, lane = tid & 63, w = tid >> 6;
    float wd0 = ndw[lane], wd1 = ndw[64 + lane];
    float wa0 = naw[lane], wa1 = naw[64 + lane];
    float wpd = pdw[lane], wpa = paw[lane];
    int wave = blockIdx.x * 4 + w, nw = gridDim.x * 4;
    for (int r = wave; r < NNET; r += nw) {
        float h = hnet2[(size_t)r * 64 + lane];
        float s0 = h * wd0, s1 = h * wd1, s2 = h * wa0, s3 = h * wa1;
        float s4 = h * wpd, s5 = h * wpa;
        for (int off = 32; off > 0; off >>= 1) {
            s0 += __shfl_down(s0, off, 64); s1 += __shfl_down(s1, off, 64);
            s2 += __shfl_down(s2, off, 64); s3 += __shfl_down(s3, off, 64);
            s4 += __shfl_down(s4, off, 64); s5 += __shfl_down(s5, off, 64);
        }
        if (lane == 0) {
            float* t = tab + (size_t)r * 8;
            t[0] = s0; t[1] = s2; t[2] = s1; t[3] = s3; t[4] = s4; t[5] = s5;
        }
    }
}

// ---------------- per-cell scalar precompute: 2 dots per cell ----------------
__global__ __launch_bounds__(256) void k_cell_scalars(
    const float* __restrict__ hcell2,
    const float* __restrict__ pdw, const float* __restrict__ paw,   // [136], use [72:136]
    float* __restrict__ tab) {   // [NCELL*2]
    int tid = threadIdx.x, lane = tid & 63, w = tid >> 6;
    float wd = pdw[72 + lane], wa = paw[72 + lane];
    int wave = blockIdx.x * 4 + w, nw = gridDim.x * 4;
    for (int r = wave; r < NCELL; r += nw) {
        float h = hcell2[(size_t)r * 64 + lane];
        float s0 = h * wd, s1 = h * wa;
        for (int off = 32; off > 0; off >>= 1) {
            s0 += __shfl_down(s0, off, 64);
            s1 += __shfl_down(s1, off, 64);
        }
        if (lane == 0) {
            tab[(size_t)r * 2] = s0;
            tab[(size_t)r * 2 + 1] = s1;
        }
    }
}

// ---------------- pair readout: one lane per pair ----------------
__global__ __launch_bounds__(256) void k_pair(
    const int* __restrict__ pairs, const float* __restrict__ tab,
    const float* __restrict__ bd, const float* __restrict__ ba,
    float* __restrict__ od, float* __restrict__ oa) {
    int i = blockIdx.x * blockDim.x + threadIdx.x;
    if (i >= NPAIR) return;
    int p0 = pairs[2 * i], p1 = pairs[2 * i + 1];
    float2 x0 = *(const float2*)(tab + (size_t)p0 * 8);       // d0, a0
    float2 x1 = *(const float2*)(tab + (size_t)p1 * 8 + 2);   // d1, a1
    od[i] = softplusf(x0.x + x1.x + bd[0]);
    oa[i] = x0.y + x1.y + ba[0];
}

// ---------------- pin readout: one lane per pin ----------------
__global__ __launch_bounds__(256) void k_pinro(
    const float* __restrict__ pin_feat,
    const int* __restrict__ pin_net, const int* __restrict__ pin_cell,
    const float* __restrict__ ntab, const float* __restrict__ ctab,
    const float* __restrict__ plw, const float* __restrict__ plb,   // [8,8],[8]
    const float* __restrict__ pdw, const float* __restrict__ paw,   // [136]
    const float* __restrict__ bd, const float* __restrict__ ba,
    float* __restrict__ od, float* __restrict__ oa) {
    int p = blockIdx.x * blockDim.x + threadIdx.x;
    if (p >= NPIN) return;
    int n = pin_net[p], c = pin_cell[p];
    float2 ns = *(const float2*)(ntab + (size_t)n * 8 + 4);   // nd, na
    float2 cs = *(const float2*)(ctab + (size_t)c * 2);       // cd, ca
    float pf[8];
    *(float4*)pf = *(const float4*)(pin_feat + (size_t)p * 8);
    *(float4*)(pf + 4) = *(const float4*)(pin_feat + (size_t)p * 8 + 4);
    float sd = ns.x + cs.x + bd[0];
    float sa = ns.y + cs.y + ba[0];
#pragma unroll
    for (int j = 0; j < 8; j++) {
        float a = plb[j];
#pragma unroll
        for (int k = 0; k < 8; k++) a = fmaf(pf[k], plw[k * 8 + j], a);
        float hp = tanhf(a);
        sd = fmaf(hp, pdw[64 + j], sd);
        sa = fmaf(hp, paw[64 + j], sa);
    }
    od[p] = softplusf(sd);
    oa[p] = sa;
}

extern "C" void kernel_launch(void* const* d_in, const int* in_sizes, int n_in,
                              void* d_out, int out_size, void* d_ws, size_t ws_size,
                              hipStream_t stream) {
    const float* cell_feat = (const float*)d_in[0];
    const float* net_feat  = (const float*)d_in[1];
    const float* pin_feat  = (const float*)d_in[2];
    const float* cell_lin_w = (const float*)d_in[3];
    const float* cell_lin_b = (const float*)d_in[4];
    const float* net_lin_w  = (const float*)d_in[5];
    const float* net_lin_b  = (const float*)d_in[6];
    const float* pin_lin_w  = (const float*)d_in[7];
    const float* pin_lin_b  = (const float*)d_in[8];
    const float* pins_w   = (const float*)d_in[9];
    const float* pins_b   = (const float*)d_in[10];
    const float* father_w = (const float*)d_in[11];
    const float* father_b = (const float*)d_in[12];
    const float* son_w    = (const float*)d_in[13];
    const float* son_b    = (const float*)d_in[14];
    const float* cf_node_w = (const float*)d_in[15];
    const float* cf_node_b = (const float*)d_in[16];
    const float* cf_e1_w  = (const float*)d_in[17];
    const float* cf_e1_b  = (const float*)d_in[18];
    const float* cf_e2_w  = (const float*)d_in[19];
    const float* cf_e2_b  = (const float*)d_in[20];
    const float* cf_out_w = (const float*)d_in[21];
    const float* cf_out_b = (const float*)d_in[22];
    const float* net_dis_w   = (const float*)d_in[23];
    const float* net_dis_b   = (const float*)d_in[24];
    const float* net_angle_w = (const float*)d_in[25];
    const float* net_angle_b = (const float*)d_in[26];
    const float* pin_dis_w   = (const float*)d_in[27];
    const float* pin_dis_b   = (const float*)d_in[28];
    const float* pin_angle_w = (const float*)d_in[29];
    const float* pin_angle_b = (const float*)d_in[30];
    const int* pin_net = (const int*)d_in[31];
    const int* pin_cell = (const int*)d_in[32];
    const int* nn_src = (const int*)d_in[33];
    const int* nn_dst = (const int*)d_in[34];
    const int* pairs = (const int*)d_in[35];

    float* ws = (float*)d_ws;
    const size_t SZ = (size_t)NNET * 64;  // 6.4M floats
    float* h_cell = ws;                // later reused for hv
    float* h_net  = ws + SZ;
    float* bufA   = ws + 2 * SZ;       // accP, later acc_cell
    float* bufB   = ws + 3 * SZ;       // accF, later h_cell2
    float* bufC   = ws + 4 * SZ;       // accS, later ntab/ctab
    float* h_net2 = ws + 5 * SZ;
    float* deg    = ws + 6 * SZ;       // 4 * NNET
    float* rC  = deg;
    float* rNp = deg + NNET;
    float* rS  = deg + 2 * NNET;
    float* rD  = deg + 3 * NNET;
    float* ntab = bufC;                       // NNET*8 floats (valid after combine)
    float* ctab = bufC + (size_t)NNET * 8;    // NCELL*2 floats

    const int GS = 2048;   // grid-stride kernels without reg pressure
    const int GSW = 1024;  // weight-resident kernels: 4 wg/CU exactly

    hipMemsetAsync(bufA, 0, 3 * SZ * sizeof(float), stream);   // accP, accF, accS
    hipMemsetAsync(deg, 0, 4 * NNET * sizeof(float), stream);

    k_degrees<<<(NPIN + 255) / 256, 256, 0, stream>>>(pin_cell, pin_net, nn_src, nn_dst,
                                                      rC, rNp, rS, rD);
    k_deg_fin<<<(4 * NNET + 255) / 256, 256, 0, stream>>>(deg);

    k_lin16<<<GS, 256, 0, stream>>>(cell_feat, cell_lin_w, cell_lin_b, h_cell, NCELL);
    k_lin16<<<GS, 256, 0, stream>>>(net_feat, net_lin_w, net_lin_b, h_net, NNET);

    // GraphConv message accumulation
    k_scatter_edge<<<GS, 256, 0, stream>>>(pin_cell, pin_net, h_cell, rC, bufA, NPIN);
    k_scatter_edge<<<GS, 256, 0, stream>>>(nn_src, nn_dst, h_net, rS, bufB, NNN);
    k_scatter_edge<<<GS, 256, 0, stream>>>(nn_dst, nn_src, h_net, rD, bufC, NNN);

    // h_net2 = max over 3 relations of (msg * cd) @ W + b
    k_mm64<0><<<GSW, 256, 0, stream>>>(bufA, rNp, pins_w, pins_b, h_net2, NNET);
    k_mm64<2><<<GSW, 256, 0, stream>>>(bufB, rD, father_w, father_b, h_net2, NNET);
    k_mm64<2><<<GSW, 256, 0, stream>>>(bufC, rS, son_w, son_b, h_net2, NNET);

    // hv = h_net @ cf_node_w + b   (into h_cell buffer, no longer needed)
    k_mm64<0><<<GSW, 256, 0, stream>>>(h_net, nullptr, cf_node_w, cf_node_b, h_cell, NNET);

    hipMemsetAsync(bufA, 0, SZ * sizeof(float), stream);       // acc_cell
    k_cfconv<<<GSW, 256, 0, stream>>>(pin_feat, cf_e1_w, cf_e1_b, cf_e2_w, cf_e2_b,
                                      h_cell, pin_net, pin_cell, bufA);
    // h_cell2 = ssp(acc_cell @ cf_out_w + b)
    k_mm64<1><<<GSW, 256, 0, stream>>>(bufA, nullptr, cf_out_w, cf_out_b, bufB, NCELL);

    // readout scalar precompute
    k_net_scalars<<<GS, 256, 0, stream>>>(h_net2, net_dis_w, net_angle_w,
                                          pin_dis_w, pin_angle_w, ntab);
    k_cell_scalars<<<GS, 256, 0, stream>>>(bufB, pin_dis_w, pin_angle_w, ctab);

    float* out = (float*)d_out;
    k_pair<<<(NPAIR + 255) / 256, 256, 0, stream>>>(pairs, ntab, net_dis_b, net_angle_b,
                                                    out, out + NPAIR);
    k_pinro<<<(NPIN + 255) / 256, 256, 0, stream>>>(pin_feat, pin_net, pin_cell,
                                                    ntab, ctab, pin_lin_w, pin_lin_b,
                                                    pin_dis_w, pin_angle_w,
                                                    pin_dis_b, pin_angle_b,
                                                    out + 2 * NPAIR, out + 2 * NPAIR + NPIN);
}

// Round 4
// 552.418 us; speedup vs baseline: 2.2288x; 1.3734x over previous
//
#include <hip/hip_runtime.h>
#include <math.h>

#define NCELL 100000
#define NNET  100000
#define NPIN  500000
#define NNN   200000
#define NPAIR 500000

typedef __attribute__((ext_vector_type(8))) short short8;
typedef __attribute__((ext_vector_type(4))) float f32x4;

union U16x8 { uint4 u; short8 s; };

__device__ __forceinline__ unsigned short f2bf(float x) {
    union { float f; unsigned u; } v; v.f = x;
    unsigned r = (v.u + 0x7FFF + ((v.u >> 16) & 1)) >> 16;   // RNE
    return (unsigned short)r;
}

__device__ __forceinline__ float softplusf(float x) {
    // max(x,0) + log1p(exp(-|x|)) with fast hw transcendentals
    return fmaxf(x, 0.f) + __logf(1.f + __expf(-fabsf(x)));
}
__device__ __forceinline__ float sspf(float x) {
    return softplusf(x) - 0.69314718055994530942f;
}

// B-fragment for mfma_f32_16x16x32_bf16: B[k][n], lane holds n=nt*16+(l&15),
// k = kt*32 + (l>>4)*8 + j  (W row-major [64][64])
__device__ __forceinline__ short8 load_bfrag(const float* __restrict__ W,
                                             int kt, int nt, int lane) {
    int k0 = kt * 32 + ((lane >> 4) & 3) * 8;
    int c = nt * 16 + (lane & 15);
    short8 f;
#pragma unroll
    for (int j = 0; j < 8; j++) f[j] = (short)f2bf(W[(k0 + j) * 64 + c]);
    return f;
}

// A-fragment: A[m][k], lane holds m=(l&15) (row pointer given), k contiguous 8
__device__ __forceinline__ short8 load_afrag(const float* __restrict__ rowbase,
                                             int kt, int lane, float s) {
    int off = kt * 32 + ((lane >> 4) & 3) * 8;
    float4 q0 = *(const float4*)(rowbase + off);
    float4 q1 = *(const float4*)(rowbase + off + 4);
    short8 a;
    a[0] = (short)f2bf(q0.x * s); a[1] = (short)f2bf(q0.y * s);
    a[2] = (short)f2bf(q0.z * s); a[3] = (short)f2bf(q0.w * s);
    a[4] = (short)f2bf(q1.x * s); a[5] = (short)f2bf(q1.y * s);
    a[6] = (short)f2bf(q1.z * s); a[7] = (short)f2bf(q1.w * s);
    return a;
}

// ---------------- degree computation ----------------
__global__ void k_degrees(const int* __restrict__ pin_cell, const int* __restrict__ pin_net,
                          const int* __restrict__ nn_src, const int* __restrict__ nn_dst,
                          float* degC, float* degNp, float* degS, float* degD) {
    int i = blockIdx.x * blockDim.x + threadIdx.x;
    if (i < NPIN) {
        atomicAdd(&degC[pin_cell[i]], 1.f);
        atomicAdd(&degNp[pin_net[i]], 1.f);
    }
    if (i < NNN) {
        atomicAdd(&degS[nn_src[i]], 1.f);
        atomicAdd(&degD[nn_dst[i]], 1.f);
    }
}

__global__ void k_deg_fin(float* deg) {
    int i = blockIdx.x * blockDim.x + threadIdx.x;
    if (i < 4 * NNET) deg[i] = rsqrtf(fmaxf(deg[i], 1.f));
}

// ---------------- [n,16] @ [16,64] + b, tanh, optional row-scale fold ----------------
__global__ __launch_bounds__(256) void k_lin16(
    const float* __restrict__ in, const float* __restrict__ W,
    const float* __restrict__ b, const float* __restrict__ scale,
    float* __restrict__ out, int n) {
    int tid = threadIdx.x, lane = tid & 63, w = tid >> 6;
    float wr[16];
#pragma unroll
    for (int k = 0; k < 16; k++) wr[k] = W[k * 64 + lane];
    float bias = b[lane];
    int wave = blockIdx.x * 4 + w, nw = gridDim.x * 4;
    for (int r = wave; r < n; r += nw) {
        const float4* ip = (const float4*)(in + (size_t)r * 16);
        float4 a = ip[0], bv = ip[1], c = ip[2], d = ip[3];
        float acc = bias;
        acc = fmaf(a.x, wr[0], acc);  acc = fmaf(a.y, wr[1], acc);
        acc = fmaf(a.z, wr[2], acc);  acc = fmaf(a.w, wr[3], acc);
        acc = fmaf(bv.x, wr[4], acc); acc = fmaf(bv.y, wr[5], acc);
        acc = fmaf(bv.z, wr[6], acc); acc = fmaf(bv.w, wr[7], acc);
        acc = fmaf(c.x, wr[8], acc);  acc = fmaf(c.y, wr[9], acc);
        acc = fmaf(c.z, wr[10], acc); acc = fmaf(c.w, wr[11], acc);
        acc = fmaf(d.x, wr[12], acc); acc = fmaf(d.y, wr[13], acc);
        acc = fmaf(d.z, wr[14], acc); acc = fmaf(d.w, wr[15], acc);
        float sc = scale ? scale[r] : 1.f;
        out[(size_t)r * 64 + lane] = tanhf(acc) * sc;
    }
}

// ---------------- pin scatter: acc[dst] += h[src] (h pre-scaled); 2 edges/iter ----------------
__global__ __launch_bounds__(256) void k_scatter_edge(
    const int* __restrict__ src, const int* __restrict__ dst,
    const float* __restrict__ h, float* __restrict__ acc, int nedge) {
    int lane = threadIdx.x & 63;
    int wave = blockIdx.x * 4 + (threadIdx.x >> 6), nw = gridDim.x * 4;
    for (int e = wave * 2; e < nedge; e += nw * 2) {
        int s0 = src[e], s1 = src[e + 1];
        int d0 = dst[e], d1 = dst[e + 1];
        float h0 = h[(size_t)s0 * 64 + lane];
        float h1 = h[(size_t)s1 * 64 + lane];
        atomicAdd(&acc[(size_t)d0 * 64 + lane], h0);
        atomicAdd(&acc[(size_t)d1 * 64 + lane], h1);
    }
}

// ---------------- fused net<->net scatters (father + son); 2 edges/iter ----------------
__global__ __launch_bounds__(256) void k_scatter_nn(
    const int* __restrict__ nn_src, const int* __restrict__ nn_dst,
    const float* __restrict__ h, const float* __restrict__ rS, const float* __restrict__ rD,
    float* __restrict__ accF, float* __restrict__ accS) {
    int lane = threadIdx.x & 63;
    int wave = blockIdx.x * 4 + (threadIdx.x >> 6), nw = gridDim.x * 4;
    for (int e = wave * 2; e < NNN; e += nw * 2) {
        int s0 = nn_src[e], s1 = nn_src[e + 1];
        int d0 = nn_dst[e], d1 = nn_dst[e + 1];
        float rs0 = rS[s0], rs1 = rS[s1];
        float rd0 = rD[d0], rd1 = rD[d1];
        float hs0 = h[(size_t)s0 * 64 + lane] * rs0;
        float hs1 = h[(size_t)s1 * 64 + lane] * rs1;
        float hd0 = h[(size_t)d0 * 64 + lane] * rd0;
        float hd1 = h[(size_t)d1 * 64 + lane] * rd1;
        atomicAdd(&accF[(size_t)d0 * 64 + lane], hs0);
        atomicAdd(&accS[(size_t)s0 * 64 + lane], hd0);
        atomicAdd(&accF[(size_t)d1 * 64 + lane], hs1);
        atomicAdd(&accS[(size_t)s1 * 64 + lane], hd1);
    }
}

// ---------------- fused 3-relation combine via MFMA: out = max_rel((A*s)@W + b) ----------------
__global__ __launch_bounds__(256, 2) void k_combine3(
    const float* __restrict__ A0, const float* __restrict__ s0,
    const float* __restrict__ W0, const float* __restrict__ b0,
    const float* __restrict__ A1, const float* __restrict__ s1,
    const float* __restrict__ W1, const float* __restrict__ b1,
    const float* __restrict__ A2, const float* __restrict__ s2,
    const float* __restrict__ W2, const float* __restrict__ b2,
    float* __restrict__ out, int n) {
    int tid = threadIdx.x, lane = tid & 63, w = tid >> 6;
    const float* Ws[3] = {W0, W1, W2};
    const float* bs[3] = {b0, b1, b2};
    const float* As[3] = {A0, A1, A2};
    const float* ss[3] = {s0, s1, s2};
    short8 Bf[3][2][4];
    float bias[3][4];
#pragma unroll
    for (int rel = 0; rel < 3; rel++) {
#pragma unroll
        for (int kt = 0; kt < 2; kt++)
#pragma unroll
            for (int nt = 0; nt < 4; nt++) Bf[rel][kt][nt] = load_bfrag(Ws[rel], kt, nt, lane);
#pragma unroll
        for (int nt = 0; nt < 4; nt++) bias[rel][nt] = bs[rel][nt * 16 + (lane & 15)];
    }
    int wave = blockIdx.x * 4 + w, nwave = gridDim.x * 4;
    int ntile = n >> 4;
    f32x4 z = {0.f, 0.f, 0.f, 0.f};
    for (int t = wave; t < ntile; t += nwave) {
        int R = t << 4;
        int rowA = R + (lane & 15);
        f32x4 res[4];
#pragma unroll
        for (int rel = 0; rel < 3; rel++) {
            float sc = ss[rel][rowA];
            const float* rb = As[rel] + (size_t)rowA * 64;
            short8 a0 = load_afrag(rb, 0, lane, sc);
            short8 a1 = load_afrag(rb, 1, lane, sc);
#pragma unroll
            for (int nt = 0; nt < 4; nt++) {
                f32x4 acc = __builtin_amdgcn_mfma_f32_16x16x32_bf16(a0, Bf[rel][0][nt], z, 0, 0, 0);
                acc = __builtin_amdgcn_mfma_f32_16x16x32_bf16(a1, Bf[rel][1][nt], acc, 0, 0, 0);
                if (rel == 0) {
#pragma unroll
                    for (int r = 0; r < 4; r++) res[nt][r] = acc[r] + bias[0][nt];
                } else {
#pragma unroll
                    for (int r = 0; r < 4; r++) res[nt][r] = fmaxf(res[nt][r], acc[r] + bias[rel][nt]);
                }
            }
        }
#pragma unroll
        for (int nt = 0; nt < 4; nt++)
#pragma unroll
            for (int r = 0; r < 4; r++)
                out[(size_t)(R + ((lane >> 4) & 3) * 4 + r) * 64 + nt * 16 + (lane & 15)] = res[nt][r];
    }
}

// ---------------- generic [n,64] @ [64,64] + b via MFMA; ACT: 0 none, 1 ssp ----------------
template <int ACT>
__global__ __launch_bounds__(256, 3) void k_mm64f(
    const float* __restrict__ in, const float* __restrict__ W,
    const float* __restrict__ b, float* __restrict__ out, int n) {
    int tid = threadIdx.x, lane = tid & 63, w = tid >> 6;
    short8 Bf[2][4];
    float bias[4];
#pragma unroll
    for (int kt = 0; kt < 2; kt++)
#pragma unroll
        for (int nt = 0; nt < 4; nt++) Bf[kt][nt] = load_bfrag(W, kt, nt, lane);
#pragma unroll
    for (int nt = 0; nt < 4; nt++) bias[nt] = b[nt * 16 + (lane & 15)];
    int wave = blockIdx.x * 4 + w, nwave = gridDim.x * 4;
    int ntile = n >> 4;
    f32x4 z = {0.f, 0.f, 0.f, 0.f};
    for (int t = wave; t < ntile; t += nwave) {
        int R = t << 4;
        const float* rb = in + (size_t)(R + (lane & 15)) * 64;
        short8 a0 = load_afrag(rb, 0, lane, 1.f);
        short8 a1 = load_afrag(rb, 1, lane, 1.f);
#pragma unroll
        for (int nt = 0; nt < 4; nt++) {
            f32x4 acc = __builtin_amdgcn_mfma_f32_16x16x32_bf16(a0, Bf[0][nt], z, 0, 0, 0);
            acc = __builtin_amdgcn_mfma_f32_16x16x32_bf16(a1, Bf[1][nt], acc, 0, 0, 0);
#pragma unroll
            for (int r = 0; r < 4; r++) {
                float v = acc[r] + bias[nt];
                if (ACT == 1) v = sspf(v);
                out[(size_t)(R + ((lane >> 4) & 3) * 4 + r) * 64 + nt * 16 + (lane & 15)] = v;
            }
        }
    }
}

// ---------------- CFConv via MFMA: e-MLP (8->64 ssp, 64->64 ssp) + gather/scatter ----------------
__global__ __launch_bounds__(256, 3) void k_cfconvf(
    const float* __restrict__ pin_feat,
    const float* __restrict__ E1, const float* __restrict__ b1,
    const float* __restrict__ E2, const float* __restrict__ b2,
    const float* __restrict__ hv,
    const int* __restrict__ pin_net, const int* __restrict__ pin_cell,
    float* __restrict__ acc) {
    __shared__ __align__(16) unsigned short sm[4][1024];   // [wave][16 rows][64 cols] bf16, swizzled
    int tid = threadIdx.x, lane = tid & 63, w = tid >> 6;
    // B1: E1 [8][64] zero-padded to K=32 (only k<8 real -> lanes with (l>>4)==0)
    short8 B1[4];
#pragma unroll
    for (int nt = 0; nt < 4; nt++) {
        short8 f = {0, 0, 0, 0, 0, 0, 0, 0};
        if (lane < 16) {
            int c = nt * 16 + (lane & 15);
#pragma unroll
            for (int j = 0; j < 8; j++) f[j] = (short)f2bf(E1[j * 64 + c]);
        }
        B1[nt] = f;
    }
    short8 B2[2][4];
#pragma unroll
    for (int kt = 0; kt < 2; kt++)
#pragma unroll
        for (int nt = 0; nt < 4; nt++) B2[kt][nt] = load_bfrag(E2, kt, nt, lane);
    float bb1[4], bb2[4];
#pragma unroll
    for (int nt = 0; nt < 4; nt++) {
        bb1[nt] = b1[nt * 16 + (lane & 15)];
        bb2[nt] = b2[nt * 16 + (lane & 15)];
    }
    int wave = blockIdx.x * 4 + w, nwave = gridDim.x * 4;
    const int ntile = NPIN >> 4;
    f32x4 z = {0.f, 0.f, 0.f, 0.f};
    for (int t = wave; t < ntile; t += nwave) {
        int P = t << 4;
        // GEMM1: A1 = pin_feat[16 pins][8] zero-padded
        short8 a1 = {0, 0, 0, 0, 0, 0, 0, 0};
        if (lane < 16) {
            const float4* q = (const float4*)(pin_feat + (size_t)(P + lane) * 8);
            float4 u0 = q[0], u1 = q[1];
            a1[0] = (short)f2bf(u0.x); a1[1] = (short)f2bf(u0.y);
            a1[2] = (short)f2bf(u0.z); a1[3] = (short)f2bf(u0.w);
            a1[4] = (short)f2bf(u1.x); a1[5] = (short)f2bf(u1.y);
            a1[6] = (short)f2bf(u1.z); a1[7] = (short)f2bf(u1.w);
        }
        // ssp(t1) -> LDS (bf16, XOR-swizzled), C-layout -> A-layout transpose
#pragma unroll
        for (int nt = 0; nt < 4; nt++) {
            f32x4 c1 = __builtin_amdgcn_mfma_f32_16x16x32_bf16(a1, B1[nt], z, 0, 0, 0);
#pragma unroll
            for (int r = 0; r < 4; r++) {
                int row = ((lane >> 4) & 3) * 4 + r;
                int col = nt * 16 + (lane & 15);
                float v = sspf(c1[r] + bb1[nt]);
                sm[w][row * 64 + (col ^ ((row & 7) << 3))] = f2bf(v);
            }
        }
        // GEMM2: read A2 frags from LDS
        int row2 = lane & 15;
        short8 a2[2];
#pragma unroll
        for (int kt = 0; kt < 2; kt++) {
            int idx = row2 * 64 + ((kt * 32 + ((lane >> 4) & 3) * 8) ^ ((row2 & 7) << 3));
            U16x8 cv;
            cv.u = *(const uint4*)&sm[w][idx];
            a2[kt] = cv.s;
        }
        f32x4 ef[4];
#pragma unroll
        for (int nt = 0; nt < 4; nt++) {
            f32x4 e = __builtin_amdgcn_mfma_f32_16x16x32_bf16(a2[0], B2[0][nt], z, 0, 0, 0);
            e = __builtin_amdgcn_mfma_f32_16x16x32_bf16(a2[1], B2[1][nt], e, 0, 0, 0);
#pragma unroll
            for (int r = 0; r < 4; r++) ef[nt][r] = sspf(e[r] + bb2[nt]);
        }
        // gather hv rows, scatter into cell accumulator
#pragma unroll
        for (int r = 0; r < 4; r++) {
            int p = P + ((lane >> 4) & 3) * 4 + r;
            int ni = pin_net[p], ci = pin_cell[p];
            const float* hvr = hv + (size_t)ni * 64 + (lane & 15);
            float* ar = acc + (size_t)ci * 64 + (lane & 15);
#pragma unroll
            for (int nt = 0; nt < 4; nt++)
                atomicAdd(ar + nt * 16, hvr[nt * 16] * ef[nt][r]);
        }
    }
}

// ---------------- per-net scalar precompute: 6 dots per net ----------------
__global__ __launch_bounds__(256) void k_net_scalars(
    const float* __restrict__ hnet2,
    const float* __restrict__ ndw, const float* __restrict__ naw,   // [128]
    const float* __restrict__ pdw, const float* __restrict__ paw,   // [136]
    float* __restrict__ tab) {
    int tid = threadIdx.x, lane = tid & 63, w = tid >> 6;
    float wd0 = ndw[lane], wd1 = ndw[64 + lane];
    float wa0 = naw[lane], wa1 = naw[64 + lane];
    float wpd = pdw[lane], wpa = paw[lane];
    int wave = blockIdx.x * 4 + w, nw = gridDim.x * 4;
    for (int r = wave; r < NNET; r += nw) {
        float h = hnet2[(size_t)r * 64 + lane];
        float s0 = h * wd0, s1 = h * wd1, s2 = h * wa0, s3 = h * wa1;
        float s4 = h * wpd, s5 = h * wpa;
        for (int off = 32; off > 0; off >>= 1) {
            s0 += __shfl_down(s0, off, 64); s1 += __shfl_down(s1, off, 64);
            s2 += __shfl_down(s2, off, 64); s3 += __shfl_down(s3, off, 64);
            s4 += __shfl_down(s4, off, 64); s5 += __shfl_down(s5, off, 64);
        }
        if (lane == 0) {
            float* t = tab + (size_t)r * 8;
            t[0] = s0; t[1] = s2; t[2] = s1; t[3] = s3; t[4] = s4; t[5] = s5;
        }
    }
}

// ---------------- per-cell scalar precompute: 2 dots per cell ----------------
__global__ __launch_bounds__(256) void k_cell_scalars(
    const float* __restrict__ hcell2,
    const float* __restrict__ pdw, const float* __restrict__ paw,   // [136], use [72:136]
    float* __restrict__ tab) {
    int tid = threadIdx.x, lane = tid & 63, w = tid >> 6;
    float wd = pdw[72 + lane], wa = paw[72 + lane];
    int wave = blockIdx.x * 4 + w, nw = gridDim.x * 4;
    for (int r = wave; r < NCELL; r += nw) {
        float h = hcell2[(size_t)r * 64 + lane];
        float s0 = h * wd, s1 = h * wa;
        for (int off = 32; off > 0; off >>= 1) {
            s0 += __shfl_down(s0, off, 64);
            s1 += __shfl_down(s1, off, 64);
        }
        if (lane == 0) {
            tab[(size_t)r * 2] = s0;
            tab[(size_t)r * 2 + 1] = s1;
        }
    }
}

// ---------------- pair readout ----------------
__global__ __launch_bounds__(256) void k_pair(
    const int* __restrict__ pairs, const float* __restrict__ tab,
    const float* __restrict__ bd, const float* __restrict__ ba,
    float* __restrict__ od, float* __restrict__ oa) {
    int i = blockIdx.x * blockDim.x + threadIdx.x;
    if (i >= NPAIR) return;
    int p0 = pairs[2 * i], p1 = pairs[2 * i + 1];
    float2 x0 = *(const float2*)(tab + (size_t)p0 * 8);
    float2 x1 = *(const float2*)(tab + (size_t)p1 * 8 + 2);
    od[i] = softplusf(x0.x + x1.x + bd[0]);
    oa[i] = x0.y + x1.y + ba[0];
}

// ---------------- pin readout ----------------
__global__ __launch_bounds__(256) void k_pinro(
    const float* __restrict__ pin_feat,
    const int* __restrict__ pin_net, const int* __restrict__ pin_cell,
    const float* __restrict__ ntab, const float* __restrict__ ctab,
    const float* __restrict__ plw, const float* __restrict__ plb,
    const float* __restrict__ pdw, const float* __restrict__ paw,
    const float* __restrict__ bd, const float* __restrict__ ba,
    float* __restrict__ od, float* __restrict__ oa) {
    int p = blockIdx.x * blockDim.x + threadIdx.x;
    if (p >= NPIN) return;
    int n = pin_net[p], c = pin_cell[p];
    float2 ns = *(const float2*)(ntab + (size_t)n * 8 + 4);
    float2 cs = *(const float2*)(ctab + (size_t)c * 2);
    float pf[8];
    *(float4*)pf = *(const float4*)(pin_feat + (size_t)p * 8);
    *(float4*)(pf + 4) = *(const float4*)(pin_feat + (size_t)p * 8 + 4);
    float sd = ns.x + cs.x + bd[0];
    float sa = ns.y + cs.y + ba[0];
#pragma unroll
    for (int j = 0; j < 8; j++) {
        float a = plb[j];
#pragma unroll
        for (int k = 0; k < 8; k++) a = fmaf(pf[k], plw[k * 8 + j], a);
        float hp = tanhf(a);
        sd = fmaf(hp, pdw[64 + j], sd);
        sa = fmaf(hp, paw[64 + j], sa);
    }
    od[p] = softplusf(sd);
    oa[p] = sa;
}

extern "C" void kernel_launch(void* const* d_in, const int* in_sizes, int n_in,
                              void* d_out, int out_size, void* d_ws, size_t ws_size,
                              hipStream_t stream) {
    const float* cell_feat = (const float*)d_in[0];
    const float* net_feat  = (const float*)d_in[1];
    const float* pin_feat  = (const float*)d_in[2];
    const float* cell_lin_w = (const float*)d_in[3];
    const float* cell_lin_b = (const float*)d_in[4];
    const float* net_lin_w  = (const float*)d_in[5];
    const float* net_lin_b  = (const float*)d_in[6];
    const float* pin_lin_w  = (const float*)d_in[7];
    const float* pin_lin_b  = (const float*)d_in[8];
    const float* pins_w   = (const float*)d_in[9];
    const float* pins_b   = (const float*)d_in[10];
    const float* father_w = (const float*)d_in[11];
    const float* father_b = (const float*)d_in[12];
    const float* son_w    = (const float*)d_in[13];
    const float* son_b    = (const float*)d_in[14];
    const float* cf_node_w = (const float*)d_in[15];
    const float* cf_node_b = (const float*)d_in[16];
    const float* cf_e1_w  = (const float*)d_in[17];
    const float* cf_e1_b  = (const float*)d_in[18];
    const float* cf_e2_w  = (const float*)d_in[19];
    const float* cf_e2_b  = (const float*)d_in[20];
    const float* cf_out_w = (const float*)d_in[21];
    const float* cf_out_b = (const float*)d_in[22];
    const float* net_dis_w   = (const float*)d_in[23];
    const float* net_dis_b   = (const float*)d_in[24];
    const float* net_angle_w = (const float*)d_in[25];
    const float* net_angle_b = (const float*)d_in[26];
    const float* pin_dis_w   = (const float*)d_in[27];
    const float* pin_dis_b   = (const float*)d_in[28];
    const float* pin_angle_w = (const float*)d_in[29];
    const float* pin_angle_b = (const float*)d_in[30];
    const int* pin_net = (const int*)d_in[31];
    const int* pin_cell = (const int*)d_in[32];
    const int* nn_src = (const int*)d_in[33];
    const int* nn_dst = (const int*)d_in[34];
    const int* pairs = (const int*)d_in[35];

    float* ws = (float*)d_ws;
    const size_t SZ = (size_t)NNET * 64;
    float* h_cell = ws;                // pre-scaled by rC; later reused for hv
    float* h_net  = ws + SZ;
    float* bufA   = ws + 2 * SZ;       // accP, later acc_cell
    float* bufB   = ws + 3 * SZ;       // accF, later h_cell2
    float* bufC   = ws + 4 * SZ;       // accS, later ntab/ctab
    float* h_net2 = ws + 5 * SZ;
    float* deg    = ws + 6 * SZ;       // 4 * NNET
    float* rC  = deg;
    float* rNp = deg + NNET;
    float* rS  = deg + 2 * NNET;
    float* rD  = deg + 3 * NNET;
    float* ntab = bufC;
    float* ctab = bufC + (size_t)NNET * 8;

    const int GS  = 2048;  // scatters / elementwise
    const int GMM = 512;   // MFMA row-tile kernels
    const int GCF = 1024;  // cfconv

    hipMemsetAsync(bufA, 0, 3 * SZ * sizeof(float), stream);
    hipMemsetAsync(deg, 0, 4 * NNET * sizeof(float), stream);

    k_degrees<<<(NPIN + 255) / 256, 256, 0, stream>>>(pin_cell, pin_net, nn_src, nn_dst,
                                                      rC, rNp, rS, rD);
    k_deg_fin<<<(4 * NNET + 255) / 256, 256, 0, stream>>>(deg);

    // h_cell folded with out-degree norm (only consumer is the cell->net conv)
    k_lin16<<<GS, 256, 0, stream>>>(cell_feat, cell_lin_w, cell_lin_b, rC, h_cell, NCELL);
    k_lin16<<<GS, 256, 0, stream>>>(net_feat, net_lin_w, net_lin_b, nullptr, h_net, NNET);

    k_scatter_edge<<<GS, 256, 0, stream>>>(pin_cell, pin_net, h_cell, bufA, NPIN);
    k_scatter_nn<<<GS, 256, 0, stream>>>(nn_src, nn_dst, h_net, rS, rD, bufB, bufC);

    k_combine3<<<GMM, 256, 0, stream>>>(bufA, rNp, pins_w, pins_b,
                                        bufB, rD, father_w, father_b,
                                        bufC, rS, son_w, son_b,
                                        h_net2, NNET);

    // hv = h_net @ cf_node_w + b  (h_cell buffer is free now)
    k_mm64f<0><<<GMM, 256, 0, stream>>>(h_net, cf_node_w, cf_node_b, h_cell, NNET);

    hipMemsetAsync(bufA, 0, SZ * sizeof(float), stream);
    k_cfconvf<<<GCF, 256, 0, stream>>>(pin_feat, cf_e1_w, cf_e1_b, cf_e2_w, cf_e2_b,
                                       h_cell, pin_net, pin_cell, bufA);
    k_mm64f<1><<<GMM, 256, 0, stream>>>(bufA, cf_out_w, cf_out_b, bufB, NCELL);

    k_net_scalars<<<GS, 256, 0, stream>>>(h_net2, net_dis_w, net_angle_w,
                                          pin_dis_w, pin_angle_w, ntab);
    k_cell_scalars<<<GS, 256, 0, stream>>>(bufB, pin_dis_w, pin_angle_w, ctab);

    float* out = (float*)d_out;
    k_pair<<<(NPAIR + 255) / 256, 256, 0, stream>>>(pairs, ntab, net_dis_b, net_angle_b,
                                                    out, out + NPAIR);
    k_pinro<<<(NPIN + 255) / 256, 256, 0, stream>>>(pin_feat, pin_net, pin_cell,
                                                    ntab, ctab, pin_lin_w, pin_lin_b,
                                                    pin_dis_w, pin_angle_w,
                                                    pin_dis_b, pin_angle_b,
                                                    out + 2 * NPAIR, out + 2 * NPAIR + NPIN);
}

// Round 5
// 415.311 us; speedup vs baseline: 2.9646x; 1.3301x over previous
//
#include <hip/hip_runtime.h>
#include <math.h>

#define NCELL 100000
#define NNET  100000
#define NPIN  500000
#define NNN   200000
#define NPAIR 500000

typedef __attribute__((ext_vector_type(8))) short short8;
typedef __attribute__((ext_vector_type(4))) float f32x4;
typedef unsigned short u16;
typedef unsigned int u32;

__device__ __forceinline__ u16 f2bf(float x) {
    union { float f; u32 u; } v; v.f = x;
    u32 r = (v.u + 0x7FFF + ((v.u >> 16) & 1)) >> 16;   // RNE
    return (u16)r;
}
__device__ __forceinline__ float bf2f(u16 u) {
    union { u32 u; float f; } v; v.u = ((u32)u) << 16; return v.f;
}
__device__ __forceinline__ u32 pack2(float lo, float hi) {
    return (u32)f2bf(lo) | ((u32)f2bf(hi) << 16);
}
__device__ __forceinline__ u32 scale_pk(u32 h, float sc) {
    return pack2(bf2f((u16)(h & 0xffff)) * sc, bf2f((u16)(h >> 16)) * sc);
}
// packed bf16x2 atomic add (device scope, no return)
__device__ __forceinline__ void pk_add(u16* addr, u32 data) {
    asm volatile("global_atomic_pk_add_bf16 %0, %1, off"
                 :: "v"((unsigned long long)(uintptr_t)addr), "v"(data)
                 : "memory");
}

__device__ __forceinline__ float softplusf(float x) {
    return fmaxf(x, 0.f) + __logf(1.f + __expf(-fabsf(x)));
}
__device__ __forceinline__ float sspf(float x) {
    return softplusf(x) - 0.69314718055994530942f;
}

// B-fragment for mfma_f32_16x16x32_bf16 from row-major f32 W[64][64]
__device__ __forceinline__ short8 load_bfrag(const float* __restrict__ W,
                                             int kt, int nt, int lane) {
    int k0 = kt * 32 + ((lane >> 4) & 3) * 8;
    int c = nt * 16 + (lane & 15);
    short8 f;
#pragma unroll
    for (int j = 0; j < 8; j++) f[j] = (short)f2bf(W[(k0 + j) * 64 + c]);
    return f;
}

// ---------------- degree computation ----------------
__global__ void k_degrees(const int* __restrict__ pin_cell, const int* __restrict__ pin_net,
                          const int* __restrict__ nn_src, const int* __restrict__ nn_dst,
                          float* degC, float* degNp, float* degS, float* degD) {
    int i = blockIdx.x * blockDim.x + threadIdx.x;
    if (i < NPIN) {
        atomicAdd(&degC[pin_cell[i]], 1.f);
        atomicAdd(&degNp[pin_net[i]], 1.f);
    }
    if (i < NNN) {
        atomicAdd(&degS[nn_src[i]], 1.f);
        atomicAdd(&degD[nn_dst[i]], 1.f);
    }
}

__global__ void k_deg_fin(float* deg) {
    int i = blockIdx.x * blockDim.x + threadIdx.x;
    if (i < 4 * NNET) deg[i] = rsqrtf(fmaxf(deg[i], 1.f));
}

// ---------------- [n,16] @ [16,64] + b, tanh, optional row-scale; bf16 out ----------------
__global__ __launch_bounds__(256) void k_lin16(
    const float* __restrict__ in, const float* __restrict__ W,
    const float* __restrict__ b, const float* __restrict__ scale,
    u16* __restrict__ out, int n) {
    int tid = threadIdx.x, lane = tid & 63, w = tid >> 6;
    float wr[16];
#pragma unroll
    for (int k = 0; k < 16; k++) wr[k] = W[k * 64 + lane];
    float bias = b[lane];
    int wave = blockIdx.x * 4 + w, nw = gridDim.x * 4;
    for (int r = wave; r < n; r += nw) {
        const float4* ip = (const float4*)(in + (size_t)r * 16);
        float4 a = ip[0], bv = ip[1], c = ip[2], d = ip[3];
        float acc = bias;
        acc = fmaf(a.x, wr[0], acc);  acc = fmaf(a.y, wr[1], acc);
        acc = fmaf(a.z, wr[2], acc);  acc = fmaf(a.w, wr[3], acc);
        acc = fmaf(bv.x, wr[4], acc); acc = fmaf(bv.y, wr[5], acc);
        acc = fmaf(bv.z, wr[6], acc); acc = fmaf(bv.w, wr[7], acc);
        acc = fmaf(c.x, wr[8], acc);  acc = fmaf(c.y, wr[9], acc);
        acc = fmaf(c.z, wr[10], acc); acc = fmaf(c.w, wr[11], acc);
        acc = fmaf(d.x, wr[12], acc); acc = fmaf(d.y, wr[13], acc);
        acc = fmaf(d.z, wr[14], acc); acc = fmaf(d.w, wr[15], acc);
        float sc = scale ? scale[r] : 1.f;
        float v = tanhf(acc) * sc;
        float vp = __shfl_xor(v, 1, 64);
        if (!(lane & 1))
            *(u32*)(out + (size_t)r * 64 + lane) = pack2(v, vp);
    }
}

// ---------------- fused edge scatter (pins + both nn directions), pk-bf16 atomics ----------------
// half-wave (32 lanes) per edge; edge norms folded in here.
__global__ __launch_bounds__(256) void k_scatter_all(
    const int* __restrict__ pin_cell, const int* __restrict__ pin_net,
    const int* __restrict__ nn_src, const int* __restrict__ nn_dst,
    const u16* __restrict__ h_cell,   // pre-scaled by rC
    const u16* __restrict__ h_net,
    const float* __restrict__ rNp, const float* __restrict__ rS, const float* __restrict__ rD,
    u16* __restrict__ accP, u16* __restrict__ accF, u16* __restrict__ accS) {
    int l32 = threadIdx.x & 31;
    int slot = blockIdx.x * 8 + (threadIdx.x >> 5), nslots = gridDim.x * 8;
    const int NTOT = NPIN + NNN;
    for (int e = slot; e < NTOT; e += nslots) {
        if (e < NPIN) {
            int c = pin_cell[e], n = pin_net[e];
            float sc = rNp[n];
            u32 h = *(const u32*)(h_cell + (size_t)c * 64 + l32 * 2);
            pk_add(accP + (size_t)n * 64 + l32 * 2, scale_pk(h, sc));
        } else {
            int i = e - NPIN;
            int s = nn_src[i], d = nn_dst[i];
            float sc = rS[s] * rD[d];
            u32 hs = *(const u32*)(h_net + (size_t)s * 64 + l32 * 2);
            u32 hd = *(const u32*)(h_net + (size_t)d * 64 + l32 * 2);
            pk_add(accF + (size_t)d * 64 + l32 * 2, scale_pk(hs, sc));
            pk_add(accS + (size_t)s * 64 + l32 * 2, scale_pk(hd, sc));
        }
    }
}

// ---------------- fused 3-relation combine via MFMA: out = max_rel(A@W + b), bf16 in/out ----------------
__global__ __launch_bounds__(256, 2) void k_combine3(
    const u16* __restrict__ A0, const float* __restrict__ W0, const float* __restrict__ b0,
    const u16* __restrict__ A1, const float* __restrict__ W1, const float* __restrict__ b1,
    const u16* __restrict__ A2, const float* __restrict__ W2, const float* __restrict__ b2,
    u16* __restrict__ out, int n) {
    int tid = threadIdx.x, lane = tid & 63, w = tid >> 6;
    const float* Ws[3] = {W0, W1, W2};
    const float* bs[3] = {b0, b1, b2};
    const u16* As[3] = {A0, A1, A2};
    short8 Bf[3][2][4];
    float bias[3][4];
#pragma unroll
    for (int rel = 0; rel < 3; rel++) {
#pragma unroll
        for (int kt = 0; kt < 2; kt++)
#pragma unroll
            for (int nt = 0; nt < 4; nt++) Bf[rel][kt][nt] = load_bfrag(Ws[rel], kt, nt, lane);
#pragma unroll
        for (int nt = 0; nt < 4; nt++) bias[rel][nt] = bs[rel][nt * 16 + (lane & 15)];
    }
    int g = (lane >> 4) & 3;
    int wave = blockIdx.x * 4 + w, nwave = gridDim.x * 4;
    int ntile = n >> 4;
    f32x4 z = {0.f, 0.f, 0.f, 0.f};
    for (int t = wave; t < ntile; t += nwave) {
        int R = t << 4;
        int rowA = R + (lane & 15);
        f32x4 res[4];
#pragma unroll
        for (int rel = 0; rel < 3; rel++) {
            const u16* rb = As[rel] + (size_t)rowA * 64;
            short8 a0 = *(const short8*)(rb + g * 8);
            short8 a1 = *(const short8*)(rb + 32 + g * 8);
#pragma unroll
            for (int nt = 0; nt < 4; nt++) {
                f32x4 acc = __builtin_amdgcn_mfma_f32_16x16x32_bf16(a0, Bf[rel][0][nt], z, 0, 0, 0);
                acc = __builtin_amdgcn_mfma_f32_16x16x32_bf16(a1, Bf[rel][1][nt], acc, 0, 0, 0);
                if (rel == 0) {
#pragma unroll
                    for (int r = 0; r < 4; r++) res[nt][r] = acc[r] + bias[0][nt];
                } else {
#pragma unroll
                    for (int r = 0; r < 4; r++) res[nt][r] = fmaxf(res[nt][r], acc[r] + bias[rel][nt]);
                }
            }
        }
#pragma unroll
        for (int nt = 0; nt < 4; nt++)
#pragma unroll
            for (int r = 0; r < 4; r++) {
                float v = res[nt][r];
                float vp = __shfl_xor(v, 1, 64);
                if (!(lane & 1))
                    *(u32*)(out + (size_t)(R + g * 4 + r) * 64 + nt * 16 + (lane & 15)) = pack2(v, vp);
            }
    }
}

// ---------------- generic [n,64] @ [64,64] + b via MFMA; bf16 in/out; ACT: 0 none, 1 ssp ----------------
template <int ACT>
__global__ __launch_bounds__(256, 3) void k_mm64f(
    const u16* __restrict__ in, const float* __restrict__ W,
    const float* __restrict__ b, u16* __restrict__ out, int n) {
    int tid = threadIdx.x, lane = tid & 63, w = tid >> 6;
    short8 Bf[2][4];
    float bias[4];
#pragma unroll
    for (int kt = 0; kt < 2; kt++)
#pragma unroll
        for (int nt = 0; nt < 4; nt++) Bf[kt][nt] = load_bfrag(W, kt, nt, lane);
#pragma unroll
    for (int nt = 0; nt < 4; nt++) bias[nt] = b[nt * 16 + (lane & 15)];
    int g = (lane >> 4) & 3;
    int wave = blockIdx.x * 4 + w, nwave = gridDim.x * 4;
    int ntile = n >> 4;
    f32x4 z = {0.f, 0.f, 0.f, 0.f};
    for (int t = wave; t < ntile; t += nwave) {
        int R = t << 4;
        const u16* rb = in + (size_t)(R + (lane & 15)) * 64;
        short8 a0 = *(const short8*)(rb + g * 8);
        short8 a1 = *(const short8*)(rb + 32 + g * 8);
#pragma unroll
        for (int nt = 0; nt < 4; nt++) {
            f32x4 acc = __builtin_amdgcn_mfma_f32_16x16x32_bf16(a0, Bf[0][nt], z, 0, 0, 0);
            acc = __builtin_amdgcn_mfma_f32_16x16x32_bf16(a1, Bf[1][nt], acc, 0, 0, 0);
#pragma unroll
            for (int r = 0; r < 4; r++) {
                float v = acc[r] + bias[nt];
                if (ACT == 1) v = sspf(v);
                float vp = __shfl_xor(v, 1, 64);
                if (!(lane & 1))
                    *(u32*)(out + (size_t)(R + g * 4 + r) * 64 + nt * 16 + (lane & 15)) = pack2(v, vp);
            }
        }
    }
}

// ---------------- CFConv via MFMA: e-MLP + gather(bf16 hv) + pk-bf16 scatter ----------------
__global__ __launch_bounds__(256, 3) void k_cfconvf(
    const float* __restrict__ pin_feat,
    const float* __restrict__ E1, const float* __restrict__ b1,
    const float* __restrict__ E2, const float* __restrict__ b2,
    const u16* __restrict__ hv,
    const int* __restrict__ pin_net, const int* __restrict__ pin_cell,
    u16* __restrict__ acc) {
    __shared__ __align__(16) u16 sm[4][1024];
    int tid = threadIdx.x, lane = tid & 63, w = tid >> 6;
    short8 B1[4];
#pragma unroll
    for (int nt = 0; nt < 4; nt++) {
        short8 f = {0, 0, 0, 0, 0, 0, 0, 0};
        if (lane < 16) {
            int c = nt * 16 + (lane & 15);
#pragma unroll
            for (int j = 0; j < 8; j++) f[j] = (short)f2bf(E1[j * 64 + c]);
        }
        B1[nt] = f;
    }
    short8 B2[2][4];
#pragma unroll
    for (int kt = 0; kt < 2; kt++)
#pragma unroll
        for (int nt = 0; nt < 4; nt++) B2[kt][nt] = load_bfrag(E2, kt, nt, lane);
    float bb1[4], bb2[4];
#pragma unroll
    for (int nt = 0; nt < 4; nt++) {
        bb1[nt] = b1[nt * 16 + (lane & 15)];
        bb2[nt] = b2[nt * 16 + (lane & 15)];
    }
    int g = (lane >> 4) & 3;
    int wave = blockIdx.x * 4 + w, nwave = gridDim.x * 4;
    const int ntile = NPIN >> 4;
    f32x4 z = {0.f, 0.f, 0.f, 0.f};
    for (int t = wave; t < ntile; t += nwave) {
        int P = t << 4;
        short8 a1 = {0, 0, 0, 0, 0, 0, 0, 0};
        if (lane < 16) {
            const float4* q = (const float4*)(pin_feat + (size_t)(P + lane) * 8);
            float4 u0 = q[0], u1 = q[1];
            a1[0] = (short)f2bf(u0.x); a1[1] = (short)f2bf(u0.y);
            a1[2] = (short)f2bf(u0.z); a1[3] = (short)f2bf(u0.w);
            a1[4] = (short)f2bf(u1.x); a1[5] = (short)f2bf(u1.y);
            a1[6] = (short)f2bf(u1.z); a1[7] = (short)f2bf(u1.w);
        }
#pragma unroll
        for (int nt = 0; nt < 4; nt++) {
            f32x4 c1 = __builtin_amdgcn_mfma_f32_16x16x32_bf16(a1, B1[nt], z, 0, 0, 0);
#pragma unroll
            for (int r = 0; r < 4; r++) {
                int row = g * 4 + r;
                int col = nt * 16 + (lane & 15);
                float v = sspf(c1[r] + bb1[nt]);
                sm[w][row * 64 + (col ^ ((row & 7) << 3))] = f2bf(v);
            }
        }
        int row2 = lane & 15;
        short8 a2[2];
#pragma unroll
        for (int kt = 0; kt < 2; kt++) {
            int idx = row2 * 64 + ((kt * 32 + g * 8) ^ ((row2 & 7) << 3));
            a2[kt] = *(const short8*)&sm[w][idx];
        }
        f32x4 ef[4];
#pragma unroll
        for (int nt = 0; nt < 4; nt++) {
            f32x4 e = __builtin_amdgcn_mfma_f32_16x16x32_bf16(a2[0], B2[0][nt], z, 0, 0, 0);
            e = __builtin_amdgcn_mfma_f32_16x16x32_bf16(a2[1], B2[1][nt], e, 0, 0, 0);
#pragma unroll
            for (int r = 0; r < 4; r++) ef[nt][r] = sspf(e[r] + bb2[nt]);
        }
#pragma unroll
        for (int r = 0; r < 4; r++) {
            int p = P + g * 4 + r;
            int ni = pin_net[p], ci = pin_cell[p];
            const u16* hvr = hv + (size_t)ni * 64 + (lane & 15);
            u16* ar = acc + (size_t)ci * 64 + (lane & 15);
#pragma unroll
            for (int nt = 0; nt < 4; nt++) {
                float v = bf2f(hvr[nt * 16]) * ef[nt][r];
                float vp = __shfl_xor(v, 1, 64);
                if (!(lane & 1)) pk_add(ar + nt * 16, pack2(v, vp));
            }
        }
    }
}

// ---------------- per-net scalars (bf16 in): 6 dots per net; half-wave per row ----------------
__global__ __launch_bounds__(256) void k_net_scalars(
    const u16* __restrict__ hnet2,
    const float* __restrict__ ndw, const float* __restrict__ naw,   // [128]
    const float* __restrict__ pdw, const float* __restrict__ paw,   // [136]
    float* __restrict__ tab) {
    int tid = threadIdx.x, l32 = tid & 31;
    int c0 = l32 * 2, c1 = c0 + 1;
    float wd0a = ndw[c0], wd0b = ndw[c1], wd1a = ndw[64 + c0], wd1b = ndw[64 + c1];
    float wa0a = naw[c0], wa0b = naw[c1], wa1a = naw[64 + c0], wa1b = naw[64 + c1];
    float wpda = pdw[c0], wpdb = pdw[c1], wpaa = paw[c0], wpab = paw[c1];
    int slot = blockIdx.x * 8 + (tid >> 5), nslots = gridDim.x * 8;
    for (int r = slot; r < NNET; r += nslots) {
        u32 h2 = *(const u32*)(hnet2 + (size_t)r * 64 + c0);
        float ha = bf2f((u16)(h2 & 0xffff)), hb = bf2f((u16)(h2 >> 16));
        float s0 = ha * wd0a + hb * wd0b;
        float s1 = ha * wd1a + hb * wd1b;
        float s2 = ha * wa0a + hb * wa0b;
        float s3 = ha * wa1a + hb * wa1b;
        float s4 = ha * wpda + hb * wpdb;
        float s5 = ha * wpaa + hb * wpab;
        for (int off = 16; off > 0; off >>= 1) {
            s0 += __shfl_down(s0, off, 32); s1 += __shfl_down(s1, off, 32);
            s2 += __shfl_down(s2, off, 32); s3 += __shfl_down(s3, off, 32);
            s4 += __shfl_down(s4, off, 32); s5 += __shfl_down(s5, off, 32);
        }
        if (l32 == 0) {
            float* t = tab + (size_t)r * 8;
            t[0] = s0; t[1] = s2; t[2] = s1; t[3] = s3; t[4] = s4; t[5] = s5;
        }
    }
}

// ---------------- per-cell scalars (bf16 in): 2 dots per cell ----------------
__global__ __launch_bounds__(256) void k_cell_scalars(
    const u16* __restrict__ hcell2,
    const float* __restrict__ pdw, const float* __restrict__ paw,   // [136], use [72:136]
    float* __restrict__ tab) {
    int tid = threadIdx.x, l32 = tid & 31;
    int c0 = l32 * 2, c1 = c0 + 1;
    float wda = pdw[72 + c0], wdb = pdw[72 + c1];
    float waa = paw[72 + c0], wab = paw[72 + c1];
    int slot = blockIdx.x * 8 + (tid >> 5), nslots = gridDim.x * 8;
    for (int r = slot; r < NCELL; r += nslots) {
        u32 h2 = *(const u32*)(hcell2 + (size_t)r * 64 + c0);
        float ha = bf2f((u16)(h2 & 0xffff)), hb = bf2f((u16)(h2 >> 16));
        float s0 = ha * wda + hb * wdb;
        float s1 = ha * waa + hb * wab;
        for (int off = 16; off > 0; off >>= 1) {
            s0 += __shfl_down(s0, off, 32);
            s1 += __shfl_down(s1, off, 32);
        }
        if (l32 == 0) {
            tab[(size_t)r * 2] = s0;
            tab[(size_t)r * 2 + 1] = s1;
        }
    }
}

// ---------------- pair readout ----------------
__global__ __launch_bounds__(256) void k_pair(
    const int* __restrict__ pairs, const float* __restrict__ tab,
    const float* __restrict__ bd, const float* __restrict__ ba,
    float* __restrict__ od, float* __restrict__ oa) {
    int i = blockIdx.x * blockDim.x + threadIdx.x;
    if (i >= NPAIR) return;
    int p0 = pairs[2 * i], p1 = pairs[2 * i + 1];
    float2 x0 = *(const float2*)(tab + (size_t)p0 * 8);
    float2 x1 = *(const float2*)(tab + (size_t)p1 * 8 + 2);
    od[i] = softplusf(x0.x + x1.x + bd[0]);
    oa[i] = x0.y + x1.y + ba[0];
}

// ---------------- pin readout ----------------
__global__ __launch_bounds__(256) void k_pinro(
    const float* __restrict__ pin_feat,
    const int* __restrict__ pin_net, const int* __restrict__ pin_cell,
    const float* __restrict__ ntab, const float* __restrict__ ctab,
    const float* __restrict__ plw, const float* __restrict__ plb,
    const float* __restrict__ pdw, const float* __restrict__ paw,
    const float* __restrict__ bd, const float* __restrict__ ba,
    float* __restrict__ od, float* __restrict__ oa) {
    int p = blockIdx.x * blockDim.x + threadIdx.x;
    if (p >= NPIN) return;
    int n = pin_net[p], c = pin_cell[p];
    float2 ns = *(const float2*)(ntab + (size_t)n * 8 + 4);
    float2 cs = *(const float2*)(ctab + (size_t)c * 2);
    float pf[8];
    *(float4*)pf = *(const float4*)(pin_feat + (size_t)p * 8);
    *(float4*)(pf + 4) = *(const float4*)(pin_feat + (size_t)p * 8 + 4);
    float sd = ns.x + cs.x + bd[0];
    float sa = ns.y + cs.y + ba[0];
#pragma unroll
    for (int j = 0; j < 8; j++) {
        float a = plb[j];
#pragma unroll
        for (int k = 0; k < 8; k++) a = fmaf(pf[k], plw[k * 8 + j], a);
        float hp = tanhf(a);
        sd = fmaf(hp, pdw[64 + j], sd);
        sa = fmaf(hp, paw[64 + j], sa);
    }
    od[p] = softplusf(sd);
    oa[p] = sa;
}

extern "C" void kernel_launch(void* const* d_in, const int* in_sizes, int n_in,
                              void* d_out, int out_size, void* d_ws, size_t ws_size,
                              hipStream_t stream) {
    const float* cell_feat = (const float*)d_in[0];
    const float* net_feat  = (const float*)d_in[1];
    const float* pin_feat  = (const float*)d_in[2];
    const float* cell_lin_w = (const float*)d_in[3];
    const float* cell_lin_b = (const float*)d_in[4];
    const float* net_lin_w  = (const float*)d_in[5];
    const float* net_lin_b  = (const float*)d_in[6];
    const float* pin_lin_w  = (const float*)d_in[7];
    const float* pin_lin_b  = (const float*)d_in[8];
    const float* pins_w   = (const float*)d_in[9];
    const float* pins_b   = (const float*)d_in[10];
    const float* father_w = (const float*)d_in[11];
    const float* father_b = (const float*)d_in[12];
    const float* son_w    = (const float*)d_in[13];
    const float* son_b    = (const float*)d_in[14];
    const float* cf_node_w = (const float*)d_in[15];
    const float* cf_node_b = (const float*)d_in[16];
    const float* cf_e1_w  = (const float*)d_in[17];
    const float* cf_e1_b  = (const float*)d_in[18];
    const float* cf_e2_w  = (const float*)d_in[19];
    const float* cf_e2_b  = (const float*)d_in[20];
    const float* cf_out_w = (const float*)d_in[21];
    const float* cf_out_b = (const float*)d_in[22];
    const float* net_dis_w   = (const float*)d_in[23];
    const float* net_dis_b   = (const float*)d_in[24];
    const float* net_angle_w = (const float*)d_in[25];
    const float* net_angle_b = (const float*)d_in[26];
    const float* pin_dis_w   = (const float*)d_in[27];
    const float* pin_dis_b   = (const float*)d_in[28];
    const float* pin_angle_w = (const float*)d_in[29];
    const float* pin_angle_b = (const float*)d_in[30];
    const int* pin_net = (const int*)d_in[31];
    const int* pin_cell = (const int*)d_in[32];
    const int* nn_src = (const int*)d_in[33];
    const int* nn_dst = (const int*)d_in[34];
    const int* pairs = (const int*)d_in[35];

    u16* ws16 = (u16*)d_ws;
    const size_t SZ = (size_t)NNET * 64;   // u16 elements per row-table
    u16* h_cell = ws16;                // pre-scaled by rC; later reused for hv
    u16* h_net  = ws16 + SZ;
    u16* bufA   = ws16 + 2 * SZ;       // accP, later acc_cell
    u16* bufB   = ws16 + 3 * SZ;       // accF, later h_cell2
    u16* bufC   = ws16 + 4 * SZ;       // accS
    u16* h_net2 = ws16 + 5 * SZ;
    float* deg  = (float*)(ws16 + 6 * SZ);     // 4 * NNET f32
    float* rC  = deg;
    float* rNp = deg + NNET;
    float* rS  = deg + 2 * NNET;
    float* rD  = deg + 3 * NNET;
    float* ntab = deg + 4 * NNET;              // NNET*8 f32
    float* ctab = ntab + (size_t)NNET * 8;     // NCELL*2 f32

    const int GS  = 2048;  // scatters / elementwise
    const int GMM = 512;   // MFMA row-tile kernels
    const int GCF = 1024;  // cfconv

    hipMemsetAsync(bufA, 0, 3 * SZ * sizeof(u16), stream);   // accP, accF, accS
    hipMemsetAsync(deg, 0, 4 * NNET * sizeof(float), stream);

    k_degrees<<<(NPIN + 255) / 256, 256, 0, stream>>>(pin_cell, pin_net, nn_src, nn_dst,
                                                      rC, rNp, rS, rD);
    k_deg_fin<<<(4 * NNET + 255) / 256, 256, 0, stream>>>(deg);

    k_lin16<<<GS, 256, 0, stream>>>(cell_feat, cell_lin_w, cell_lin_b, rC, h_cell, NCELL);
    k_lin16<<<GS, 256, 0, stream>>>(net_feat, net_lin_w, net_lin_b, nullptr, h_net, NNET);

    k_scatter_all<<<GS, 256, 0, stream>>>(pin_cell, pin_net, nn_src, nn_dst,
                                          h_cell, h_net, rNp, rS, rD,
                                          bufA, bufB, bufC);

    k_combine3<<<GMM, 256, 0, stream>>>(bufA, pins_w, pins_b,
                                        bufB, father_w, father_b,
                                        bufC, son_w, son_b,
                                        h_net2, NNET);

    // hv = h_net @ cf_node_w + b  (h_cell buffer is free now)
    k_mm64f<0><<<GMM, 256, 0, stream>>>(h_net, cf_node_w, cf_node_b, h_cell, NNET);

    hipMemsetAsync(bufA, 0, SZ * sizeof(u16), stream);       // acc_cell
    k_cfconvf<<<GCF, 256, 0, stream>>>(pin_feat, cf_e1_w, cf_e1_b, cf_e2_w, cf_e2_b,
                                       h_cell, pin_net, pin_cell, bufA);
    k_mm64f<1><<<GMM, 256, 0, stream>>>(bufA, cf_out_w, cf_out_b, bufB, NCELL);

    k_net_scalars<<<GS, 256, 0, stream>>>(h_net2, net_dis_w, net_angle_w,
                                          pin_dis_w, pin_angle_w, ntab);
    k_cell_scalars<<<GS, 256, 0, stream>>>(bufB, pin_dis_w, pin_angle_w, ctab);

    float* out = (float*)d_out;
    k_pair<<<(NPAIR + 255) / 256, 256, 0, stream>>>(pairs, ntab, net_dis_b, net_angle_b,
                                                    out, out + NPAIR);
    k_pinro<<<(NPIN + 255) / 256, 256, 0, stream>>>(pin_feat, pin_net, pin_cell,
                                                    ntab, ctab, pin_lin_w, pin_lin_b,
                                                    pin_dis_w, pin_angle_w,
                                                    pin_dis_b, pin_angle_b,
                                                    out + 2 * NPAIR, out + 2 * NPAIR + NPIN);
}

// Round 6
// 413.256 us; speedup vs baseline: 2.9793x; 1.0050x over previous
//
#include <hip/hip_runtime.h>
#include <math.h>

#define NCELL 100000
#define NNET  100000
#define NPIN  500000
#define NNN   200000
#define NPAIR 500000

typedef __attribute__((ext_vector_type(8))) short short8;
typedef __attribute__((ext_vector_type(4))) float f32x4;
typedef unsigned short u16;
typedef unsigned int u32;

__device__ __forceinline__ u16 f2bf(float x) {
    union { float f; u32 u; } v; v.f = x;
    u32 r = (v.u + 0x7FFF + ((v.u >> 16) & 1)) >> 16;   // RNE
    return (u16)r;
}
__device__ __forceinline__ float bf2f(u16 u) {
    union { u32 u; float f; } v; v.u = ((u32)u) << 16; return v.f;
}
__device__ __forceinline__ u32 pack2(float lo, float hi) {
    return (u32)f2bf(lo) | ((u32)f2bf(hi) << 16);
}
__device__ __forceinline__ u32 scale_pk(u32 h, float sc) {
    return pack2(bf2f((u16)(h & 0xffff)) * sc, bf2f((u16)(h >> 16)) * sc);
}
// packed bf16x2 atomic add. NOTE: no "memory" clobber — targets are write-only
// accumulators in this kernel; volatile keeps emission + mutual order, and the
// compiler stays free to hoist the next iteration's loads above the atomics.
__device__ __forceinline__ void pk_add(u16* addr, u32 data) {
    asm volatile("global_atomic_pk_add_bf16 %0, %1, off"
                 :: "v"((unsigned long long)(uintptr_t)addr), "v"(data));
}

__device__ __forceinline__ float softplusf(float x) {
    return fmaxf(x, 0.f) + __logf(1.f + __expf(-fabsf(x)));
}
__device__ __forceinline__ float sspf(float x) {
    return softplusf(x) - 0.69314718055994530942f;
}
// fast tanh: (e^2x - 1)/(e^2x + 1), clamped so e^2x can't overflow
__device__ __forceinline__ float ftanh(float x) {
    float xc = fminf(fmaxf(x, -9.f), 9.f);
    float e = __expf(2.f * xc);
    return (e - 1.f) * __builtin_amdgcn_rcpf(e + 1.f);
}

// B-fragment for mfma_f32_16x16x32_bf16 from row-major f32 W[64][64]
__device__ __forceinline__ short8 load_bfrag(const float* __restrict__ W,
                                             int kt, int nt, int lane) {
    int k0 = kt * 32 + ((lane >> 4) & 3) * 8;
    int c = nt * 16 + (lane & 15);
    short8 f;
#pragma unroll
    for (int j = 0; j < 8; j++) f[j] = (short)f2bf(W[(k0 + j) * 64 + c]);
    return f;
}

// ---------------- degree computation ----------------
__global__ void k_degrees(const int* __restrict__ pin_cell, const int* __restrict__ pin_net,
                          const int* __restrict__ nn_src, const int* __restrict__ nn_dst,
                          float* degC, float* degNp, float* degS, float* degD) {
    int i = blockIdx.x * blockDim.x + threadIdx.x;
    if (i < NPIN) {
        atomicAdd(&degC[pin_cell[i]], 1.f);
        atomicAdd(&degNp[pin_net[i]], 1.f);
    }
    if (i < NNN) {
        atomicAdd(&degS[nn_src[i]], 1.f);
        atomicAdd(&degD[nn_dst[i]], 1.f);
    }
}

__global__ void k_deg_fin(float* deg) {
    int i = blockIdx.x * blockDim.x + threadIdx.x;
    if (i < 4 * NNET) deg[i] = rsqrtf(fmaxf(deg[i], 1.f));
}

// ---------------- [n,16] @ [16,64] + b, tanh, optional row-scale; bf16 out ----------------
__global__ __launch_bounds__(256) void k_lin16(
    const float* __restrict__ in, const float* __restrict__ W,
    const float* __restrict__ b, const float* __restrict__ scale,
    u16* __restrict__ out, int n) {
    int tid = threadIdx.x, lane = tid & 63, w = tid >> 6;
    float wr[16];
#pragma unroll
    for (int k = 0; k < 16; k++) wr[k] = W[k * 64 + lane];
    float bias = b[lane];
    int wave = blockIdx.x * 4 + w, nw = gridDim.x * 4;
    for (int r = wave; r < n; r += nw) {
        const float4* ip = (const float4*)(in + (size_t)r * 16);
        float4 a = ip[0], bv = ip[1], c = ip[2], d = ip[3];
        float acc = bias;
        acc = fmaf(a.x, wr[0], acc);  acc = fmaf(a.y, wr[1], acc);
        acc = fmaf(a.z, wr[2], acc);  acc = fmaf(a.w, wr[3], acc);
        acc = fmaf(bv.x, wr[4], acc); acc = fmaf(bv.y, wr[5], acc);
        acc = fmaf(bv.z, wr[6], acc); acc = fmaf(bv.w, wr[7], acc);
        acc = fmaf(c.x, wr[8], acc);  acc = fmaf(c.y, wr[9], acc);
        acc = fmaf(c.z, wr[10], acc); acc = fmaf(c.w, wr[11], acc);
        acc = fmaf(d.x, wr[12], acc); acc = fmaf(d.y, wr[13], acc);
        acc = fmaf(d.z, wr[14], acc); acc = fmaf(d.w, wr[15], acc);
        float sc = scale ? scale[r] : 1.f;
        float v = ftanh(acc) * sc;
        float vp = __shfl_xor(v, 1, 64);
        if (!(lane & 1))
            *(u32*)(out + (size_t)r * 64 + lane) = pack2(v, vp);
    }
}

// ---------------- fused edge scatter (pins + both nn directions), pk-bf16 atomics ----------------
// half-wave (32 lanes) per edge; edge norms folded in here. Two branch-free loops.
__global__ __launch_bounds__(256) void k_scatter_all(
    const int* __restrict__ pin_cell, const int* __restrict__ pin_net,
    const int* __restrict__ nn_src, const int* __restrict__ nn_dst,
    const u16* __restrict__ h_cell,   // pre-scaled by rC
    const u16* __restrict__ h_net,
    const float* __restrict__ rNp, const float* __restrict__ rS, const float* __restrict__ rD,
    u16* __restrict__ accP, u16* __restrict__ accF, u16* __restrict__ accS) {
    int l32 = threadIdx.x & 31;
    int slot = blockIdx.x * 8 + (threadIdx.x >> 5), nslots = gridDim.x * 8;
#pragma unroll 2
    for (int e = slot; e < NPIN; e += nslots) {
        int c = pin_cell[e], n = pin_net[e];
        float sc = rNp[n];
        u32 h = *(const u32*)(h_cell + (size_t)c * 64 + l32 * 2);
        pk_add(accP + (size_t)n * 64 + l32 * 2, scale_pk(h, sc));
    }
#pragma unroll 2
    for (int i = slot; i < NNN; i += nslots) {
        int s = nn_src[i], d = nn_dst[i];
        float sc = rS[s] * rD[d];
        u32 hs = *(const u32*)(h_net + (size_t)s * 64 + l32 * 2);
        u32 hd = *(const u32*)(h_net + (size_t)d * 64 + l32 * 2);
        pk_add(accF + (size_t)d * 64 + l32 * 2, scale_pk(hs, sc));
        pk_add(accS + (size_t)s * 64 + l32 * 2, scale_pk(hd, sc));
    }
}

// ---------------- fused 3-relation combine via MFMA: out = max_rel(A@W + b), bf16 in/out ----------------
__global__ __launch_bounds__(256, 3) void k_combine3(
    const u16* __restrict__ A0, const float* __restrict__ W0, const float* __restrict__ b0,
    const u16* __restrict__ A1, const float* __restrict__ W1, const float* __restrict__ b1,
    const u16* __restrict__ A2, const float* __restrict__ W2, const float* __restrict__ b2,
    u16* __restrict__ out, int n) {
    int tid = threadIdx.x, lane = tid & 63, w = tid >> 6;
    const float* Ws[3] = {W0, W1, W2};
    const float* bs[3] = {b0, b1, b2};
    const u16* As[3] = {A0, A1, A2};
    short8 Bf[3][2][4];
    float bias[3][4];
#pragma unroll
    for (int rel = 0; rel < 3; rel++) {
#pragma unroll
        for (int kt = 0; kt < 2; kt++)
#pragma unroll
            for (int nt = 0; nt < 4; nt++) Bf[rel][kt][nt] = load_bfrag(Ws[rel], kt, nt, lane);
#pragma unroll
        for (int nt = 0; nt < 4; nt++) bias[rel][nt] = bs[rel][nt * 16 + (lane & 15)];
    }
    int g = (lane >> 4) & 3;
    int wave = blockIdx.x * 4 + w, nwave = gridDim.x * 4;
    int ntile = n >> 4;
    f32x4 z = {0.f, 0.f, 0.f, 0.f};
    for (int t = wave; t < ntile; t += nwave) {
        int R = t << 4;
        int rowA = R + (lane & 15);
        f32x4 res[4];
#pragma unroll
        for (int rel = 0; rel < 3; rel++) {
            const u16* rb = As[rel] + (size_t)rowA * 64;
            short8 a0 = *(const short8*)(rb + g * 8);
            short8 a1 = *(const short8*)(rb + 32 + g * 8);
#pragma unroll
            for (int nt = 0; nt < 4; nt++) {
                f32x4 acc = __builtin_amdgcn_mfma_f32_16x16x32_bf16(a0, Bf[rel][0][nt], z, 0, 0, 0);
                acc = __builtin_amdgcn_mfma_f32_16x16x32_bf16(a1, Bf[rel][1][nt], acc, 0, 0, 0);
                if (rel == 0) {
#pragma unroll
                    for (int r = 0; r < 4; r++) res[nt][r] = acc[r] + bias[0][nt];
                } else {
#pragma unroll
                    for (int r = 0; r < 4; r++) res[nt][r] = fmaxf(res[nt][r], acc[r] + bias[rel][nt]);
                }
            }
        }
#pragma unroll
        for (int nt = 0; nt < 4; nt++)
#pragma unroll
            for (int r = 0; r < 4; r++) {
                float v = res[nt][r];
                float vp = __shfl_xor(v, 1, 64);
                if (!(lane & 1))
                    *(u32*)(out + (size_t)(R + g * 4 + r) * 64 + nt * 16 + (lane & 15)) = pack2(v, vp);
            }
    }
}

// ---------------- generic [n,64] @ [64,64] + b via MFMA; bf16 in/out; ACT: 0 none, 1 ssp ----------------
template <int ACT>
__global__ __launch_bounds__(256, 4) void k_mm64f(
    const u16* __restrict__ in, const float* __restrict__ W,
    const float* __restrict__ b, u16* __restrict__ out, int n) {
    int tid = threadIdx.x, lane = tid & 63, w = tid >> 6;
    short8 Bf[2][4];
    float bias[4];
#pragma unroll
    for (int kt = 0; kt < 2; kt++)
#pragma unroll
        for (int nt = 0; nt < 4; nt++) Bf[kt][nt] = load_bfrag(W, kt, nt, lane);
#pragma unroll
    for (int nt = 0; nt < 4; nt++) bias[nt] = b[nt * 16 + (lane & 15)];
    int g = (lane >> 4) & 3;
    int wave = blockIdx.x * 4 + w, nwave = gridDim.x * 4;
    int ntile = n >> 4;
    f32x4 z = {0.f, 0.f, 0.f, 0.f};
    for (int t = wave; t < ntile; t += nwave) {
        int R = t << 4;
        const u16* rb = in + (size_t)(R + (lane & 15)) * 64;
        short8 a0 = *(const short8*)(rb + g * 8);
        short8 a1 = *(const short8*)(rb + 32 + g * 8);
#pragma unroll
        for (int nt = 0; nt < 4; nt++) {
            f32x4 acc = __builtin_amdgcn_mfma_f32_16x16x32_bf16(a0, Bf[0][nt], z, 0, 0, 0);
            acc = __builtin_amdgcn_mfma_f32_16x16x32_bf16(a1, Bf[1][nt], acc, 0, 0, 0);
#pragma unroll
            for (int r = 0; r < 4; r++) {
                float v = acc[r] + bias[nt];
                if (ACT == 1) v = sspf(v);
                float vp = __shfl_xor(v, 1, 64);
                if (!(lane & 1))
                    *(u32*)(out + (size_t)(R + g * 4 + r) * 64 + nt * 16 + (lane & 15)) = pack2(v, vp);
            }
        }
    }
}

// ---------------- CFConv via MFMA: prefetch gathers, e-MLP, pk-bf16 scatter ----------------
__global__ __launch_bounds__(256, 4) void k_cfconvf(
    const float* __restrict__ pin_feat,
    const float* __restrict__ E1, const float* __restrict__ b1,
    const float* __restrict__ E2, const float* __restrict__ b2,
    const u16* __restrict__ hv,
    const int* __restrict__ pin_net, const int* __restrict__ pin_cell,
    u16* __restrict__ acc) {
    __shared__ __align__(16) u16 sm[4][1024];
    int tid = threadIdx.x, lane = tid & 63, w = tid >> 6;
    short8 B1[4];
#pragma unroll
    for (int nt = 0; nt < 4; nt++) {
        short8 f = {0, 0, 0, 0, 0, 0, 0, 0};
        if (lane < 16) {
            int c = nt * 16 + (lane & 15);
#pragma unroll
            for (int j = 0; j < 8; j++) f[j] = (short)f2bf(E1[j * 64 + c]);
        }
        B1[nt] = f;
    }
    short8 B2[2][4];
#pragma unroll
    for (int kt = 0; kt < 2; kt++)
#pragma unroll
        for (int nt = 0; nt < 4; nt++) B2[kt][nt] = load_bfrag(E2, kt, nt, lane);
    float bb1[4], bb2[4];
#pragma unroll
    for (int nt = 0; nt < 4; nt++) {
        bb1[nt] = b1[nt * 16 + (lane & 15)];
        bb2[nt] = b2[nt * 16 + (lane & 15)];
    }
    int g = (lane >> 4) & 3;
    int wave = blockIdx.x * 4 + w, nwave = gridDim.x * 4;
    const int ntile = NPIN >> 4;
    f32x4 z = {0.f, 0.f, 0.f, 0.f};
    for (int t = wave; t < ntile; t += nwave) {
        int P = t << 4;
        // ---- prefetch: indices + hv gather rows (latency hides under the 2 GEMMs) ----
        int ni[4], ci[4];
#pragma unroll
        for (int r = 0; r < 4; r++) {
            int p = P + g * 4 + r;
            ni[r] = pin_net[p];
            ci[r] = pin_cell[p];
        }
        u16 hvp[4][4];
#pragma unroll
        for (int r = 0; r < 4; r++)
#pragma unroll
            for (int nt = 0; nt < 4; nt++)
                hvp[r][nt] = hv[(size_t)ni[r] * 64 + nt * 16 + (lane & 15)];
        // ---- GEMM1: pin_feat[16][8] zero-padded to K=32 ----
        short8 a1 = {0, 0, 0, 0, 0, 0, 0, 0};
        if (lane < 16) {
            const float4* q = (const float4*)(pin_feat + (size_t)(P + lane) * 8);
            float4 u0 = q[0], u1 = q[1];
            a1[0] = (short)f2bf(u0.x); a1[1] = (short)f2bf(u0.y);
            a1[2] = (short)f2bf(u0.z); a1[3] = (short)f2bf(u0.w);
            a1[4] = (short)f2bf(u1.x); a1[5] = (short)f2bf(u1.y);
            a1[6] = (short)f2bf(u1.z); a1[7] = (short)f2bf(u1.w);
        }
#pragma unroll
        for (int nt = 0; nt < 4; nt++) {
            f32x4 c1 = __builtin_amdgcn_mfma_f32_16x16x32_bf16(a1, B1[nt], z, 0, 0, 0);
#pragma unroll
            for (int r = 0; r < 4; r++) {
                int row = g * 4 + r;
                int col = nt * 16 + (lane & 15);
                float v = sspf(c1[r] + bb1[nt]);
                sm[w][row * 64 + (col ^ ((row & 7) << 3))] = f2bf(v);
            }
        }
        // ---- GEMM2: A from LDS (swizzled transpose) ----
        int row2 = lane & 15;
        short8 a2[2];
#pragma unroll
        for (int kt = 0; kt < 2; kt++) {
            int idx = row2 * 64 + ((kt * 32 + g * 8) ^ ((row2 & 7) << 3));
            a2[kt] = *(const short8*)&sm[w][idx];
        }
        f32x4 ef[4];
#pragma unroll
        for (int nt = 0; nt < 4; nt++) {
            f32x4 e = __builtin_amdgcn_mfma_f32_16x16x32_bf16(a2[0], B2[0][nt], z, 0, 0, 0);
            e = __builtin_amdgcn_mfma_f32_16x16x32_bf16(a2[1], B2[1][nt], e, 0, 0, 0);
#pragma unroll
            for (int r = 0; r < 4; r++) ef[nt][r] = sspf(e[r] + bb2[nt]);
        }
        // ---- scatter: hv(prefetched) * e -> acc[cell], pk-bf16 atomics ----
#pragma unroll
        for (int r = 0; r < 4; r++) {
            u16* ar = acc + (size_t)ci[r] * 64 + (lane & 15);
#pragma unroll
            for (int nt = 0; nt < 4; nt++) {
                float v = bf2f(hvp[r][nt]) * ef[nt][r];
                float vp = __shfl_xor(v, 1, 64);
                if (!(lane & 1)) pk_add(ar + nt * 16, pack2(v, vp));
            }
        }
    }
}

// ---------------- per-net scalars (bf16 in): 6 dots per net; half-wave per row ----------------
__global__ __launch_bounds__(256) void k_net_scalars(
    const u16* __restrict__ hnet2,
    const float* __restrict__ ndw, const float* __restrict__ naw,   // [128]
    const float* __restrict__ pdw, const float* __restrict__ paw,   // [136]
    float* __restrict__ tab) {
    int tid = threadIdx.x, l32 = tid & 31;
    int c0 = l32 * 2, c1 = c0 + 1;
    float wd0a = ndw[c0], wd0b = ndw[c1], wd1a = ndw[64 + c0], wd1b = ndw[64 + c1];
    float wa0a = naw[c0], wa0b = naw[c1], wa1a = naw[64 + c0], wa1b = naw[64 + c1];
    float wpda = pdw[c0], wpdb = pdw[c1], wpaa = paw[c0], wpab = paw[c1];
    int slot = blockIdx.x * 8 + (tid >> 5), nslots = gridDim.x * 8;
    for (int r = slot; r < NNET; r += nslots) {
        u32 h2 = *(const u32*)(hnet2 + (size_t)r * 64 + c0);
        float ha = bf2f((u16)(h2 & 0xffff)), hb = bf2f((u16)(h2 >> 16));
        float s0 = ha * wd0a + hb * wd0b;
        float s1 = ha * wd1a + hb * wd1b;
        float s2 = ha * wa0a + hb * wa0b;
        float s3 = ha * wa1a + hb * wa1b;
        float s4 = ha * wpda + hb * wpdb;
        float s5 = ha * wpaa + hb * wpab;
        for (int off = 16; off > 0; off >>= 1) {
            s0 += __shfl_down(s0, off, 32); s1 += __shfl_down(s1, off, 32);
            s2 += __shfl_down(s2, off, 32); s3 += __shfl_down(s3, off, 32);
            s4 += __shfl_down(s4, off, 32); s5 += __shfl_down(s5, off, 32);
        }
        if (l32 == 0) {
            float* t = tab + (size_t)r * 8;
            t[0] = s0; t[1] = s2; t[2] = s1; t[3] = s3; t[4] = s4; t[5] = s5;
        }
    }
}

// ---------------- per-cell scalars (bf16 in): 2 dots per cell ----------------
__global__ __launch_bounds__(256) void k_cell_scalars(
    const u16* __restrict__ hcell2,
    const float* __restrict__ pdw, const float* __restrict__ paw,   // [136], use [72:136]
    float* __restrict__ tab) {
    int tid = threadIdx.x, l32 = tid & 31;
    int c0 = l32 * 2, c1 = c0 + 1;
    float wda = pdw[72 + c0], wdb = pdw[72 + c1];
    float waa = paw[72 + c0], wab = paw[72 + c1];
    int slot = blockIdx.x * 8 + (tid >> 5), nslots = gridDim.x * 8;
    for (int r = slot; r < NCELL; r += nslots) {
        u32 h2 = *(const u32*)(hcell2 + (size_t)r * 64 + c0);
        float ha = bf2f((u16)(h2 & 0xffff)), hb = bf2f((u16)(h2 >> 16));
        float s0 = ha * wda + hb * wdb;
        float s1 = ha * waa + hb * wab;
        for (int off = 16; off > 0; off >>= 1) {
            s0 += __shfl_down(s0, off, 32);
            s1 += __shfl_down(s1, off, 32);
        }
        if (l32 == 0) {
            tab[(size_t)r * 2] = s0;
            tab[(size_t)r * 2 + 1] = s1;
        }
    }
}

// ---------------- pair readout ----------------
__global__ __launch_bounds__(256) void k_pair(
    const int* __restrict__ pairs, const float* __restrict__ tab,
    const float* __restrict__ bd, const float* __restrict__ ba,
    float* __restrict__ od, float* __restrict__ oa) {
    int i = blockIdx.x * blockDim.x + threadIdx.x;
    if (i >= NPAIR) return;
    int p0 = pairs[2 * i], p1 = pairs[2 * i + 1];
    float2 x0 = *(const float2*)(tab + (size_t)p0 * 8);
    float2 x1 = *(const float2*)(tab + (size_t)p1 * 8 + 2);
    od[i] = softplusf(x0.x + x1.x + bd[0]);
    oa[i] = x0.y + x1.y + ba[0];
}

// ---------------- pin readout ----------------
__global__ __launch_bounds__(256) void k_pinro(
    const float* __restrict__ pin_feat,
    const int* __restrict__ pin_net, const int* __restrict__ pin_cell,
    const float* __restrict__ ntab, const float* __restrict__ ctab,
    const float* __restrict__ plw, const float* __restrict__ plb,
    const float* __restrict__ pdw, const float* __restrict__ paw,
    const float* __restrict__ bd, const float* __restrict__ ba,
    float* __restrict__ od, float* __restrict__ oa) {
    int p = blockIdx.x * blockDim.x + threadIdx.x;
    if (p >= NPIN) return;
    int n = pin_net[p], c = pin_cell[p];
    float2 ns = *(const float2*)(ntab + (size_t)n * 8 + 4);
    float2 cs = *(const float2*)(ctab + (size_t)c * 2);
    float pf[8];
    *(float4*)pf = *(const float4*)(pin_feat + (size_t)p * 8);
    *(float4*)(pf + 4) = *(const float4*)(pin_feat + (size_t)p * 8 + 4);
    float sd = ns.x + cs.x + bd[0];
    float sa = ns.y + cs.y + ba[0];
#pragma unroll
    for (int j = 0; j < 8; j++) {
        float a = plb[j];
#pragma unroll
        for (int k = 0; k < 8; k++) a = fmaf(pf[k], plw[k * 8 + j], a);
        float hp = ftanh(a);
        sd = fmaf(hp, pdw[64 + j], sd);
        sa = fmaf(hp, paw[64 + j], sa);
    }
    od[p] = softplusf(sd);
    oa[p] = sa;
}

extern "C" void kernel_launch(void* const* d_in, const int* in_sizes, int n_in,
                              void* d_out, int out_size, void* d_ws, size_t ws_size,
                              hipStream_t stream) {
    const float* cell_feat = (const float*)d_in[0];
    const float* net_feat  = (const float*)d_in[1];
    const float* pin_feat  = (const float*)d_in[2];
    const float* cell_lin_w = (const float*)d_in[3];
    const float* cell_lin_b = (const float*)d_in[4];
    const float* net_lin_w  = (const float*)d_in[5];
    const float* net_lin_b  = (const float*)d_in[6];
    const float* pin_lin_w  = (const float*)d_in[7];
    const float* pin_lin_b  = (const float*)d_in[8];
    const float* pins_w   = (const float*)d_in[9];
    const float* pins_b   = (const float*)d_in[10];
    const float* father_w = (const float*)d_in[11];
    const float* father_b = (const float*)d_in[12];
    const float* son_w    = (const float*)d_in[13];
    const float* son_b    = (const float*)d_in[14];
    const float* cf_node_w = (const float*)d_in[15];
    const float* cf_node_b = (const float*)d_in[16];
    const float* cf_e1_w  = (const float*)d_in[17];
    const float* cf_e1_b  = (const float*)d_in[18];
    const float* cf_e2_w  = (const float*)d_in[19];
    const float* cf_e2_b  = (const float*)d_in[20];
    const float* cf_out_w = (const float*)d_in[21];
    const float* cf_out_b = (const float*)d_in[22];
    const float* net_dis_w   = (const float*)d_in[23];
    const float* net_dis_b   = (const float*)d_in[24];
    const float* net_angle_w = (const float*)d_in[25];
    const float* net_angle_b = (const float*)d_in[26];
    const float* pin_dis_w   = (const float*)d_in[27];
    const float* pin_dis_b   = (const float*)d_in[28];
    const float* pin_angle_w = (const float*)d_in[29];
    const float* pin_angle_b = (const float*)d_in[30];
    const int* pin_net = (const int*)d_in[31];
    const int* pin_cell = (const int*)d_in[32];
    const int* nn_src = (const int*)d_in[33];
    const int* nn_dst = (const int*)d_in[34];
    const int* pairs = (const int*)d_in[35];

    u16* ws16 = (u16*)d_ws;
    const size_t SZ = (size_t)NNET * 64;   // u16 elements per row-table
    u16* h_cell = ws16;                // pre-scaled by rC; later reused for hv
    u16* h_net  = ws16 + SZ;
    u16* bufA   = ws16 + 2 * SZ;       // accP, later acc_cell
    u16* bufB   = ws16 + 3 * SZ;       // accF, later h_cell2
    u16* bufC   = ws16 + 4 * SZ;       // accS
    u16* h_net2 = ws16 + 5 * SZ;
    float* deg  = (float*)(ws16 + 6 * SZ);     // 4 * NNET f32
    float* rC  = deg;
    float* rNp = deg + NNET;
    float* rS  = deg + 2 * NNET;
    float* rD  = deg + 3 * NNET;
    float* ntab = deg + 4 * NNET;              // NNET*8 f32
    float* ctab = ntab + (size_t)NNET * 8;     // NCELL*2 f32

    const int GS  = 2048;  // scatters / elementwise
    const int GC3 = 768;   // combine3 (3 blocks/CU resident)
    const int GMM = 1024;  // mm64f (4 blocks/CU resident)
    const int GCF = 1024;  // cfconv (4 blocks/CU resident)

    hipMemsetAsync(bufA, 0, 3 * SZ * sizeof(u16), stream);   // accP, accF, accS
    hipMemsetAsync(deg, 0, 4 * NNET * sizeof(float), stream);

    k_degrees<<<(NPIN + 255) / 256, 256, 0, stream>>>(pin_cell, pin_net, nn_src, nn_dst,
                                                      rC, rNp, rS, rD);
    k_deg_fin<<<(4 * NNET + 255) / 256, 256, 0, stream>>>(deg);

    k_lin16<<<GS, 256, 0, stream>>>(cell_feat, cell_lin_w, cell_lin_b, rC, h_cell, NCELL);
    k_lin16<<<GS, 256, 0, stream>>>(net_feat, net_lin_w, net_lin_b, nullptr, h_net, NNET);

    k_scatter_all<<<GS, 256, 0, stream>>>(pin_cell, pin_net, nn_src, nn_dst,
                                          h_cell, h_net, rNp, rS, rD,
                                          bufA, bufB, bufC);

    k_combine3<<<GC3, 256, 0, stream>>>(bufA, pins_w, pins_b,
                                        bufB, father_w, father_b,
                                        bufC, son_w, son_b,
                                        h_net2, NNET);

    // hv = h_net @ cf_node_w + b  (h_cell buffer is free now)
    k_mm64f<0><<<GMM, 256, 0, stream>>>(h_net, cf_node_w, cf_node_b, h_cell, NNET);

    hipMemsetAsync(bufA, 0, SZ * sizeof(u16), stream);       // acc_cell
    k_cfconvf<<<GCF, 256, 0, stream>>>(pin_feat, cf_e1_w, cf_e1_b, cf_e2_w, cf_e2_b,
                                       h_cell, pin_net, pin_cell, bufA);
    k_mm64f<1><<<GMM, 256, 0, stream>>>(bufA, cf_out_w, cf_out_b, bufB, NCELL);

    k_net_scalars<<<GS, 256, 0, stream>>>(h_net2, net_dis_w, net_angle_w,
                                          pin_dis_w, pin_angle_w, ntab);
    k_cell_scalars<<<GS, 256, 0, stream>>>(bufB, pin_dis_w, pin_angle_w, ctab);

    float* out = (float*)d_out;
    k_pair<<<(NPAIR + 255) / 256, 256, 0, stream>>>(pairs, ntab, net_dis_b, net_angle_b,
                                                    out, out + NPAIR);
    k_pinro<<<(NPIN + 255) / 256, 256, 0, stream>>>(pin_feat, pin_net, pin_cell,
                                                    ntab, ctab, pin_lin_w, pin_lin_b,
                                                    pin_dis_w, pin_angle_w,
                                                    pin_dis_b, pin_angle_b,
                                                    out + 2 * NPAIR, out + 2 * NPAIR + NPIN);
}

// Round 7
// 413.159 us; speedup vs baseline: 2.9800x; 1.0002x over previous
//
#include <hip/hip_runtime.h>
#include <math.h>

#define NCELL 100000
#define NNET  100000
#define NPIN  500000
#define NNN   200000
#define NPAIR 500000

typedef __attribute__((ext_vector_type(8))) short short8;
typedef __attribute__((ext_vector_type(4))) float f32x4;
typedef unsigned short u16;
typedef unsigned int u32;

__device__ __forceinline__ u16 f2bf(float x) {
    union { float f; u32 u; } v; v.f = x;
    u32 r = (v.u + 0x7FFF + ((v.u >> 16) & 1)) >> 16;   // RNE
    return (u16)r;
}
__device__ __forceinline__ float bf2f(u16 u) {
    union { u32 u; float f; } v; v.u = ((u32)u) << 16; return v.f;
}
__device__ __forceinline__ u32 pack2(float lo, float hi) {
    return (u32)f2bf(lo) | ((u32)f2bf(hi) << 16);
}
__device__ __forceinline__ u32 scale_pk(u32 h, float sc) {
    return pack2(bf2f((u16)(h & 0xffff)) * sc, bf2f((u16)(h >> 16)) * sc);
}
// packed bf16x2 atomic add; no "memory" clobber (write-only accumulators)
__device__ __forceinline__ void pk_add(u16* addr, u32 data) {
    asm volatile("global_atomic_pk_add_bf16 %0, %1, off"
                 :: "v"((unsigned long long)(uintptr_t)addr), "v"(data));
}

__device__ __forceinline__ float softplusf(float x) {
    return fmaxf(x, 0.f) + __logf(1.f + __expf(-fabsf(x)));
}
__device__ __forceinline__ float sspf(float x) {
    return softplusf(x) - 0.69314718055994530942f;
}
// fast tanh: (e^2x - 1)/(e^2x + 1), clamped
__device__ __forceinline__ float ftanh(float x) {
    float xc = fminf(fmaxf(x, -9.f), 9.f);
    float e = __expf(2.f * xc);
    return (e - 1.f) * __builtin_amdgcn_rcpf(e + 1.f);
}

// B-fragment for mfma_f32_16x16x32_bf16 from row-major f32 W[64][64]
__device__ __forceinline__ short8 load_bfrag(const float* __restrict__ W,
                                             int kt, int nt, int lane) {
    int k0 = kt * 32 + ((lane >> 4) & 3) * 8;
    int c = nt * 16 + (lane & 15);
    short8 f;
#pragma unroll
    for (int j = 0; j < 8; j++) f[j] = (short)f2bf(W[(k0 + j) * 64 + c]);
    return f;
}

// ---------------- degree computation ----------------
__global__ void k_degrees(const int* __restrict__ pin_cell, const int* __restrict__ pin_net,
                          const int* __restrict__ nn_src, const int* __restrict__ nn_dst,
                          float* degC, float* degNp, float* degS, float* degD) {
    int i = blockIdx.x * blockDim.x + threadIdx.x;
    if (i < NPIN) {
        atomicAdd(&degC[pin_cell[i]], 1.f);
        atomicAdd(&degNp[pin_net[i]], 1.f);
    }
    if (i < NNN) {
        atomicAdd(&degS[nn_src[i]], 1.f);
        atomicAdd(&degD[nn_dst[i]], 1.f);
    }
}

__global__ void k_deg_fin(float* deg) {
    int i = blockIdx.x * blockDim.x + threadIdx.x;
    if (i < 4 * NNET) deg[i] = rsqrtf(fmaxf(deg[i], 1.f));
}

// ---------------- [n,16] @ [16,64] + b, tanh, optional row-scale; bf16 out ----------------
__global__ __launch_bounds__(256) void k_lin16(
    const float* __restrict__ in, const float* __restrict__ W,
    const float* __restrict__ b, const float* __restrict__ scale,
    u16* __restrict__ out, int n) {
    int tid = threadIdx.x, lane = tid & 63, w = tid >> 6;
    float wr[16];
#pragma unroll
    for (int k = 0; k < 16; k++) wr[k] = W[k * 64 + lane];
    float bias = b[lane];
    int wave = blockIdx.x * 4 + w, nw = gridDim.x * 4;
    for (int r = wave; r < n; r += nw) {
        const float4* ip = (const float4*)(in + (size_t)r * 16);
        float4 a = ip[0], bv = ip[1], c = ip[2], d = ip[3];
        float acc = bias;
        acc = fmaf(a.x, wr[0], acc);  acc = fmaf(a.y, wr[1], acc);
        acc = fmaf(a.z, wr[2], acc);  acc = fmaf(a.w, wr[3], acc);
        acc = fmaf(bv.x, wr[4], acc); acc = fmaf(bv.y, wr[5], acc);
        acc = fmaf(bv.z, wr[6], acc); acc = fmaf(bv.w, wr[7], acc);
        acc = fmaf(c.x, wr[8], acc);  acc = fmaf(c.y, wr[9], acc);
        acc = fmaf(c.z, wr[10], acc); acc = fmaf(c.w, wr[11], acc);
        acc = fmaf(d.x, wr[12], acc); acc = fmaf(d.y, wr[13], acc);
        acc = fmaf(d.z, wr[14], acc); acc = fmaf(d.w, wr[15], acc);
        float sc = scale ? scale[r] : 1.f;
        float v = ftanh(acc) * sc;
        float vp = __shfl_xor(v, 1, 64);
        if (!(lane & 1))
            *(u32*)(out + (size_t)r * 64 + lane) = pack2(v, vp);
    }
}

// ---------------- fused edge scatter (pins + both nn directions), pk-bf16 atomics ----------------
__global__ __launch_bounds__(256) void k_scatter_all(
    const int* __restrict__ pin_cell, const int* __restrict__ pin_net,
    const int* __restrict__ nn_src, const int* __restrict__ nn_dst,
    const u16* __restrict__ h_cell,   // pre-scaled by rC
    const u16* __restrict__ h_net,
    const float* __restrict__ rNp, const float* __restrict__ rS, const float* __restrict__ rD,
    u16* __restrict__ accP, u16* __restrict__ accF, u16* __restrict__ accS) {
    int l32 = threadIdx.x & 31;
    int slot = blockIdx.x * 8 + (threadIdx.x >> 5), nslots = gridDim.x * 8;
#pragma unroll 2
    for (int e = slot; e < NPIN; e += nslots) {
        int c = pin_cell[e], n = pin_net[e];
        float sc = rNp[n];
        u32 h = *(const u32*)(h_cell + (size_t)c * 64 + l32 * 2);
        pk_add(accP + (size_t)n * 64 + l32 * 2, scale_pk(h, sc));
    }
#pragma unroll 2
    for (int i = slot; i < NNN; i += nslots) {
        int s = nn_src[i], d = nn_dst[i];
        float sc = rS[s] * rD[d];
        u32 hs = *(const u32*)(h_net + (size_t)s * 64 + l32 * 2);
        u32 hd = *(const u32*)(h_net + (size_t)d * 64 + l32 * 2);
        pk_add(accF + (size_t)d * 64 + l32 * 2, scale_pk(hs, sc));
        pk_add(accS + (size_t)s * 64 + l32 * 2, scale_pk(hd, sc));
    }
}

// ---------------- fused 3-relation combine via MFMA: out = max_rel(A@W + b), bf16 in/out ----------------
__global__ __launch_bounds__(256, 3) void k_combine3(
    const u16* __restrict__ A0, const float* __restrict__ W0, const float* __restrict__ b0,
    const u16* __restrict__ A1, const float* __restrict__ W1, const float* __restrict__ b1,
    const u16* __restrict__ A2, const float* __restrict__ W2, const float* __restrict__ b2,
    u16* __restrict__ out, int n) {
    int tid = threadIdx.x, lane = tid & 63, w = tid >> 6;
    const float* Ws[3] = {W0, W1, W2};
    const float* bs[3] = {b0, b1, b2};
    const u16* As[3] = {A0, A1, A2};
    short8 Bf[3][2][4];
    float bias[3][4];
#pragma unroll
    for (int rel = 0; rel < 3; rel++) {
#pragma unroll
        for (int kt = 0; kt < 2; kt++)
#pragma unroll
            for (int nt = 0; nt < 4; nt++) Bf[rel][kt][nt] = load_bfrag(Ws[rel], kt, nt, lane);
#pragma unroll
        for (int nt = 0; nt < 4; nt++) bias[rel][nt] = bs[rel][nt * 16 + (lane & 15)];
    }
    int g = (lane >> 4) & 3;
    int wave = blockIdx.x * 4 + w, nwave = gridDim.x * 4;
    int ntile = n >> 4;
    f32x4 z = {0.f, 0.f, 0.f, 0.f};
    for (int t = wave; t < ntile; t += nwave) {
        int R = t << 4;
        int rowA = R + (lane & 15);
        f32x4 res[4];
#pragma unroll
        for (int rel = 0; rel < 3; rel++) {
            const u16* rb = As[rel] + (size_t)rowA * 64;
            short8 a0 = *(const short8*)(rb + g * 8);
            short8 a1 = *(const short8*)(rb + 32 + g * 8);
#pragma unroll
            for (int nt = 0; nt < 4; nt++) {
                f32x4 acc = __builtin_amdgcn_mfma_f32_16x16x32_bf16(a0, Bf[rel][0][nt], z, 0, 0, 0);
                acc = __builtin_amdgcn_mfma_f32_16x16x32_bf16(a1, Bf[rel][1][nt], acc, 0, 0, 0);
                if (rel == 0) {
#pragma unroll
                    for (int r = 0; r < 4; r++) res[nt][r] = acc[r] + bias[0][nt];
                } else {
#pragma unroll
                    for (int r = 0; r < 4; r++) res[nt][r] = fmaxf(res[nt][r], acc[r] + bias[rel][nt]);
                }
            }
        }
#pragma unroll
        for (int nt = 0; nt < 4; nt++)
#pragma unroll
            for (int r = 0; r < 4; r++) {
                float v = res[nt][r];
                float vp = __shfl_xor(v, 1, 64);
                if (!(lane & 1))
                    *(u32*)(out + (size_t)(R + g * 4 + r) * 64 + nt * 16 + (lane & 15)) = pack2(v, vp);
            }
    }
}

// ---------------- generic [n,64] @ [64,64] + b via MFMA; bf16 in/out; ACT: 0 none, 1 ssp ----------------
template <int ACT>
__global__ __launch_bounds__(256, 4) void k_mm64f(
    const u16* __restrict__ in, const float* __restrict__ W,
    const float* __restrict__ b, u16* __restrict__ out, int n) {
    int tid = threadIdx.x, lane = tid & 63, w = tid >> 6;
    short8 Bf[2][4];
    float bias[4];
#pragma unroll
    for (int kt = 0; kt < 2; kt++)
#pragma unroll
        for (int nt = 0; nt < 4; nt++) Bf[kt][nt] = load_bfrag(W, kt, nt, lane);
#pragma unroll
    for (int nt = 0; nt < 4; nt++) bias[nt] = b[nt * 16 + (lane & 15)];
    int g = (lane >> 4) & 3;
    int wave = blockIdx.x * 4 + w, nwave = gridDim.x * 4;
    int ntile = n >> 4;
    f32x4 z = {0.f, 0.f, 0.f, 0.f};
    for (int t = wave; t < ntile; t += nwave) {
        int R = t << 4;
        const u16* rb = in + (size_t)(R + (lane & 15)) * 64;
        short8 a0 = *(const short8*)(rb + g * 8);
        short8 a1 = *(const short8*)(rb + 32 + g * 8);
#pragma unroll
        for (int nt = 0; nt < 4; nt++) {
            f32x4 acc = __builtin_amdgcn_mfma_f32_16x16x32_bf16(a0, Bf[0][nt], z, 0, 0, 0);
            acc = __builtin_amdgcn_mfma_f32_16x16x32_bf16(a1, Bf[1][nt], acc, 0, 0, 0);
#pragma unroll
            for (int r = 0; r < 4; r++) {
                float v = acc[r] + bias[nt];
                if (ACT == 1) v = sspf(v);
                float vp = __shfl_xor(v, 1, 64);
                if (!(lane & 1))
                    *(u32*)(out + (size_t)(R + g * 4 + r) * 64 + nt * 16 + (lane & 15)) = pack2(v, vp);
            }
        }
    }
}

// ---------------- CFConv via MFMA: prefetch gathers, e-MLP, pk-bf16 scatter ----------------
__global__ __launch_bounds__(256, 4) void k_cfconvf(
    const float* __restrict__ pin_feat,
    const float* __restrict__ E1, const float* __restrict__ b1,
    const float* __restrict__ E2, const float* __restrict__ b2,
    const u16* __restrict__ hv,
    const int* __restrict__ pin_net, const int* __restrict__ pin_cell,
    u16* __restrict__ acc) {
    __shared__ __align__(16) u16 sm[4][1024];
    int tid = threadIdx.x, lane = tid & 63, w = tid >> 6;
    short8 B1[4];
#pragma unroll
    for (int nt = 0; nt < 4; nt++) {
        short8 f = {0, 0, 0, 0, 0, 0, 0, 0};
        if (lane < 16) {
            int c = nt * 16 + (lane & 15);
#pragma unroll
            for (int j = 0; j < 8; j++) f[j] = (short)f2bf(E1[j * 64 + c]);
        }
        B1[nt] = f;
    }
    short8 B2[2][4];
#pragma unroll
    for (int kt = 0; kt < 2; kt++)
#pragma unroll
        for (int nt = 0; nt < 4; nt++) B2[kt][nt] = load_bfrag(E2, kt, nt, lane);
    float bb1[4], bb2[4];
#pragma unroll
    for (int nt = 0; nt < 4; nt++) {
        bb1[nt] = b1[nt * 16 + (lane & 15)];
        bb2[nt] = b2[nt * 16 + (lane & 15)];
    }
    int g = (lane >> 4) & 3;
    int wave = blockIdx.x * 4 + w, nwave = gridDim.x * 4;
    const int ntile = NPIN >> 4;
    f32x4 z = {0.f, 0.f, 0.f, 0.f};
    for (int t = wave; t < ntile; t += nwave) {
        int P = t << 4;
        // ---- prefetch: indices + hv gather rows ----
        int ni[4], ci[4];
#pragma unroll
        for (int r = 0; r < 4; r++) {
            int p = P + g * 4 + r;
            ni[r] = pin_net[p];
            ci[r] = pin_cell[p];
        }
        u16 hvp[4][4];
#pragma unroll
        for (int r = 0; r < 4; r++)
#pragma unroll
            for (int nt = 0; nt < 4; nt++)
                hvp[r][nt] = hv[(size_t)ni[r] * 64 + nt * 16 + (lane & 15)];
        // ---- GEMM1: pin_feat[16][8] zero-padded to K=32 ----
        short8 a1 = {0, 0, 0, 0, 0, 0, 0, 0};
        if (lane < 16) {
            const float4* q = (const float4*)(pin_feat + (size_t)(P + lane) * 8);
            float4 u0 = q[0], u1 = q[1];
            a1[0] = (short)f2bf(u0.x); a1[1] = (short)f2bf(u0.y);
            a1[2] = (short)f2bf(u0.z); a1[3] = (short)f2bf(u0.w);
            a1[4] = (short)f2bf(u1.x); a1[5] = (short)f2bf(u1.y);
            a1[6] = (short)f2bf(u1.z); a1[7] = (short)f2bf(u1.w);
        }
#pragma unroll
        for (int nt = 0; nt < 4; nt++) {
            f32x4 c1 = __builtin_amdgcn_mfma_f32_16x16x32_bf16(a1, B1[nt], z, 0, 0, 0);
#pragma unroll
            for (int r = 0; r < 4; r++) {
                int row = g * 4 + r;
                int col = nt * 16 + (lane & 15);
                float v = sspf(c1[r] + bb1[nt]);
                sm[w][row * 64 + (col ^ ((row & 7) << 3))] = f2bf(v);
            }
        }
        // ---- GEMM2: A from LDS (swizzled transpose) ----
        int row2 = lane & 15;
        short8 a2[2];
#pragma unroll
        for (int kt = 0; kt < 2; kt++) {
            int idx = row2 * 64 + ((kt * 32 + g * 8) ^ ((row2 & 7) << 3));
            a2[kt] = *(const short8*)&sm[w][idx];
        }
        f32x4 ef[4];
#pragma unroll
        for (int nt = 0; nt < 4; nt++) {
            f32x4 e = __builtin_amdgcn_mfma_f32_16x16x32_bf16(a2[0], B2[0][nt], z, 0, 0, 0);
            e = __builtin_amdgcn_mfma_f32_16x16x32_bf16(a2[1], B2[1][nt], e, 0, 0, 0);
#pragma unroll
            for (int r = 0; r < 4; r++) ef[nt][r] = sspf(e[r] + bb2[nt]);
        }
        // ---- scatter: hv(prefetched) * e -> acc[cell], pk-bf16 atomics ----
#pragma unroll
        for (int r = 0; r < 4; r++) {
            u16* ar = acc + (size_t)ci[r] * 64 + (lane & 15);
#pragma unroll
            for (int nt = 0; nt < 4; nt++) {
                float v = bf2f(hvp[r][nt]) * ef[nt][r];
                float vp = __shfl_xor(v, 1, 64);
                if (!(lane & 1)) pk_add(ar + nt * 16, pack2(v, vp));
            }
        }
    }
}

// ---------------- fused per-net + per-cell scalar precompute ----------------
// net r: tab[r*8 + {0:d0,1:a0,2:d1,3:a1,4:nd,5:na}]; cell c: ctab[c*2 + {0,1}]
__global__ __launch_bounds__(256) void k_scalars(
    const u16* __restrict__ hnet2, const u16* __restrict__ hcell2,
    const float* __restrict__ ndw, const float* __restrict__ naw,   // [128]
    const float* __restrict__ pdw, const float* __restrict__ paw,   // [136]
    float* __restrict__ ntab, float* __restrict__ ctab) {
    int tid = threadIdx.x, l32 = tid & 31;
    int c0 = l32 * 2, c1 = c0 + 1;
    float wd0a = ndw[c0], wd0b = ndw[c1], wd1a = ndw[64 + c0], wd1b = ndw[64 + c1];
    float wa0a = naw[c0], wa0b = naw[c1], wa1a = naw[64 + c0], wa1b = naw[64 + c1];
    float wpda = pdw[c0], wpdb = pdw[c1], wpaa = paw[c0], wpab = paw[c1];
    float wcda = pdw[72 + c0], wcdb = pdw[72 + c1];
    float wcaa = paw[72 + c0], wcab = paw[72 + c1];
    int slot = blockIdx.x * 8 + (tid >> 5), nslots = gridDim.x * 8;
    const int NTOT = NNET + NCELL;
    for (int r = slot; r < NTOT; r += nslots) {
        if (r < NNET) {
            u32 h2 = *(const u32*)(hnet2 + (size_t)r * 64 + c0);
            float ha = bf2f((u16)(h2 & 0xffff)), hb = bf2f((u16)(h2 >> 16));
            float s0 = ha * wd0a + hb * wd0b;
            float s1 = ha * wd1a + hb * wd1b;
            float s2 = ha * wa0a + hb * wa0b;
            float s3 = ha * wa1a + hb * wa1b;
            float s4 = ha * wpda + hb * wpdb;
            float s5 = ha * wpaa + hb * wpab;
            for (int off = 16; off > 0; off >>= 1) {
                s0 += __shfl_down(s0, off, 32); s1 += __shfl_down(s1, off, 32);
                s2 += __shfl_down(s2, off, 32); s3 += __shfl_down(s3, off, 32);
                s4 += __shfl_down(s4, off, 32); s5 += __shfl_down(s5, off, 32);
            }
            if (l32 == 0) {
                float* t = ntab + (size_t)r * 8;
                t[0] = s0; t[1] = s2; t[2] = s1; t[3] = s3; t[4] = s4; t[5] = s5;
            }
        } else {
            int rc = r - NNET;
            u32 h2 = *(const u32*)(hcell2 + (size_t)rc * 64 + c0);
            float ha = bf2f((u16)(h2 & 0xffff)), hb = bf2f((u16)(h2 >> 16));
            float s0 = ha * wcda + hb * wcdb;
            float s1 = ha * wcaa + hb * wcab;
            for (int off = 16; off > 0; off >>= 1) {
                s0 += __shfl_down(s0, off, 32);
                s1 += __shfl_down(s1, off, 32);
            }
            if (l32 == 0) {
                ctab[(size_t)rc * 2] = s0;
                ctab[(size_t)rc * 2 + 1] = s1;
            }
        }
    }
}

// ---------------- fused pair + pin readout ----------------
__global__ __launch_bounds__(256) void k_readout(
    const int* __restrict__ pairs,
    const float* __restrict__ pin_feat,
    const int* __restrict__ pin_net, const int* __restrict__ pin_cell,
    const float* __restrict__ ntab, const float* __restrict__ ctab,
    const float* __restrict__ plw, const float* __restrict__ plb,
    const float* __restrict__ pdw, const float* __restrict__ paw,
    const float* __restrict__ nbd, const float* __restrict__ nba,
    const float* __restrict__ pbd, const float* __restrict__ pba,
    float* __restrict__ out) {
    int i = blockIdx.x * blockDim.x + threadIdx.x;
    if (i < NPAIR) {
        int p0 = pairs[2 * i], p1 = pairs[2 * i + 1];
        float2 x0 = *(const float2*)(ntab + (size_t)p0 * 8);
        float2 x1 = *(const float2*)(ntab + (size_t)p1 * 8 + 2);
        out[i] = softplusf(x0.x + x1.x + nbd[0]);
        out[NPAIR + i] = x0.y + x1.y + nba[0];
    } else if (i < NPAIR + NPIN) {
        int p = i - NPAIR;
        int n = pin_net[p], c = pin_cell[p];
        float2 ns = *(const float2*)(ntab + (size_t)n * 8 + 4);
        float2 cs = *(const float2*)(ctab + (size_t)c * 2);
        float pf[8];
        *(float4*)pf = *(const float4*)(pin_feat + (size_t)p * 8);
        *(float4*)(pf + 4) = *(const float4*)(pin_feat + (size_t)p * 8 + 4);
        float sd = ns.x + cs.x + pbd[0];
        float sa = ns.y + cs.y + pba[0];
#pragma unroll
        for (int j = 0; j < 8; j++) {
            float a = plb[j];
#pragma unroll
            for (int k = 0; k < 8; k++) a = fmaf(pf[k], plw[k * 8 + j], a);
            float hp = ftanh(a);
            sd = fmaf(hp, pdw[64 + j], sd);
            sa = fmaf(hp, paw[64 + j], sa);
        }
        out[2 * NPAIR + p] = softplusf(sd);
        out[2 * NPAIR + NPIN + p] = sa;
    }
}

extern "C" void kernel_launch(void* const* d_in, const int* in_sizes, int n_in,
                              void* d_out, int out_size, void* d_ws, size_t ws_size,
                              hipStream_t stream) {
    const float* cell_feat = (const float*)d_in[0];
    const float* net_feat  = (const float*)d_in[1];
    const float* pin_feat  = (const float*)d_in[2];
    const float* cell_lin_w = (const float*)d_in[3];
    const float* cell_lin_b = (const float*)d_in[4];
    const float* net_lin_w  = (const float*)d_in[5];
    const float* net_lin_b  = (const float*)d_in[6];
    const float* pin_lin_w  = (const float*)d_in[7];
    const float* pin_lin_b  = (const float*)d_in[8];
    const float* pins_w   = (const float*)d_in[9];
    const float* pins_b   = (const float*)d_in[10];
    const float* father_w = (const float*)d_in[11];
    const float* father_b = (const float*)d_in[12];
    const float* son_w    = (const float*)d_in[13];
    const float* son_b    = (const float*)d_in[14];
    const float* cf_node_w = (const float*)d_in[15];
    const float* cf_node_b = (const float*)d_in[16];
    const float* cf_e1_w  = (const float*)d_in[17];
    const float* cf_e1_b  = (const float*)d_in[18];
    const float* cf_e2_w  = (const float*)d_in[19];
    const float* cf_e2_b  = (const float*)d_in[20];
    const float* cf_out_w = (const float*)d_in[21];
    const float* cf_out_b = (const float*)d_in[22];
    const float* net_dis_w   = (const float*)d_in[23];
    const float* net_dis_b   = (const float*)d_in[24];
    const float* net_angle_w = (const float*)d_in[25];
    const float* net_angle_b = (const float*)d_in[26];
    const float* pin_dis_w   = (const float*)d_in[27];
    const float* pin_dis_b   = (const float*)d_in[28];
    const float* pin_angle_w = (const float*)d_in[29];
    const float* pin_angle_b = (const float*)d_in[30];
    const int* pin_net = (const int*)d_in[31];
    const int* pin_cell = (const int*)d_in[32];
    const int* nn_src = (const int*)d_in[33];
    const int* nn_dst = (const int*)d_in[34];
    const int* pairs = (const int*)d_in[35];

    u16* ws16 = (u16*)d_ws;
    const size_t SZ = (size_t)NNET * 64;   // u16 elements per row-table
    u16* h_cell = ws16;                // pre-scaled by rC; later reused for hv
    u16* h_net  = ws16 + SZ;
    u16* bufA   = ws16 + 2 * SZ;       // accP, later acc_cell
    u16* bufB   = ws16 + 3 * SZ;       // accF, later h_cell2
    u16* bufC   = ws16 + 4 * SZ;       // accS
    u16* h_net2 = ws16 + 5 * SZ;
    float* deg  = (float*)(ws16 + 6 * SZ);     // 4 * NNET f32
    float* rC  = deg;
    float* rNp = deg + NNET;
    float* rS  = deg + 2 * NNET;
    float* rD  = deg + 3 * NNET;
    float* ntab = deg + 4 * NNET;              // NNET*8 f32
    float* ctab = ntab + (size_t)NNET * 8;     // NCELL*2 f32

    const int GS  = 2048;  // scatters / elementwise (8 blocks/CU)
    const int GC3 = 768;   // combine3 (3 blocks/CU, high-VGPR)
    const int GMM = 2048;  // mm64f (8 blocks/CU)
    const int GCF = 2048;  // cfconv (8 blocks/CU)

    hipMemsetAsync(bufA, 0, 3 * SZ * sizeof(u16), stream);   // accP, accF, accS
    hipMemsetAsync(deg, 0, 4 * NNET * sizeof(float), stream);

    k_degrees<<<(NPIN + 255) / 256, 256, 0, stream>>>(pin_cell, pin_net, nn_src, nn_dst,
                                                      rC, rNp, rS, rD);
    k_deg_fin<<<(4 * NNET + 255) / 256, 256, 0, stream>>>(deg);

    k_lin16<<<GS, 256, 0, stream>>>(cell_feat, cell_lin_w, cell_lin_b, rC, h_cell, NCELL);
    k_lin16<<<GS, 256, 0, stream>>>(net_feat, net_lin_w, net_lin_b, nullptr, h_net, NNET);

    k_scatter_all<<<GS, 256, 0, stream>>>(pin_cell, pin_net, nn_src, nn_dst,
                                          h_cell, h_net, rNp, rS, rD,
                                          bufA, bufB, bufC);

    k_combine3<<<GC3, 256, 0, stream>>>(bufA, pins_w, pins_b,
                                        bufB, father_w, father_b,
                                        bufC, son_w, son_b,
                                        h_net2, NNET);

    // hv = h_net @ cf_node_w + b  (h_cell buffer is free now)
    k_mm64f<0><<<GMM, 256, 0, stream>>>(h_net, cf_node_w, cf_node_b, h_cell, NNET);

    hipMemsetAsync(bufA, 0, SZ * sizeof(u16), stream);       // acc_cell
    k_cfconvf<<<GCF, 256, 0, stream>>>(pin_feat, cf_e1_w, cf_e1_b, cf_e2_w, cf_e2_b,
                                       h_cell, pin_net, pin_cell, bufA);
    k_mm64f<1><<<GMM, 256, 0, stream>>>(bufA, cf_out_w, cf_out_b, bufB, NCELL);

    k_scalars<<<GS, 256, 0, stream>>>(h_net2, bufB, net_dis_w, net_angle_w,
                                      pin_dis_w, pin_angle_w, ntab, ctab);

    float* out = (float*)d_out;
    k_readout<<<(NPAIR + NPIN + 255) / 256, 256, 0, stream>>>(
        pairs, pin_feat, pin_net, pin_cell, ntab, ctab,
        pin_lin_w, pin_lin_b, pin_dis_w, pin_angle_w,
        net_dis_b, net_angle_b, pin_dis_b, pin_angle_b, out);
}

// Round 8
// 402.979 us; speedup vs baseline: 3.0553x; 1.0253x over previous
//
#include <hip/hip_runtime.h>
#include <math.h>

#define NCELL 100000
#define NNET  100000
#define NPIN  500000
#define NNN   200000
#define NPAIR 500000

typedef __attribute__((ext_vector_type(8))) short short8;
typedef __attribute__((ext_vector_type(4))) float f32x4;
typedef unsigned short u16;
typedef unsigned int u32;

__device__ __forceinline__ u16 f2bf(float x) {
    union { float f; u32 u; } v; v.f = x;
    u32 r = (v.u + 0x7FFF + ((v.u >> 16) & 1)) >> 16;   // RNE
    return (u16)r;
}
__device__ __forceinline__ float bf2f(u16 u) {
    union { u32 u; float f; } v; v.u = ((u32)u) << 16; return v.f;
}
__device__ __forceinline__ u32 pack2(float lo, float hi) {
    return (u32)f2bf(lo) | ((u32)f2bf(hi) << 16);
}
// packed bf16x2 atomic add; no "memory" clobber (write-only accumulators)
__device__ __forceinline__ void pk_add(u16* addr, u32 data) {
    asm volatile("global_atomic_pk_add_bf16 %0, %1, off"
                 :: "v"((unsigned long long)(uintptr_t)addr), "v"(data));
}

__device__ __forceinline__ float softplusf(float x) {
    return fmaxf(x, 0.f) + __logf(1.f + __expf(-fabsf(x)));
}
__device__ __forceinline__ float sspf(float x) {
    return softplusf(x) - 0.69314718055994530942f;
}
__device__ __forceinline__ float ftanh(float x) {
    float xc = fminf(fmaxf(x, -9.f), 9.f);
    float e = __expf(2.f * xc);
    return (e - 1.f) * __builtin_amdgcn_rcpf(e + 1.f);
}

// B-fragment for mfma_f32_16x16x32_bf16 from row-major f32 W[64][64]
__device__ __forceinline__ short8 load_bfrag(const float* __restrict__ W,
                                             int kt, int nt, int lane) {
    int k0 = kt * 32 + ((lane >> 4) & 3) * 8;
    int c = nt * 16 + (lane & 15);
    short8 f;
#pragma unroll
    for (int j = 0; j < 8; j++) f[j] = (short)f2bf(W[(k0 + j) * 64 + c]);
    return f;
}

// ---------------- degree computation ----------------
__global__ void k_degrees(const int* __restrict__ pin_cell, const int* __restrict__ pin_net,
                          const int* __restrict__ nn_src, const int* __restrict__ nn_dst,
                          float* degC, float* degNp, float* degS, float* degD) {
    int i = blockIdx.x * blockDim.x + threadIdx.x;
    if (i < NPIN) {
        atomicAdd(&degC[pin_cell[i]], 1.f);
        atomicAdd(&degNp[pin_net[i]], 1.f);
    }
    if (i < NNN) {
        atomicAdd(&degS[nn_src[i]], 1.f);
        atomicAdd(&degD[nn_dst[i]], 1.f);
    }
}

__global__ void k_deg_fin(float* deg) {
    int i = blockIdx.x * blockDim.x + threadIdx.x;
    if (i < 4 * NNET) deg[i] = rsqrtf(fmaxf(deg[i], 1.f));
}

// ---------------- fused input linears: cells (rC-scaled) + nets (3 copies) ----------------
__global__ __launch_bounds__(256) void k_lin16_all(
    const float* __restrict__ cf, const float* __restrict__ nf,
    const float* __restrict__ Wc, const float* __restrict__ bc,
    const float* __restrict__ Wn, const float* __restrict__ bn,
    const float* __restrict__ rC, const float* __restrict__ rS, const float* __restrict__ rD,
    u16* __restrict__ h_cell, u16* __restrict__ h_net,
    u16* __restrict__ hS, u16* __restrict__ hD) {
    int tid = threadIdx.x, lane = tid & 63, w = tid >> 6;
    float wc[16], wn[16];
#pragma unroll
    for (int k = 0; k < 16; k++) { wc[k] = Wc[k * 64 + lane]; wn[k] = Wn[k * 64 + lane]; }
    float bC = bc[lane], bN = bn[lane];
    int wave = blockIdx.x * 4 + w, nw = gridDim.x * 4;
    for (int r = wave; r < NCELL; r += nw) {
        const float4* ip = (const float4*)(cf + (size_t)r * 16);
        float4 a = ip[0], bv = ip[1], c = ip[2], d = ip[3];
        float acc = bC;
        acc = fmaf(a.x, wc[0], acc);  acc = fmaf(a.y, wc[1], acc);
        acc = fmaf(a.z, wc[2], acc);  acc = fmaf(a.w, wc[3], acc);
        acc = fmaf(bv.x, wc[4], acc); acc = fmaf(bv.y, wc[5], acc);
        acc = fmaf(bv.z, wc[6], acc); acc = fmaf(bv.w, wc[7], acc);
        acc = fmaf(c.x, wc[8], acc);  acc = fmaf(c.y, wc[9], acc);
        acc = fmaf(c.z, wc[10], acc); acc = fmaf(c.w, wc[11], acc);
        acc = fmaf(d.x, wc[12], acc); acc = fmaf(d.y, wc[13], acc);
        acc = fmaf(d.z, wc[14], acc); acc = fmaf(d.w, wc[15], acc);
        float v = ftanh(acc) * rC[r];
        float vp = __shfl_xor(v, 1, 64);
        if (!(lane & 1))
            *(u32*)(h_cell + (size_t)r * 64 + lane) = pack2(v, vp);
    }
    for (int r = wave; r < NNET; r += nw) {
        const float4* ip = (const float4*)(nf + (size_t)r * 16);
        float4 a = ip[0], bv = ip[1], c = ip[2], d = ip[3];
        float acc = bN;
        acc = fmaf(a.x, wn[0], acc);  acc = fmaf(a.y, wn[1], acc);
        acc = fmaf(a.z, wn[2], acc);  acc = fmaf(a.w, wn[3], acc);
        acc = fmaf(bv.x, wn[4], acc); acc = fmaf(bv.y, wn[5], acc);
        acc = fmaf(bv.z, wn[6], acc); acc = fmaf(bv.w, wn[7], acc);
        acc = fmaf(c.x, wn[8], acc);  acc = fmaf(c.y, wn[9], acc);
        acc = fmaf(c.z, wn[10], acc); acc = fmaf(c.w, wn[11], acc);
        acc = fmaf(d.x, wn[12], acc); acc = fmaf(d.y, wn[13], acc);
        acc = fmaf(d.z, wn[14], acc); acc = fmaf(d.w, wn[15], acc);
        float v = ftanh(acc);
        float vs = v * rS[r], vd = v * rD[r];
        float vp = __shfl_xor(v, 1, 64);
        float vsp = __shfl_xor(vs, 1, 64);
        float vdp = __shfl_xor(vd, 1, 64);
        if (!(lane & 1)) {
            *(u32*)(h_net + (size_t)r * 64 + lane) = pack2(v, vp);
            *(u32*)(hS + (size_t)r * 64 + lane) = pack2(vs, vsp);
            *(u32*)(hD + (size_t)r * 64 + lane) = pack2(vd, vdp);
        }
    }
}

// ---------------- pure edge scatter (no per-edge scales), batch-4 loads ----------------
__global__ __launch_bounds__(256) void k_scatter_all(
    const int* __restrict__ pin_cell, const int* __restrict__ pin_net,
    const int* __restrict__ nn_src, const int* __restrict__ nn_dst,
    const u16* __restrict__ h_cell,   // pre-scaled by rC
    const u16* __restrict__ hS, const u16* __restrict__ hD,
    u16* __restrict__ accP, u16* __restrict__ accF, u16* __restrict__ accS) {
    int l32 = threadIdx.x & 31;
    int off2 = l32 * 2;
    int slot = blockIdx.x * 8 + (threadIdx.x >> 5), ns = gridDim.x * 8;
    int e = slot;
    for (; e + 3 * ns < NPIN; e += 4 * ns) {
        int c0 = pin_cell[e],          n0 = pin_net[e];
        int c1 = pin_cell[e + ns],     n1 = pin_net[e + ns];
        int c2 = pin_cell[e + 2 * ns], n2 = pin_net[e + 2 * ns];
        int c3 = pin_cell[e + 3 * ns], n3 = pin_net[e + 3 * ns];
        u32 h0 = *(const u32*)(h_cell + (size_t)c0 * 64 + off2);
        u32 h1 = *(const u32*)(h_cell + (size_t)c1 * 64 + off2);
        u32 h2 = *(const u32*)(h_cell + (size_t)c2 * 64 + off2);
        u32 h3 = *(const u32*)(h_cell + (size_t)c3 * 64 + off2);
        pk_add(accP + (size_t)n0 * 64 + off2, h0);
        pk_add(accP + (size_t)n1 * 64 + off2, h1);
        pk_add(accP + (size_t)n2 * 64 + off2, h2);
        pk_add(accP + (size_t)n3 * 64 + off2, h3);
    }
    for (; e < NPIN; e += ns) {
        int c = pin_cell[e], n = pin_net[e];
        u32 h = *(const u32*)(h_cell + (size_t)c * 64 + off2);
        pk_add(accP + (size_t)n * 64 + off2, h);
    }
    int i = slot;
    for (; i + ns < NNN; i += 2 * ns) {
        int s0 = nn_src[i], d0 = nn_dst[i];
        int s1 = nn_src[i + ns], d1 = nn_dst[i + ns];
        u32 a0 = *(const u32*)(hS + (size_t)s0 * 64 + off2);
        u32 a1 = *(const u32*)(hS + (size_t)s1 * 64 + off2);
        u32 b0 = *(const u32*)(hD + (size_t)d0 * 64 + off2);
        u32 b1 = *(const u32*)(hD + (size_t)d1 * 64 + off2);
        pk_add(accF + (size_t)d0 * 64 + off2, a0);
        pk_add(accS + (size_t)s0 * 64 + off2, b0);
        pk_add(accF + (size_t)d1 * 64 + off2, a1);
        pk_add(accS + (size_t)s1 * 64 + off2, b1);
    }
    for (; i < NNN; i += ns) {
        int s = nn_src[i], d = nn_dst[i];
        u32 a = *(const u32*)(hS + (size_t)s * 64 + off2);
        u32 b = *(const u32*)(hD + (size_t)d * 64 + off2);
        pk_add(accF + (size_t)d * 64 + off2, a);
        pk_add(accS + (size_t)s * 64 + off2, b);
    }
}

// ---------------- 3-relation combine + row scales + fused ntab dots (no h_net2) ----------------
__global__ __launch_bounds__(256, 2) void k_combine3(
    const u16* __restrict__ A0, const float* __restrict__ W0, const float* __restrict__ b0,
    const u16* __restrict__ A1, const float* __restrict__ W1, const float* __restrict__ b1,
    const u16* __restrict__ A2, const float* __restrict__ W2, const float* __restrict__ b2,
    const float* __restrict__ sc0, const float* __restrict__ sc1, const float* __restrict__ sc2,
    const float* __restrict__ ndw, const float* __restrict__ naw,
    const float* __restrict__ pdw, const float* __restrict__ paw,
    float* __restrict__ ntab, int n) {
    int tid = threadIdx.x, lane = tid & 63, w = tid >> 6;
    int l15 = lane & 15, g = (lane >> 4) & 3;
    const float* Ws[3] = {W0, W1, W2};
    const float* bs[3] = {b0, b1, b2};
    const u16* As[3] = {A0, A1, A2};
    short8 Bf[3][2][4];
    float bias[3][4];
#pragma unroll
    for (int rel = 0; rel < 3; rel++) {
#pragma unroll
        for (int kt = 0; kt < 2; kt++)
#pragma unroll
            for (int nt = 0; nt < 4; nt++) Bf[rel][kt][nt] = load_bfrag(Ws[rel], kt, nt, lane);
#pragma unroll
        for (int nt = 0; nt < 4; nt++) bias[rel][nt] = bs[rel][nt * 16 + l15];
    }
    float wt[6][4];
#pragma unroll
    for (int nt = 0; nt < 4; nt++) {
        int c = nt * 16 + l15;
        wt[0][nt] = ndw[c];      wt[1][nt] = naw[c];
        wt[2][nt] = ndw[64 + c]; wt[3][nt] = naw[64 + c];
        wt[4][nt] = pdw[c];      wt[5][nt] = paw[c];
    }
    int wave = blockIdx.x * 4 + w, nwave = gridDim.x * 4;
    int ntile = n >> 4;
    f32x4 z = {0.f, 0.f, 0.f, 0.f};
    for (int t = wave; t < ntile; t += nwave) {
        int R = t << 4;
        int rowA = R + l15;
        float s0a[4], s1a[4], s2a[4];
        *(float4*)s0a = *(const float4*)(sc0 + R + g * 4);
        *(float4*)s1a = *(const float4*)(sc1 + R + g * 4);
        *(float4*)s2a = *(const float4*)(sc2 + R + g * 4);
        f32x4 res[4];
#pragma unroll
        for (int rel = 0; rel < 3; rel++) {
            const u16* rb = As[rel] + (size_t)rowA * 64;
            short8 a0 = *(const short8*)(rb + g * 8);
            short8 a1 = *(const short8*)(rb + 32 + g * 8);
            const float* sa = (rel == 0) ? s0a : (rel == 1) ? s1a : s2a;
#pragma unroll
            for (int nt = 0; nt < 4; nt++) {
                f32x4 acc = __builtin_amdgcn_mfma_f32_16x16x32_bf16(a0, Bf[rel][0][nt], z, 0, 0, 0);
                acc = __builtin_amdgcn_mfma_f32_16x16x32_bf16(a1, Bf[rel][1][nt], acc, 0, 0, 0);
                if (rel == 0) {
#pragma unroll
                    for (int r = 0; r < 4; r++) res[nt][r] = sa[r] * acc[r] + bias[0][nt];
                } else {
#pragma unroll
                    for (int r = 0; r < 4; r++)
                        res[nt][r] = fmaxf(res[nt][r], sa[r] * acc[r] + bias[rel][nt]);
                }
            }
        }
        // fused 6-dot epilogue -> ntab
#pragma unroll
        for (int r = 0; r < 4; r++) {
            float a0 = 0.f, a1 = 0.f, a2 = 0.f, a3 = 0.f, a4 = 0.f, a5 = 0.f;
#pragma unroll
            for (int nt = 0; nt < 4; nt++) {
                float v = res[nt][r];
                a0 = fmaf(v, wt[0][nt], a0);
                a1 = fmaf(v, wt[1][nt], a1);
                a2 = fmaf(v, wt[2][nt], a2);
                a3 = fmaf(v, wt[3][nt], a3);
                a4 = fmaf(v, wt[4][nt], a4);
                a5 = fmaf(v, wt[5][nt], a5);
            }
#pragma unroll
            for (int off = 1; off < 16; off <<= 1) {
                a0 += __shfl_xor(a0, off, 64);
                a1 += __shfl_xor(a1, off, 64);
                a2 += __shfl_xor(a2, off, 64);
                a3 += __shfl_xor(a3, off, 64);
                a4 += __shfl_xor(a4, off, 64);
                a5 += __shfl_xor(a5, off, 64);
            }
            if (l15 == 0) {
                float* tp = ntab + (size_t)(R + g * 4 + r) * 8;
                *(float2*)tp = float2{a0, a1};
                *(float2*)(tp + 2) = float2{a2, a3};
                *(float2*)(tp + 4) = float2{a4, a5};
            }
        }
    }
}

// ---------------- hv = h_net @ cf_node_w + b (bf16 in/out) ----------------
__global__ __launch_bounds__(256, 4) void k_mm64hv(
    const u16* __restrict__ in, const float* __restrict__ W,
    const float* __restrict__ b, u16* __restrict__ out, int n) {
    int tid = threadIdx.x, lane = tid & 63, w = tid >> 6;
    int l15 = lane & 15, g = (lane >> 4) & 3;
    short8 Bf[2][4];
    float bias[4];
#pragma unroll
    for (int kt = 0; kt < 2; kt++)
#pragma unroll
        for (int nt = 0; nt < 4; nt++) Bf[kt][nt] = load_bfrag(W, kt, nt, lane);
#pragma unroll
    for (int nt = 0; nt < 4; nt++) bias[nt] = b[nt * 16 + l15];
    int wave = blockIdx.x * 4 + w, nwave = gridDim.x * 4;
    int ntile = n >> 4;
    f32x4 z = {0.f, 0.f, 0.f, 0.f};
    for (int t = wave; t < ntile; t += nwave) {
        int R = t << 4;
        const u16* rb = in + (size_t)(R + l15) * 64;
        short8 a0 = *(const short8*)(rb + g * 8);
        short8 a1 = *(const short8*)(rb + 32 + g * 8);
#pragma unroll
        for (int nt = 0; nt < 4; nt++) {
            f32x4 acc = __builtin_amdgcn_mfma_f32_16x16x32_bf16(a0, Bf[0][nt], z, 0, 0, 0);
            acc = __builtin_amdgcn_mfma_f32_16x16x32_bf16(a1, Bf[1][nt], acc, 0, 0, 0);
#pragma unroll
            for (int r = 0; r < 4; r++) {
                float v = acc[r] + bias[nt];
                float vp = __shfl_xor(v, 1, 64);
                if (!(lane & 1))
                    *(u32*)(out + (size_t)(R + g * 4 + r) * 64 + nt * 16 + l15) = pack2(v, vp);
            }
        }
    }
}

// ---------------- cell out-layer: ssp(acc @ W + b) fused with ctab dots (no h_cell2) ----------------
__global__ __launch_bounds__(256, 3) void k_mm64c(
    const u16* __restrict__ in, const float* __restrict__ W, const float* __restrict__ b,
    const float* __restrict__ pdw, const float* __restrict__ paw,
    float* __restrict__ ctab, int n) {
    int tid = threadIdx.x, lane = tid & 63, w = tid >> 6;
    int l15 = lane & 15, g = (lane >> 4) & 3;
    short8 Bf[2][4];
    float bias[4], wdv[4], wav[4];
#pragma unroll
    for (int kt = 0; kt < 2; kt++)
#pragma unroll
        for (int nt = 0; nt < 4; nt++) Bf[kt][nt] = load_bfrag(W, kt, nt, lane);
#pragma unroll
    for (int nt = 0; nt < 4; nt++) {
        int c = nt * 16 + l15;
        bias[nt] = b[c];
        wdv[nt] = pdw[72 + c];
        wav[nt] = paw[72 + c];
    }
    int wave = blockIdx.x * 4 + w, nwave = gridDim.x * 4;
    int ntile = n >> 4;
    f32x4 z = {0.f, 0.f, 0.f, 0.f};
    for (int t = wave; t < ntile; t += nwave) {
        int R = t << 4;
        const u16* rb = in + (size_t)(R + l15) * 64;
        short8 a0 = *(const short8*)(rb + g * 8);
        short8 a1 = *(const short8*)(rb + 32 + g * 8);
        float sd[4] = {0.f, 0.f, 0.f, 0.f}, sa[4] = {0.f, 0.f, 0.f, 0.f};
#pragma unroll
        for (int nt = 0; nt < 4; nt++) {
            f32x4 acc = __builtin_amdgcn_mfma_f32_16x16x32_bf16(a0, Bf[0][nt], z, 0, 0, 0);
            acc = __builtin_amdgcn_mfma_f32_16x16x32_bf16(a1, Bf[1][nt], acc, 0, 0, 0);
#pragma unroll
            for (int r = 0; r < 4; r++) {
                float v = sspf(acc[r] + bias[nt]);
                sd[r] = fmaf(v, wdv[nt], sd[r]);
                sa[r] = fmaf(v, wav[nt], sa[r]);
            }
        }
#pragma unroll
        for (int r = 0; r < 4; r++) {
            float d = sd[r], a = sa[r];
#pragma unroll
            for (int off = 1; off < 16; off <<= 1) {
                d += __shfl_xor(d, off, 64);
                a += __shfl_xor(a, off, 64);
            }
            if (l15 == 0)
                *(float2*)(ctab + (size_t)(R + g * 4 + r) * 2) = float2{d, a};
        }
    }
}

// ---------------- CFConv via MFMA, software-pipelined across tiles ----------------
__global__ __launch_bounds__(256, 4) void k_cfconvf(
    const float* __restrict__ pin_feat,
    const float* __restrict__ E1, const float* __restrict__ b1,
    const float* __restrict__ E2, const float* __restrict__ b2,
    const u16* __restrict__ hv,
    const int* __restrict__ pin_net, const int* __restrict__ pin_cell,
    u16* __restrict__ acc) {
    __shared__ __align__(16) u16 sm[4][1024];
    int tid = threadIdx.x, lane = tid & 63, w = tid >> 6;
    int l15 = lane & 15, g = (lane >> 4) & 3;
    short8 B1[4];
#pragma unroll
    for (int nt = 0; nt < 4; nt++) {
        short8 f = {0, 0, 0, 0, 0, 0, 0, 0};
        if (lane < 16) {
            int c = nt * 16 + l15;
#pragma unroll
            for (int j = 0; j < 8; j++) f[j] = (short)f2bf(E1[j * 64 + c]);
        }
        B1[nt] = f;
    }
    short8 B2[2][4];
#pragma unroll
    for (int kt = 0; kt < 2; kt++)
#pragma unroll
        for (int nt = 0; nt < 4; nt++) B2[kt][nt] = load_bfrag(E2, kt, nt, lane);
    float bb1[4], bb2[4];
#pragma unroll
    for (int nt = 0; nt < 4; nt++) {
        bb1[nt] = b1[nt * 16 + l15];
        bb2[nt] = b2[nt * 16 + l15];
    }
    int wave = blockIdx.x * 4 + w, nwave = gridDim.x * 4;
    const int ntile = NPIN >> 4;
    f32x4 z = {0.f, 0.f, 0.f, 0.f};
    int t = wave;
    if (t >= ntile) return;
    // ---- prologue: state for tile t ----
    int ci[4], ni0[4];
#pragma unroll
    for (int r = 0; r < 4; r++) {
        int p = (t << 4) + g * 4 + r;
        ni0[r] = pin_net[p];
        ci[r] = pin_cell[p];
    }
    u16 hvp[4][4];
#pragma unroll
    for (int r = 0; r < 4; r++)
#pragma unroll
        for (int nt = 0; nt < 4; nt++)
            hvp[r][nt] = hv[(size_t)ni0[r] * 64 + nt * 16 + l15];
    float4 pfa = {0, 0, 0, 0}, pfb = {0, 0, 0, 0};
    if (lane < 16) {
        const float4* q = (const float4*)(pin_feat + (size_t)((t << 4) + lane) * 8);
        pfa = q[0]; pfb = q[1];
    }
    while (true) {
        int t2 = t + nwave;
        bool more = t2 < ntile;
        // issue next tile's indices
        int niN[4], ciN[4];
        if (more) {
#pragma unroll
            for (int r = 0; r < 4; r++) {
                int p = (t2 << 4) + g * 4 + r;
                niN[r] = pin_net[p];
                ciN[r] = pin_cell[p];
            }
        }
        // GEMM1 from registered pin feats
        short8 a1 = {0, 0, 0, 0, 0, 0, 0, 0};
        if (lane < 16) {
            a1[0] = (short)f2bf(pfa.x); a1[1] = (short)f2bf(pfa.y);
            a1[2] = (short)f2bf(pfa.z); a1[3] = (short)f2bf(pfa.w);
            a1[4] = (short)f2bf(pfb.x); a1[5] = (short)f2bf(pfb.y);
            a1[6] = (short)f2bf(pfb.z); a1[7] = (short)f2bf(pfb.w);
        }
#pragma unroll
        for (int nt = 0; nt < 4; nt++) {
            f32x4 c1 = __builtin_amdgcn_mfma_f32_16x16x32_bf16(a1, B1[nt], z, 0, 0, 0);
#pragma unroll
            for (int r = 0; r < 4; r++) {
                int row = g * 4 + r;
                int col = nt * 16 + l15;
                sm[w][row * 64 + (col ^ ((row & 7) << 3))] = f2bf(sspf(c1[r] + bb1[nt]));
            }
        }
        // prefetch next tile's hv rows + pin feats (indices arrived during GEMM1)
        u16 hvpN[4][4];
        float4 pfaN = {0, 0, 0, 0}, pfbN = {0, 0, 0, 0};
        if (more) {
#pragma unroll
            for (int r = 0; r < 4; r++)
#pragma unroll
                for (int nt = 0; nt < 4; nt++)
                    hvpN[r][nt] = hv[(size_t)niN[r] * 64 + nt * 16 + l15];
            if (lane < 16) {
                const float4* q = (const float4*)(pin_feat + (size_t)((t2 << 4) + lane) * 8);
                pfaN = q[0]; pfbN = q[1];
            }
        }
        // GEMM2 from LDS transpose
        short8 a2[2];
#pragma unroll
        for (int kt = 0; kt < 2; kt++) {
            int idx = l15 * 64 + ((kt * 32 + g * 8) ^ ((l15 & 7) << 3));
            a2[kt] = *(const short8*)&sm[w][idx];
        }
        f32x4 ef[4];
#pragma unroll
        for (int nt = 0; nt < 4; nt++) {
            f32x4 e = __builtin_amdgcn_mfma_f32_16x16x32_bf16(a2[0], B2[0][nt], z, 0, 0, 0);
            e = __builtin_amdgcn_mfma_f32_16x16x32_bf16(a2[1], B2[1][nt], e, 0, 0, 0);
#pragma unroll
            for (int r = 0; r < 4; r++) ef[nt][r] = sspf(e[r] + bb2[nt]);
        }
        // scatter current tile
#pragma unroll
        for (int r = 0; r < 4; r++) {
            u16* ar = acc + (size_t)ci[r] * 64 + l15;
#pragma unroll
            for (int nt = 0; nt < 4; nt++) {
                float v = bf2f(hvp[r][nt]) * ef[nt][r];
                float vp = __shfl_xor(v, 1, 64);
                if (!(lane & 1)) pk_add(ar + nt * 16, pack2(v, vp));
            }
        }
        if (!more) break;
        t = t2;
#pragma unroll
        for (int r = 0; r < 4; r++) {
            ci[r] = ciN[r];
#pragma unroll
            for (int nt = 0; nt < 4; nt++) hvp[r][nt] = hvpN[r][nt];
        }
        pfa = pfaN; pfb = pfbN;
    }
}

// ---------------- fused pair + pin readout ----------------
__global__ __launch_bounds__(256) void k_readout(
    const int* __restrict__ pairs,
    const float* __restrict__ pin_feat,
    const int* __restrict__ pin_net, const int* __restrict__ pin_cell,
    const float* __restrict__ ntab, const float* __restrict__ ctab,
    const float* __restrict__ plw, const float* __restrict__ plb,
    const float* __restrict__ pdw, const float* __restrict__ paw,
    const float* __restrict__ nbd, const float* __restrict__ nba,
    const float* __restrict__ pbd, const float* __restrict__ pba,
    float* __restrict__ out) {
    int i = blockIdx.x * blockDim.x + threadIdx.x;
    if (i < NPAIR) {
        int p0 = pairs[2 * i], p1 = pairs[2 * i + 1];
        float2 x0 = *(const float2*)(ntab + (size_t)p0 * 8);
        float2 x1 = *(const float2*)(ntab + (size_t)p1 * 8 + 2);
        out[i] = softplusf(x0.x + x1.x + nbd[0]);
        out[NPAIR + i] = x0.y + x1.y + nba[0];
    } else if (i < NPAIR + NPIN) {
        int p = i - NPAIR;
        int n = pin_net[p], c = pin_cell[p];
        float2 ns = *(const float2*)(ntab + (size_t)n * 8 + 4);
        float2 cs = *(const float2*)(ctab + (size_t)c * 2);
        float pf[8];
        *(float4*)pf = *(const float4*)(pin_feat + (size_t)p * 8);
        *(float4*)(pf + 4) = *(const float4*)(pin_feat + (size_t)p * 8 + 4);
        float sd = ns.x + cs.x + pbd[0];
        float sa = ns.y + cs.y + pba[0];
#pragma unroll
        for (int j = 0; j < 8; j++) {
            float a = plb[j];
#pragma unroll
            for (int k = 0; k < 8; k++) a = fmaf(pf[k], plw[k * 8 + j], a);
            float hp = ftanh(a);
            sd = fmaf(hp, pdw[64 + j], sd);
            sa = fmaf(hp, paw[64 + j], sa);
        }
        out[2 * NPAIR + p] = softplusf(sd);
        out[2 * NPAIR + NPIN + p] = sa;
    }
}

extern "C" void kernel_launch(void* const* d_in, const int* in_sizes, int n_in,
                              void* d_out, int out_size, void* d_ws, size_t ws_size,
                              hipStream_t stream) {
    const float* cell_feat = (const float*)d_in[0];
    const float* net_feat  = (const float*)d_in[1];
    const float* pin_feat  = (const float*)d_in[2];
    const float* cell_lin_w = (const float*)d_in[3];
    const float* cell_lin_b = (const float*)d_in[4];
    const float* net_lin_w  = (const float*)d_in[5];
    const float* net_lin_b  = (const float*)d_in[6];
    const float* pin_lin_w  = (const float*)d_in[7];
    const float* pin_lin_b  = (const float*)d_in[8];
    const float* pins_w   = (const float*)d_in[9];
    const float* pins_b   = (const float*)d_in[10];
    const float* father_w = (const float*)d_in[11];
    const float* father_b = (const float*)d_in[12];
    const float* son_w    = (const float*)d_in[13];
    const float* son_b    = (const float*)d_in[14];
    const float* cf_node_w = (const float*)d_in[15];
    const float* cf_node_b = (const float*)d_in[16];
    const float* cf_e1_w  = (const float*)d_in[17];
    const float* cf_e1_b  = (const float*)d_in[18];
    const float* cf_e2_w  = (const float*)d_in[19];
    const float* cf_e2_b  = (const float*)d_in[20];
    const float* cf_out_w = (const float*)d_in[21];
    const float* cf_out_b = (const float*)d_in[22];
    const float* net_dis_w   = (const float*)d_in[23];
    const float* net_dis_b   = (const float*)d_in[24];
    const float* net_angle_w = (const float*)d_in[25];
    const float* net_angle_b = (const float*)d_in[26];
    const float* pin_dis_w   = (const float*)d_in[27];
    const float* pin_dis_b   = (const float*)d_in[28];
    const float* pin_angle_w = (const float*)d_in[29];
    const float* pin_angle_b = (const float*)d_in[30];
    const int* pin_net = (const int*)d_in[31];
    const int* pin_cell = (const int*)d_in[32];
    const int* nn_src = (const int*)d_in[33];
    const int* nn_dst = (const int*)d_in[34];
    const int* pairs = (const int*)d_in[35];

    u16* ws16 = (u16*)d_ws;
    const size_t SZ = (size_t)NNET * 64;   // u16 elements per row-table
    u16* h_cell = ws16;                // rC-scaled; later reused for hv
    u16* h_net  = ws16 + SZ;
    u16* hS     = ws16 + 2 * SZ;
    u16* hD     = ws16 + 3 * SZ;
    u16* bufA   = ws16 + 4 * SZ;       // accP, later acc_cell
    u16* bufB   = ws16 + 5 * SZ;       // accF
    u16* bufC   = ws16 + 6 * SZ;       // accS
    float* deg  = (float*)(ws16 + 7 * SZ);     // 4 * NNET f32
    float* rC  = deg;
    float* rNp = deg + NNET;
    float* rS  = deg + 2 * NNET;
    float* rD  = deg + 3 * NNET;
    float* ntab = deg + 4 * NNET;              // NNET*8 f32
    float* ctab = ntab + (size_t)NNET * 8;     // NCELL*2 f32

    hipMemsetAsync(bufA, 0, 3 * SZ * sizeof(u16), stream);   // accP, accF, accS
    hipMemsetAsync(deg, 0, 4 * NNET * sizeof(float), stream);

    k_degrees<<<(NPIN + 255) / 256, 256, 0, stream>>>(pin_cell, pin_net, nn_src, nn_dst,
                                                      rC, rNp, rS, rD);
    k_deg_fin<<<(4 * NNET + 255) / 256, 256, 0, stream>>>(deg);

    k_lin16_all<<<2048, 256, 0, stream>>>(cell_feat, net_feat,
                                          cell_lin_w, cell_lin_b, net_lin_w, net_lin_b,
                                          rC, rS, rD, h_cell, h_net, hS, hD);

    k_scatter_all<<<2048, 256, 0, stream>>>(pin_cell, pin_net, nn_src, nn_dst,
                                            h_cell, hS, hD, bufA, bufB, bufC);

    k_combine3<<<512, 256, 0, stream>>>(bufA, pins_w, pins_b,
                                        bufB, father_w, father_b,
                                        bufC, son_w, son_b,
                                        rNp, rD, rS,
                                        net_dis_w, net_angle_w, pin_dis_w, pin_angle_w,
                                        ntab, NNET);

    // hv = h_net @ cf_node_w + b  (h_cell buffer is free now)
    k_mm64hv<<<512, 256, 0, stream>>>(h_net, cf_node_w, cf_node_b, h_cell, NNET);

    hipMemsetAsync(bufA, 0, SZ * sizeof(u16), stream);       // acc_cell
    k_cfconvf<<<1024, 256, 0, stream>>>(pin_feat, cf_e1_w, cf_e1_b, cf_e2_w, cf_e2_b,
                                        h_cell, pin_net, pin_cell, bufA);
    k_mm64c<<<512, 256, 0, stream>>>(bufA, cf_out_w, cf_out_b,
                                     pin_dis_w, pin_angle_w, ctab, NCELL);

    float* out = (float*)d_out;
    k_readout<<<(NPAIR + NPIN + 255) / 256, 256, 0, stream>>>(
        pairs, pin_feat, pin_net, pin_cell, ntab, ctab,
        pin_lin_w, pin_lin_b, pin_dis_w, pin_angle_w,
        net_dis_b, net_angle_b, pin_dis_b, pin_angle_b, out);
}

// Round 9
// 384.273 us; speedup vs baseline: 3.2040x; 1.0487x over previous
//
#include <hip/hip_runtime.h>
#include <math.h>

#define NCELL 100000
#define NNET  100000
#define NPIN  500000
#define NNN   200000
#define NPAIR 500000

typedef __attribute__((ext_vector_type(8))) short short8;
typedef __attribute__((ext_vector_type(4))) float f32x4;
typedef unsigned short u16;
typedef unsigned int u32;

__device__ __forceinline__ u16 f2bf(float x) {
    union { float f; u32 u; } v; v.f = x;
    u32 r = (v.u + 0x7FFF + ((v.u >> 16) & 1)) >> 16;   // RNE
    return (u16)r;
}
__device__ __forceinline__ float bf2f(u16 u) {
    union { u32 u; float f; } v; v.u = ((u32)u) << 16; return v.f;
}
__device__ __forceinline__ u32 pack2(float lo, float hi) {
    return (u32)f2bf(lo) | ((u32)f2bf(hi) << 16);
}
__device__ __forceinline__ u32 mul_pk(u32 a, u32 b) {
    return pack2(bf2f((u16)(a & 0xffff)) * bf2f((u16)(b & 0xffff)),
                 bf2f((u16)(a >> 16)) * bf2f((u16)(b >> 16)));
}
// packed bf16x2 atomic add; no "memory" clobber (write-only accumulators)
__device__ __forceinline__ void pk_add(u16* addr, u32 data) {
    asm volatile("global_atomic_pk_add_bf16 %0, %1, off"
                 :: "v"((unsigned long long)(uintptr_t)addr), "v"(data));
}

__device__ __forceinline__ float softplusf(float x) {
    return fmaxf(x, 0.f) + __logf(1.f + __expf(-fabsf(x)));
}
__device__ __forceinline__ float sspf(float x) {
    return softplusf(x) - 0.69314718055994530942f;
}
__device__ __forceinline__ float ftanh(float x) {
    float xc = fminf(fmaxf(x, -9.f), 9.f);
    float e = __expf(2.f * xc);
    return (e - 1.f) * __builtin_amdgcn_rcpf(e + 1.f);
}

// B-fragment for mfma_f32_16x16x32_bf16 from row-major f32 W[64][64]
__device__ __forceinline__ short8 load_bfrag(const float* __restrict__ W,
                                             int kt, int nt, int lane) {
    int k0 = kt * 32 + ((lane >> 4) & 3) * 8;
    int c = nt * 16 + (lane & 15);
    short8 f;
#pragma unroll
    for (int j = 0; j < 8; j++) f[j] = (short)f2bf(W[(k0 + j) * 64 + c]);
    return f;
}

// ---------------- degree computation ----------------
__global__ void k_degrees(const int* __restrict__ pin_cell, const int* __restrict__ pin_net,
                          const int* __restrict__ nn_src, const int* __restrict__ nn_dst,
                          float* degC, float* degNp, float* degS, float* degD) {
    int i = blockIdx.x * blockDim.x + threadIdx.x;
    if (i < NPIN) {
        atomicAdd(&degC[pin_cell[i]], 1.f);
        atomicAdd(&degNp[pin_net[i]], 1.f);
    }
    if (i < NNN) {
        atomicAdd(&degS[nn_src[i]], 1.f);
        atomicAdd(&degD[nn_dst[i]], 1.f);
    }
}

__global__ void k_deg_fin(float* deg) {
    int i = blockIdx.x * blockDim.x + threadIdx.x;
    if (i < 4 * NNET) deg[i] = rsqrtf(fmaxf(deg[i], 1.f));
}

// ---------------- fused input linears: cells (rC-scaled) + nets (3 copies) ----------------
__global__ __launch_bounds__(256) void k_lin16_all(
    const float* __restrict__ cf, const float* __restrict__ nf,
    const float* __restrict__ Wc, const float* __restrict__ bc,
    const float* __restrict__ Wn, const float* __restrict__ bn,
    const float* __restrict__ rC, const float* __restrict__ rS, const float* __restrict__ rD,
    u16* __restrict__ h_cell, u16* __restrict__ h_net,
    u16* __restrict__ hS, u16* __restrict__ hD) {
    int tid = threadIdx.x, lane = tid & 63, w = tid >> 6;
    float wc[16], wn[16];
#pragma unroll
    for (int k = 0; k < 16; k++) { wc[k] = Wc[k * 64 + lane]; wn[k] = Wn[k * 64 + lane]; }
    float bC = bc[lane], bN = bn[lane];
    int wave = blockIdx.x * 4 + w, nw = gridDim.x * 4;
    for (int r = wave; r < NCELL; r += nw) {
        const float4* ip = (const float4*)(cf + (size_t)r * 16);
        float4 a = ip[0], bv = ip[1], c = ip[2], d = ip[3];
        float acc = bC;
        acc = fmaf(a.x, wc[0], acc);  acc = fmaf(a.y, wc[1], acc);
        acc = fmaf(a.z, wc[2], acc);  acc = fmaf(a.w, wc[3], acc);
        acc = fmaf(bv.x, wc[4], acc); acc = fmaf(bv.y, wc[5], acc);
        acc = fmaf(bv.z, wc[6], acc); acc = fmaf(bv.w, wc[7], acc);
        acc = fmaf(c.x, wc[8], acc);  acc = fmaf(c.y, wc[9], acc);
        acc = fmaf(c.z, wc[10], acc); acc = fmaf(c.w, wc[11], acc);
        acc = fmaf(d.x, wc[12], acc); acc = fmaf(d.y, wc[13], acc);
        acc = fmaf(d.z, wc[14], acc); acc = fmaf(d.w, wc[15], acc);
        float v = ftanh(acc) * rC[r];
        float vp = __shfl_xor(v, 1, 64);
        if (!(lane & 1))
            *(u32*)(h_cell + (size_t)r * 64 + lane) = pack2(v, vp);
    }
    for (int r = wave; r < NNET; r += nw) {
        const float4* ip = (const float4*)(nf + (size_t)r * 16);
        float4 a = ip[0], bv = ip[1], c = ip[2], d = ip[3];
        float acc = bN;
        acc = fmaf(a.x, wn[0], acc);  acc = fmaf(a.y, wn[1], acc);
        acc = fmaf(a.z, wn[2], acc);  acc = fmaf(a.w, wn[3], acc);
        acc = fmaf(bv.x, wn[4], acc); acc = fmaf(bv.y, wn[5], acc);
        acc = fmaf(bv.z, wn[6], acc); acc = fmaf(bv.w, wn[7], acc);
        acc = fmaf(c.x, wn[8], acc);  acc = fmaf(c.y, wn[9], acc);
        acc = fmaf(c.z, wn[10], acc); acc = fmaf(c.w, wn[11], acc);
        acc = fmaf(d.x, wn[12], acc); acc = fmaf(d.y, wn[13], acc);
        acc = fmaf(d.z, wn[14], acc); acc = fmaf(d.w, wn[15], acc);
        float v = ftanh(acc);
        float vs = v * rS[r], vd = v * rD[r];
        float vp = __shfl_xor(v, 1, 64);
        float vsp = __shfl_xor(vs, 1, 64);
        float vdp = __shfl_xor(vd, 1, 64);
        if (!(lane & 1)) {
            *(u32*)(h_net + (size_t)r * 64 + lane) = pack2(v, vp);
            *(u32*)(hS + (size_t)r * 64 + lane) = pack2(vs, vsp);
            *(u32*)(hD + (size_t)r * 64 + lane) = pack2(vd, vdp);
        }
    }
}

// ---------------- pure edge scatter (no per-edge scales), batch-4 loads ----------------
__global__ __launch_bounds__(256) void k_scatter_all(
    const int* __restrict__ pin_cell, const int* __restrict__ pin_net,
    const int* __restrict__ nn_src, const int* __restrict__ nn_dst,
    const u16* __restrict__ h_cell,   // pre-scaled by rC
    const u16* __restrict__ hS, const u16* __restrict__ hD,
    u16* __restrict__ accP, u16* __restrict__ accF, u16* __restrict__ accS) {
    int l32 = threadIdx.x & 31;
    int off2 = l32 * 2;
    int slot = blockIdx.x * 8 + (threadIdx.x >> 5), ns = gridDim.x * 8;
    int e = slot;
    for (; e + 3 * ns < NPIN; e += 4 * ns) {
        int c0 = pin_cell[e],          n0 = pin_net[e];
        int c1 = pin_cell[e + ns],     n1 = pin_net[e + ns];
        int c2 = pin_cell[e + 2 * ns], n2 = pin_net[e + 2 * ns];
        int c3 = pin_cell[e + 3 * ns], n3 = pin_net[e + 3 * ns];
        u32 h0 = *(const u32*)(h_cell + (size_t)c0 * 64 + off2);
        u32 h1 = *(const u32*)(h_cell + (size_t)c1 * 64 + off2);
        u32 h2 = *(const u32*)(h_cell + (size_t)c2 * 64 + off2);
        u32 h3 = *(const u32*)(h_cell + (size_t)c3 * 64 + off2);
        pk_add(accP + (size_t)n0 * 64 + off2, h0);
        pk_add(accP + (size_t)n1 * 64 + off2, h1);
        pk_add(accP + (size_t)n2 * 64 + off2, h2);
        pk_add(accP + (size_t)n3 * 64 + off2, h3);
    }
    for (; e < NPIN; e += ns) {
        int c = pin_cell[e], n = pin_net[e];
        u32 h = *(const u32*)(h_cell + (size_t)c * 64 + off2);
        pk_add(accP + (size_t)n * 64 + off2, h);
    }
    int i = slot;
    for (; i + ns < NNN; i += 2 * ns) {
        int s0 = nn_src[i], d0 = nn_dst[i];
        int s1 = nn_src[i + ns], d1 = nn_dst[i + ns];
        u32 a0 = *(const u32*)(hS + (size_t)s0 * 64 + off2);
        u32 a1 = *(const u32*)(hS + (size_t)s1 * 64 + off2);
        u32 b0 = *(const u32*)(hD + (size_t)d0 * 64 + off2);
        u32 b1 = *(const u32*)(hD + (size_t)d1 * 64 + off2);
        pk_add(accF + (size_t)d0 * 64 + off2, a0);
        pk_add(accS + (size_t)s0 * 64 + off2, b0);
        pk_add(accF + (size_t)d1 * 64 + off2, a1);
        pk_add(accS + (size_t)s1 * 64 + off2, b1);
    }
    for (; i < NNN; i += ns) {
        int s = nn_src[i], d = nn_dst[i];
        u32 a = *(const u32*)(hS + (size_t)s * 64 + off2);
        u32 b = *(const u32*)(hD + (size_t)d * 64 + off2);
        pk_add(accF + (size_t)d * 64 + off2, a);
        pk_add(accS + (size_t)s * 64 + off2, b);
    }
}

// ---------------- 3-relation combine + row scales + fused ntab dots (no h_net2) ----------------
__global__ __launch_bounds__(256, 2) void k_combine3(
    const u16* __restrict__ A0, const float* __restrict__ W0, const float* __restrict__ b0,
    const u16* __restrict__ A1, const float* __restrict__ W1, const float* __restrict__ b1,
    const u16* __restrict__ A2, const float* __restrict__ W2, const float* __restrict__ b2,
    const float* __restrict__ sc0, const float* __restrict__ sc1, const float* __restrict__ sc2,
    const float* __restrict__ ndw, const float* __restrict__ naw,
    const float* __restrict__ pdw, const float* __restrict__ paw,
    float* __restrict__ ntab, int n) {
    int tid = threadIdx.x, lane = tid & 63, w = tid >> 6;
    int l15 = lane & 15, g = (lane >> 4) & 3;
    const float* Ws[3] = {W0, W1, W2};
    const float* bs[3] = {b0, b1, b2};
    const u16* As[3] = {A0, A1, A2};
    short8 Bf[3][2][4];
    float bias[3][4];
#pragma unroll
    for (int rel = 0; rel < 3; rel++) {
#pragma unroll
        for (int kt = 0; kt < 2; kt++)
#pragma unroll
            for (int nt = 0; nt < 4; nt++) Bf[rel][kt][nt] = load_bfrag(Ws[rel], kt, nt, lane);
#pragma unroll
        for (int nt = 0; nt < 4; nt++) bias[rel][nt] = bs[rel][nt * 16 + l15];
    }
    float wt[6][4];
#pragma unroll
    for (int nt = 0; nt < 4; nt++) {
        int c = nt * 16 + l15;
        wt[0][nt] = ndw[c];      wt[1][nt] = naw[c];
        wt[2][nt] = ndw[64 + c]; wt[3][nt] = naw[64 + c];
        wt[4][nt] = pdw[c];      wt[5][nt] = paw[c];
    }
    int wave = blockIdx.x * 4 + w, nwave = gridDim.x * 4;
    int ntile = n >> 4;
    f32x4 z = {0.f, 0.f, 0.f, 0.f};
    for (int t = wave; t < ntile; t += nwave) {
        int R = t << 4;
        int rowA = R + l15;
        float s0a[4], s1a[4], s2a[4];
        *(float4*)s0a = *(const float4*)(sc0 + R + g * 4);
        *(float4*)s1a = *(const float4*)(sc1 + R + g * 4);
        *(float4*)s2a = *(const float4*)(sc2 + R + g * 4);
        f32x4 res[4];
#pragma unroll
        for (int rel = 0; rel < 3; rel++) {
            const u16* rb = As[rel] + (size_t)rowA * 64;
            short8 a0 = *(const short8*)(rb + g * 8);
            short8 a1 = *(const short8*)(rb + 32 + g * 8);
            const float* sa = (rel == 0) ? s0a : (rel == 1) ? s1a : s2a;
#pragma unroll
            for (int nt = 0; nt < 4; nt++) {
                f32x4 acc = __builtin_amdgcn_mfma_f32_16x16x32_bf16(a0, Bf[rel][0][nt], z, 0, 0, 0);
                acc = __builtin_amdgcn_mfma_f32_16x16x32_bf16(a1, Bf[rel][1][nt], acc, 0, 0, 0);
                if (rel == 0) {
#pragma unroll
                    for (int r = 0; r < 4; r++) res[nt][r] = sa[r] * acc[r] + bias[0][nt];
                } else {
#pragma unroll
                    for (int r = 0; r < 4; r++)
                        res[nt][r] = fmaxf(res[nt][r], sa[r] * acc[r] + bias[rel][nt]);
                }
            }
        }
        // fused 6-dot epilogue -> ntab
#pragma unroll
        for (int r = 0; r < 4; r++) {
            float a0 = 0.f, a1 = 0.f, a2 = 0.f, a3 = 0.f, a4 = 0.f, a5 = 0.f;
#pragma unroll
            for (int nt = 0; nt < 4; nt++) {
                float v = res[nt][r];
                a0 = fmaf(v, wt[0][nt], a0);
                a1 = fmaf(v, wt[1][nt], a1);
                a2 = fmaf(v, wt[2][nt], a2);
                a3 = fmaf(v, wt[3][nt], a3);
                a4 = fmaf(v, wt[4][nt], a4);
                a5 = fmaf(v, wt[5][nt], a5);
            }
#pragma unroll
            for (int off = 1; off < 16; off <<= 1) {
                a0 += __shfl_xor(a0, off, 64);
                a1 += __shfl_xor(a1, off, 64);
                a2 += __shfl_xor(a2, off, 64);
                a3 += __shfl_xor(a3, off, 64);
                a4 += __shfl_xor(a4, off, 64);
                a5 += __shfl_xor(a5, off, 64);
            }
            if (l15 == 0) {
                float* tp = ntab + (size_t)(R + g * 4 + r) * 8;
                *(float2*)tp = float2{a0, a1};
                *(float2*)(tp + 2) = float2{a2, a3};
                *(float2*)(tp + 4) = float2{a4, a5};
            }
        }
    }
}

// ---------------- hv = h_net @ cf_node_w + b (bf16 in/out) ----------------
__global__ __launch_bounds__(256, 4) void k_mm64hv(
    const u16* __restrict__ in, const float* __restrict__ W,
    const float* __restrict__ b, u16* __restrict__ out, int n) {
    int tid = threadIdx.x, lane = tid & 63, w = tid >> 6;
    int l15 = lane & 15, g = (lane >> 4) & 3;
    short8 Bf[2][4];
    float bias[4];
#pragma unroll
    for (int kt = 0; kt < 2; kt++)
#pragma unroll
        for (int nt = 0; nt < 4; nt++) Bf[kt][nt] = load_bfrag(W, kt, nt, lane);
#pragma unroll
    for (int nt = 0; nt < 4; nt++) bias[nt] = b[nt * 16 + l15];
    int wave = blockIdx.x * 4 + w, nwave = gridDim.x * 4;
    int ntile = n >> 4;
    f32x4 z = {0.f, 0.f, 0.f, 0.f};
    for (int t = wave; t < ntile; t += nwave) {
        int R = t << 4;
        const u16* rb = in + (size_t)(R + l15) * 64;
        short8 a0 = *(const short8*)(rb + g * 8);
        short8 a1 = *(const short8*)(rb + 32 + g * 8);
#pragma unroll
        for (int nt = 0; nt < 4; nt++) {
            f32x4 acc = __builtin_amdgcn_mfma_f32_16x16x32_bf16(a0, Bf[0][nt], z, 0, 0, 0);
            acc = __builtin_amdgcn_mfma_f32_16x16x32_bf16(a1, Bf[1][nt], acc, 0, 0, 0);
#pragma unroll
            for (int r = 0; r < 4; r++) {
                float v = acc[r] + bias[nt];
                float vp = __shfl_xor(v, 1, 64);
                if (!(lane & 1))
                    *(u32*)(out + (size_t)(R + g * 4 + r) * 64 + nt * 16 + l15) = pack2(v, vp);
            }
        }
    }
}

// ---------------- e-MLP streaming: e[p][64] = ssp(ssp(pf@E1+b1)@E2+b2), bf16 out ----------------
__global__ __launch_bounds__(256, 4) void k_emlp(
    const float* __restrict__ pin_feat,
    const float* __restrict__ E1, const float* __restrict__ b1,
    const float* __restrict__ E2, const float* __restrict__ b2,
    u16* __restrict__ etab) {
    __shared__ __align__(16) u16 sm[4][1024];
    int tid = threadIdx.x, lane = tid & 63, w = tid >> 6;
    int l15 = lane & 15, g = (lane >> 4) & 3;
    short8 B1[4];
#pragma unroll
    for (int nt = 0; nt < 4; nt++) {
        short8 f = {0, 0, 0, 0, 0, 0, 0, 0};
        if (lane < 16) {
            int c = nt * 16 + l15;
#pragma unroll
            for (int j = 0; j < 8; j++) f[j] = (short)f2bf(E1[j * 64 + c]);
        }
        B1[nt] = f;
    }
    short8 B2[2][4];
#pragma unroll
    for (int kt = 0; kt < 2; kt++)
#pragma unroll
        for (int nt = 0; nt < 4; nt++) B2[kt][nt] = load_bfrag(E2, kt, nt, lane);
    float bb1[4], bb2[4];
#pragma unroll
    for (int nt = 0; nt < 4; nt++) {
        bb1[nt] = b1[nt * 16 + l15];
        bb2[nt] = b2[nt * 16 + l15];
    }
    int wave = blockIdx.x * 4 + w, nwave = gridDim.x * 4;
    const int ntile = NPIN >> 4;
    f32x4 z = {0.f, 0.f, 0.f, 0.f};
    for (int t = wave; t < ntile; t += nwave) {
        int P = t << 4;
        short8 a1 = {0, 0, 0, 0, 0, 0, 0, 0};
        if (lane < 16) {
            const float4* q = (const float4*)(pin_feat + (size_t)(P + lane) * 8);
            float4 u0 = q[0], u1 = q[1];
            a1[0] = (short)f2bf(u0.x); a1[1] = (short)f2bf(u0.y);
            a1[2] = (short)f2bf(u0.z); a1[3] = (short)f2bf(u0.w);
            a1[4] = (short)f2bf(u1.x); a1[5] = (short)f2bf(u1.y);
            a1[6] = (short)f2bf(u1.z); a1[7] = (short)f2bf(u1.w);
        }
#pragma unroll
        for (int nt = 0; nt < 4; nt++) {
            f32x4 c1 = __builtin_amdgcn_mfma_f32_16x16x32_bf16(a1, B1[nt], z, 0, 0, 0);
#pragma unroll
            for (int r = 0; r < 4; r++) {
                int row = g * 4 + r;
                int col = nt * 16 + l15;
                sm[w][row * 64 + (col ^ ((row & 7) << 3))] = f2bf(sspf(c1[r] + bb1[nt]));
            }
        }
        short8 a2[2];
#pragma unroll
        for (int kt = 0; kt < 2; kt++) {
            int idx = l15 * 64 + ((kt * 32 + g * 8) ^ ((l15 & 7) << 3));
            a2[kt] = *(const short8*)&sm[w][idx];
        }
#pragma unroll
        for (int nt = 0; nt < 4; nt++) {
            f32x4 e = __builtin_amdgcn_mfma_f32_16x16x32_bf16(a2[0], B2[0][nt], z, 0, 0, 0);
            e = __builtin_amdgcn_mfma_f32_16x16x32_bf16(a2[1], B2[1][nt], e, 0, 0, 0);
#pragma unroll
            for (int r = 0; r < 4; r++) {
                float v = sspf(e[r] + bb2[nt]);
                float vp = __shfl_xor(v, 1, 64);
                if (!(lane & 1))
                    *(u32*)(etab + (size_t)(P + g * 4 + r) * 64 + nt * 16 + l15) = pack2(v, vp);
            }
        }
    }
}

// ---------------- e-scatter: acc[cell] += hv[net] * e[pin]; half-wave per pin ----------------
__global__ __launch_bounds__(256) void k_escatter(
    const u16* __restrict__ etab, const u16* __restrict__ hv,
    const int* __restrict__ pin_net, const int* __restrict__ pin_cell,
    u16* __restrict__ acc) {
    int l32 = threadIdx.x & 31;
    int off2 = l32 * 2;
    int slot = blockIdx.x * 8 + (threadIdx.x >> 5), ns = gridDim.x * 8;
    int p = slot;
    for (; p + ns < NPIN; p += 2 * ns) {
        int n0 = pin_net[p], c0 = pin_cell[p];
        int n1 = pin_net[p + ns], c1 = pin_cell[p + ns];
        u32 e0 = *(const u32*)(etab + (size_t)p * 64 + off2);
        u32 e1 = *(const u32*)(etab + (size_t)(p + ns) * 64 + off2);
        u32 h0 = *(const u32*)(hv + (size_t)n0 * 64 + off2);
        u32 h1 = *(const u32*)(hv + (size_t)n1 * 64 + off2);
        pk_add(acc + (size_t)c0 * 64 + off2, mul_pk(e0, h0));
        pk_add(acc + (size_t)c1 * 64 + off2, mul_pk(e1, h1));
    }
    for (; p < NPIN; p += ns) {
        int n = pin_net[p], c = pin_cell[p];
        u32 e = *(const u32*)(etab + (size_t)p * 64 + off2);
        u32 h = *(const u32*)(hv + (size_t)n * 64 + off2);
        pk_add(acc + (size_t)c * 64 + off2, mul_pk(e, h));
    }
}

// ---------------- cell out-layer: ssp(acc @ W + b) fused with ctab dots (no h_cell2) ----------------
__global__ __launch_bounds__(256, 3) void k_mm64c(
    const u16* __restrict__ in, const float* __restrict__ W, const float* __restrict__ b,
    const float* __restrict__ pdw, const float* __restrict__ paw,
    float* __restrict__ ctab, int n) {
    int tid = threadIdx.x, lane = tid & 63, w = tid >> 6;
    int l15 = lane & 15, g = (lane >> 4) & 3;
    short8 Bf[2][4];
    float bias[4], wdv[4], wav[4];
#pragma unroll
    for (int kt = 0; kt < 2; kt++)
#pragma unroll
        for (int nt = 0; nt < 4; nt++) Bf[kt][nt] = load_bfrag(W, kt, nt, lane);
#pragma unroll
    for (int nt = 0; nt < 4; nt++) {
        int c = nt * 16 + l15;
        bias[nt] = b[c];
        wdv[nt] = pdw[72 + c];
        wav[nt] = paw[72 + c];
    }
    int wave = blockIdx.x * 4 + w, nwave = gridDim.x * 4;
    int ntile = n >> 4;
    f32x4 z = {0.f, 0.f, 0.f, 0.f};
    for (int t = wave; t < ntile; t += nwave) {
        int R = t << 4;
        const u16* rb = in + (size_t)(R + l15) * 64;
        short8 a0 = *(const short8*)(rb + g * 8);
        short8 a1 = *(const short8*)(rb + 32 + g * 8);
        float sd[4] = {0.f, 0.f, 0.f, 0.f}, sa[4] = {0.f, 0.f, 0.f, 0.f};
#pragma unroll
        for (int nt = 0; nt < 4; nt++) {
            f32x4 acc = __builtin_amdgcn_mfma_f32_16x16x32_bf16(a0, Bf[0][nt], z, 0, 0, 0);
            acc = __builtin_amdgcn_mfma_f32_16x16x32_bf16(a1, Bf[1][nt], acc, 0, 0, 0);
#pragma unroll
            for (int r = 0; r < 4; r++) {
                float v = sspf(acc[r] + bias[nt]);
                sd[r] = fmaf(v, wdv[nt], sd[r]);
                sa[r] = fmaf(v, wav[nt], sa[r]);
            }
        }
#pragma unroll
        for (int r = 0; r < 4; r++) {
            float d = sd[r], a = sa[r];
#pragma unroll
            for (int off = 1; off < 16; off <<= 1) {
                d += __shfl_xor(d, off, 64);
                a += __shfl_xor(a, off, 64);
            }
            if (l15 == 0)
                *(float2*)(ctab + (size_t)(R + g * 4 + r) * 2) = float2{d, a};
        }
    }
}

// ---------------- fused pair + pin readout ----------------
__global__ __launch_bounds__(256) void k_readout(
    const int* __restrict__ pairs,
    const float* __restrict__ pin_feat,
    const int* __restrict__ pin_net, const int* __restrict__ pin_cell,
    const float* __restrict__ ntab, const float* __restrict__ ctab,
    const float* __restrict__ plw, const float* __restrict__ plb,
    const float* __restrict__ pdw, const float* __restrict__ paw,
    const float* __restrict__ nbd, const float* __restrict__ nba,
    const float* __restrict__ pbd, const float* __restrict__ pba,
    float* __restrict__ out) {
    int i = blockIdx.x * blockDim.x + threadIdx.x;
    if (i < NPAIR) {
        int p0 = pairs[2 * i], p1 = pairs[2 * i + 1];
        float2 x0 = *(const float2*)(ntab + (size_t)p0 * 8);
        float2 x1 = *(const float2*)(ntab + (size_t)p1 * 8 + 2);
        out[i] = softplusf(x0.x + x1.x + nbd[0]);
        out[NPAIR + i] = x0.y + x1.y + nba[0];
    } else if (i < NPAIR + NPIN) {
        int p = i - NPAIR;
        int n = pin_net[p], c = pin_cell[p];
        float2 ns = *(const float2*)(ntab + (size_t)n * 8 + 4);
        float2 cs = *(const float2*)(ctab + (size_t)c * 2);
        float pf[8];
        *(float4*)pf = *(const float4*)(pin_feat + (size_t)p * 8);
        *(float4*)(pf + 4) = *(const float4*)(pin_feat + (size_t)p * 8 + 4);
        float sd = ns.x + cs.x + pbd[0];
        float sa = ns.y + cs.y + pba[0];
#pragma unroll
        for (int j = 0; j < 8; j++) {
            float a = plb[j];
#pragma unroll
            for (int k = 0; k < 8; k++) a = fmaf(pf[k], plw[k * 8 + j], a);
            float hp = ftanh(a);
            sd = fmaf(hp, pdw[64 + j], sd);
            sa = fmaf(hp, paw[64 + j], sa);
        }
        out[2 * NPAIR + p] = softplusf(sd);
        out[2 * NPAIR + NPIN + p] = sa;
    }
}

extern "C" void kernel_launch(void* const* d_in, const int* in_sizes, int n_in,
                              void* d_out, int out_size, void* d_ws, size_t ws_size,
                              hipStream_t stream) {
    const float* cell_feat = (const float*)d_in[0];
    const float* net_feat  = (const float*)d_in[1];
    const float* pin_feat  = (const float*)d_in[2];
    const float* cell_lin_w = (const float*)d_in[3];
    const float* cell_lin_b = (const float*)d_in[4];
    const float* net_lin_w  = (const float*)d_in[5];
    const float* net_lin_b  = (const float*)d_in[6];
    const float* pin_lin_w  = (const float*)d_in[7];
    const float* pin_lin_b  = (const float*)d_in[8];
    const float* pins_w   = (const float*)d_in[9];
    const float* pins_b   = (const float*)d_in[10];
    const float* father_w = (const float*)d_in[11];
    const float* father_b = (const float*)d_in[12];
    const float* son_w    = (const float*)d_in[13];
    const float* son_b    = (const float*)d_in[14];
    const float* cf_node_w = (const float*)d_in[15];
    const float* cf_node_b = (const float*)d_in[16];
    const float* cf_e1_w  = (const float*)d_in[17];
    const float* cf_e1_b  = (const float*)d_in[18];
    const float* cf_e2_w  = (const float*)d_in[19];
    const float* cf_e2_b  = (const float*)d_in[20];
    const float* cf_out_w = (const float*)d_in[21];
    const float* cf_out_b = (const float*)d_in[22];
    const float* net_dis_w   = (const float*)d_in[23];
    const float* net_dis_b   = (const float*)d_in[24];
    const float* net_angle_w = (const float*)d_in[25];
    const float* net_angle_b = (const float*)d_in[26];
    const float* pin_dis_w   = (const float*)d_in[27];
    const float* pin_dis_b   = (const float*)d_in[28];
    const float* pin_angle_w = (const float*)d_in[29];
    const float* pin_angle_b = (const float*)d_in[30];
    const int* pin_net = (const int*)d_in[31];
    const int* pin_cell = (const int*)d_in[32];
    const int* nn_src = (const int*)d_in[33];
    const int* nn_dst = (const int*)d_in[34];
    const int* pairs = (const int*)d_in[35];

    u16* ws16 = (u16*)d_ws;
    const size_t SZ = (size_t)NNET * 64;   // u16 elements per row-table
    // layout: h_cell | bufA | h_net | hS | hD | bufB | bufC | (f32 tail)
    // etab (5*SZ) aliases h_net..bufC after their last consumers.
    u16* h_cell = ws16;                // rC-scaled; later reused for hv
    u16* bufA   = ws16 + SZ;           // accP, later acc_cell
    u16* h_net  = ws16 + 2 * SZ;
    u16* hS     = ws16 + 3 * SZ;
    u16* hD     = ws16 + 4 * SZ;
    u16* bufB   = ws16 + 5 * SZ;       // accF
    u16* bufC   = ws16 + 6 * SZ;       // accS
    u16* etab   = ws16 + 2 * SZ;       // NPIN*64 u16 = 5*SZ (after mm64hv)
    float* deg  = (float*)(ws16 + 7 * SZ);     // 4 * NNET f32
    float* rC  = deg;
    float* rNp = deg + NNET;
    float* rS  = deg + 2 * NNET;
    float* rD  = deg + 3 * NNET;
    float* ntab = deg + 4 * NNET;              // NNET*8 f32
    float* ctab = ntab + (size_t)NNET * 8;     // NCELL*2 f32

    hipMemsetAsync(bufA, 0, SZ * sizeof(u16), stream);            // accP
    hipMemsetAsync(bufB, 0, 2 * SZ * sizeof(u16), stream);        // accF, accS
    hipMemsetAsync(deg, 0, 4 * NNET * sizeof(float), stream);

    k_degrees<<<(NPIN + 255) / 256, 256, 0, stream>>>(pin_cell, pin_net, nn_src, nn_dst,
                                                      rC, rNp, rS, rD);
    k_deg_fin<<<(4 * NNET + 255) / 256, 256, 0, stream>>>(deg);

    k_lin16_all<<<2048, 256, 0, stream>>>(cell_feat, net_feat,
                                          cell_lin_w, cell_lin_b, net_lin_w, net_lin_b,
                                          rC, rS, rD, h_cell, h_net, hS, hD);

    k_scatter_all<<<2048, 256, 0, stream>>>(pin_cell, pin_net, nn_src, nn_dst,
                                            h_cell, hS, hD, bufA, bufB, bufC);

    k_combine3<<<512, 256, 0, stream>>>(bufA, pins_w, pins_b,
                                        bufB, father_w, father_b,
                                        bufC, son_w, son_b,
                                        rNp, rD, rS,
                                        net_dis_w, net_angle_w, pin_dis_w, pin_angle_w,
                                        ntab, NNET);

    // hv = h_net @ cf_node_w + b   -> h_cell buffer (free after scatter_all)
    k_mm64hv<<<512, 256, 0, stream>>>(h_net, cf_node_w, cf_node_b, h_cell, NNET);

    // e-table: streaming e-MLP over all pins (h_net..bufC now free -> etab)
    k_emlp<<<1024, 256, 0, stream>>>(pin_feat, cf_e1_w, cf_e1_b, cf_e2_w, cf_e2_b, etab);

    hipMemsetAsync(bufA, 0, SZ * sizeof(u16), stream);            // acc_cell
    k_escatter<<<2048, 256, 0, stream>>>(etab, h_cell, pin_net, pin_cell, bufA);

    k_mm64c<<<512, 256, 0, stream>>>(bufA, cf_out_w, cf_out_b,
                                     pin_dis_w, pin_angle_w, ctab, NCELL);

    float* out = (float*)d_out;
    k_readout<<<(NPAIR + NPIN + 255) / 256, 256, 0, stream>>>(
        pairs, pin_feat, pin_net, pin_cell, ntab, ctab,
        pin_lin_w, pin_lin_b, pin_dis_w, pin_angle_w,
        net_dis_b, net_angle_b, pin_dis_b, pin_angle_b, out);
}